// Round 3
// baseline (1351.059 us; speedup 1.0000x reference)
//
#include <hip/hip_runtime.h>
#include <hip/hip_bf16.h>

#define NUSERS 60000
#define NNODES 100000
#define DD 64

typedef __hip_bfloat16 bf16;

__device__ __forceinline__ float b2f(bf16 x) { return __bfloat162float(x); }
__device__ __forceinline__ bf16 f2b(float x) { return __float2bfloat16(x); }
__device__ __forceinline__ float lo_bf16(unsigned w) {
    union { unsigned u; float f; } t; t.u = w << 16; return t.f;
}
__device__ __forceinline__ float hi_bf16(unsigned w) {
    union { unsigned u; float f; } t; t.u = w & 0xFFFF0000u; return t.f;
}

// Runtime-dtype float load: isbf ? bf16[i] : f32[i]
__device__ __forceinline__ float ldf(const void* p, size_t i, int isbf) {
    if (isbf) return b2f(((const bf16*)p)[i]);
    return ((const float*)p)[i];
}

// Sniff the device dtype of u_features. For bf16 data, even-index u16s are
// bf16 values ~N(0,1): exponent field ((h>>7)&0xFF) concentrated in [100,140]
// (~100%). For fp32 data, even u16s are low mantissa halves: uniform (~16%).
// Also zeroes the reduction scratch red[0:256].
__global__ void k_sniff(const unsigned short* __restrict__ h,
                        int* __restrict__ flag, float* __restrict__ red)
{
    __shared__ int cs[256];
    int t = threadIdx.x;
    int cnt = 0;
    for (int i = t; i < 1024; i += 256) {
        int e = (h[2 * i] >> 7) & 0xFF;
        cnt += (e >= 100 && e <= 140) ? 1 : 0;
    }
    cs[t] = cnt;
    __syncthreads();
    for (int s = 128; s > 0; s >>= 1) {
        if (t < s) cs[t] += cs[t + s];
        __syncthreads();
    }
    if (t == 0) flag[0] = (cs[0] > 512) ? 1 : 0;
    red[t] = 0.f;
}

// Two fused GEMMs over x [NNODES,64]:
//   out0 = x@W0 + b0   (fp32 if OUT0F32 else bf16)
//   out1 = x@W1 + b1   (bf16)
// MODE 0: x rows from concat(u,v), dtype per flag.
// MODE 1: x = relu(ab[c]*Aacc[r,c] + ab[64+c])  (BN+relu fused; fp32 source).
template <int MODE, int OUT0F32>
__global__ __launch_bounds__(256) void k_mm2(
    const void* __restrict__ u, const void* __restrict__ v,
    const float* __restrict__ Aacc, const float* __restrict__ ab,
    const void* __restrict__ W0, const void* __restrict__ W1,
    const void* __restrict__ b0, const void* __restrict__ b1,
    const int* __restrict__ flag,
    void* out0, bf16* __restrict__ out1)
{
    __shared__ float Ws[2][DD][DD];  // 32 KB
    __shared__ float xs[4][DD];
    const int bf = flag[0];
    const int tid = threadIdx.x;
    for (int i = tid; i < DD * DD; i += 256) {
        Ws[0][i >> 6][i & 63] = ldf(W0, i, bf);
        Ws[1][i >> 6][i & 63] = ldf(W1, i, bf);
    }
    const int c = tid & 63, rg = tid >> 6;
    const float bias0 = b0 ? ldf(b0, c, bf) : 0.f;
    const float bias1 = b1 ? ldf(b1, c, bf) : 0.f;
    float a_c = 0.f, b_c = 0.f;
    if (MODE == 1) { a_c = ab[c]; b_c = ab[64 + c]; }
    __syncthreads();
    for (int base = blockIdx.x * 4; base < NNODES; base += gridDim.x * 4) {
        int row = base + rg;
        size_t o = (size_t)row * DD + c;
        if (row < NNODES) {
            float xv;
            if (MODE == 0) {
                xv = (row < NUSERS) ? ldf(u, (size_t)row * DD + c, bf)
                                    : ldf(v, (size_t)(row - NUSERS) * DD + c, bf);
            } else {
                float t = a_c * Aacc[o] + b_c;
                xv = t > 0.f ? t : 0.f;
            }
            xs[rg][c] = xv;
        }
        __syncthreads();
        if (row < NNODES) {
            float s0 = bias0, s1 = bias1;
#pragma unroll
            for (int k = 0; k < DD; k++) {
                float xv = xs[rg][k];
                s0 += xv * Ws[0][k][c];
                s1 += xv * Ws[1][k][c];
            }
            if (OUT0F32) ((float*)out0)[o] = s0;
            else         ((bf16*)out0)[o] = f2b(s0);
            out1[o] = f2b(s1);
        }
        __syncthreads();
    }
}

// 32 threads per edge, each handles one bf16 feature-pair (4B loads).
__global__ __launch_bounds__(256) void k_edge(
    const int* __restrict__ es, const int* __restrict__ ee,
    const bf16* __restrict__ gU, const bf16* __restrict__ gVs,
    const bf16* __restrict__ gVe, float* __restrict__ acc, int nE)
{
    int t = blockIdx.x * 256 + threadIdx.x;
    int e = t >> 5;
    if (e >= nE) return;
    int c2 = t & 31;
    int s = es[e], d = ee[e];
    unsigned a = *(const unsigned*)(gVe + (size_t)d * DD + 2 * c2);
    unsigned b = *(const unsigned*)(gVs + (size_t)s * DD + 2 * c2);
    unsigned m = *(const unsigned*)(gU  + (size_t)s * DD + 2 * c2);
    float g0 = lo_bf16(a) + lo_bf16(b);
    float g1 = hi_bf16(a) + hi_bf16(b);
    float msg0 = lo_bf16(m) / (1.f + __expf(-g0));
    float msg1 = hi_bf16(m) / (1.f + __expf(-g1));
    float* p = acc + (size_t)d * DD + 2 * c2;
    unsafeAtomicAdd(p, msg0);
    unsafeAtomicAdd(p + 1, msg1);
}

// Column sums + sumsq over fp32 [NNODES,64] -> red[0:64]=sum, red[64:128]=sumsq
__global__ __launch_bounds__(256) void k_reduce(
    const float* __restrict__ x, float* __restrict__ red)
{
    __shared__ float s1[256], s2[256];
    const int c = threadIdx.x & 63, rg = threadIdx.x >> 6;
    float sum = 0.f, sq = 0.f;
    for (int row = blockIdx.x * 4 + rg; row < NNODES; row += gridDim.x * 4) {
        float vv = x[(size_t)row * DD + c];
        sum += vv;
        sq += vv * vv;
    }
    s1[threadIdx.x] = sum;
    s2[threadIdx.x] = sq;
    __syncthreads();
    if (threadIdx.x < 64) {
        sum = s1[c] + s1[64 + c] + s1[128 + c] + s1[192 + c];
        sq = s2[c] + s2[64 + c] + s2[128 + c] + s2[192 + c];
        unsafeAtomicAdd(&red[c], sum);
        unsafeAtomicAdd(&red[64 + c], sq);
    }
}

// ab[c] = gamma*rstd ; ab[64+c] = beta - mean*gamma*rstd
__global__ void k_stats(const float* __restrict__ red,
                        const void* __restrict__ gamma,
                        const void* __restrict__ beta,
                        const int* __restrict__ flag,
                        float* __restrict__ ab)
{
    int c = threadIdx.x;  // 64 threads
    int bf = flag[0];
    float mean = red[c] * (1.f / NNODES);
    float var = red[64 + c] * (1.f / NNODES) - mean * mean;
    float rstd = rsqrtf(var + 1e-3f);
    float a = ldf(gamma, c, bf) * rstd;
    ab[c] = a;
    ab[64 + c] = ldf(beta, c, bf) - mean * a;
}

// out = relu(ab[c]*A + ab[64+c] + x_in@R), stored per flag dtype.
__global__ __launch_bounds__(256) void k_final(
    const float* __restrict__ A, const float* __restrict__ ab,
    const void* __restrict__ u, const void* __restrict__ v,
    const void* __restrict__ R, const int* __restrict__ flag,
    void* __restrict__ out)
{
    __shared__ float Rw[DD][DD];
    __shared__ float xs[4][DD];
    const int bf = flag[0];
    const int tid = threadIdx.x;
    for (int i = tid; i < DD * DD; i += 256)
        Rw[i >> 6][i & 63] = ldf(R, i, bf);
    const int c = tid & 63, rg = tid >> 6;
    const float a_c = ab[c], b_c = ab[64 + c];
    __syncthreads();
    for (int base = blockIdx.x * 4; base < NNODES; base += gridDim.x * 4) {
        int row = base + rg;
        size_t o = (size_t)row * DD + c;
        if (row < NNODES) {
            xs[rg][c] = (row < NUSERS) ? ldf(u, (size_t)row * DD + c, bf)
                                       : ldf(v, (size_t)(row - NUSERS) * DD + c, bf);
        }
        __syncthreads();
        if (row < NNODES) {
            float s = 0.f;
#pragma unroll
            for (int k = 0; k < DD; k++)
                s += xs[rg][k] * Rw[k][c];
            float vv = a_c * A[o] + b_c + s;
            vv = vv > 0.f ? vv : 0.f;
            if (bf) ((bf16*)out)[o] = f2b(vv);
            else    ((float*)out)[o] = vv;
        }
        __syncthreads();
    }
}

extern "C" void kernel_launch(void* const* d_in, const int* in_sizes, int n_in,
                              void* d_out, int out_size, void* d_ws, size_t ws_size,
                              hipStream_t stream)
{
    const void* u   = d_in[0];
    const void* v   = d_in[1];
    const int* es   = (const int*)d_in[2];
    const int* ee   = (const int*)d_in[3];
    const void* Ui1 = d_in[4];
    const void* Uj1 = d_in[5];
    const void* Vi1 = d_in[6];
    const void* Vj1 = d_in[7];
    const void* bu1 = d_in[8];
    const void* bv1 = d_in[9];
    const void* Ui2 = d_in[10];
    const void* Uj2 = d_in[11];
    const void* Vi2 = d_in[12];
    const void* Vj2 = d_in[13];
    const void* bu2 = d_in[14];
    const void* bv2 = d_in[15];
    const void* R   = d_in[16];
    const void* g1  = d_in[17];
    const void* be1 = d_in[18];
    const void* g2  = d_in[19];
    const void* be2 = d_in[20];
    const int E = in_sizes[2];

    // Workspace layout (51.2 MB + 2.1 KB). gU lives in d_out (>=12.8 MB both dtypes).
    char* ws = (char*)d_ws;
    float* A    = (float*)(ws);                 // 25.6 MB fp32 accumulator
    bf16* gVs   = (bf16*)(ws + 25600000);       // 12.8 MB
    bf16* gVe   = (bf16*)(ws + 38400000);       // 12.8 MB (ends 51,200,000)
    float* red  = (float*)(ws + 51200000);      // red1[128], red2[128], ab1[128], ab2[128]
    int* flag   = (int*)(ws + 51202048);
    float* red1 = red, *red2 = red + 128, *ab1 = red + 256, *ab2 = red + 384;
    bf16* gU    = (bf16*)d_out;                 // scratch until k_final overwrites

    k_sniff<<<1, 256, 0, stream>>>((const unsigned short*)u, flag, red);

    // ---- stage 1 ----
    k_mm2<0, 1><<<1024, 256, 0, stream>>>(u, v, nullptr, nullptr,
                                          Uj1, Ui1, bu1, nullptr, flag, A, gU);
    k_mm2<0, 0><<<1024, 256, 0, stream>>>(u, v, nullptr, nullptr,
                                          Vi1, Vj1, bv1, nullptr, flag, gVe, gVs);
    k_edge<<<(E * 32 + 255) / 256, 256, 0, stream>>>(es, ee, gU, gVs, gVe, A, E);
    k_reduce<<<512, 256, 0, stream>>>(A, red1);
    k_stats<<<1, 64, 0, stream>>>(red1, g1, be1, flag, ab1);

    // ---- stage 2 (BN1+relu fused; mmB reads A first, then mmA updates A in place) ----
    k_mm2<1, 0><<<1024, 256, 0, stream>>>(nullptr, nullptr, A, ab1,
                                          Vi2, Vj2, bv2, nullptr, flag, gVe, gVs);
    k_mm2<1, 1><<<1024, 256, 0, stream>>>(nullptr, nullptr, A, ab1,
                                          Uj2, Ui2, bu2, nullptr, flag, A, gU);
    k_edge<<<(E * 32 + 255) / 256, 256, 0, stream>>>(es, ee, gU, gVs, gVe, A, E);
    k_reduce<<<512, 256, 0, stream>>>(A, red2);
    k_stats<<<1, 64, 0, stream>>>(red2, g2, be2, flag, ab2);

    // ---- BN2 + residual (x_in@R recomputed) + relu -> out ----
    k_final<<<1024, 256, 0, stream>>>(A, ab2, u, v, R, flag, d_out);
}

// Round 4
// 864.333 us; speedup vs baseline: 1.5631x; 1.5631x over previous
//
#include <hip/hip_runtime.h>
#include <hip/hip_bf16.h>

#define NUSERS 60000
#define NNODES 100000
#define DD 64
#define NB 391  // ceil(NNODES/256)

typedef __hip_bfloat16 bf16;

__device__ __forceinline__ float b2f(bf16 x) { return __bfloat162float(x); }
__device__ __forceinline__ bf16 f2b(float x) { return __float2bfloat16(x); }
__device__ __forceinline__ unsigned short fbits(float x) {
    union { bf16 b; unsigned short u; } cv; cv.b = f2b(x); return cv.u;
}
__device__ __forceinline__ float lo_bf16(unsigned w) {
    union { unsigned u; float f; } t; t.u = w << 16; return t.f;
}
__device__ __forceinline__ float hi_bf16(unsigned w) {
    union { unsigned u; float f; } t; t.u = w & 0xFFFF0000u; return t.f;
}
// Runtime-dtype float load: isbf ? bf16[i] : f32[i]
__device__ __forceinline__ float ldf(const void* p, size_t i, int isbf) {
    if (isbf) return b2f(((const bf16*)p)[i]);
    return ((const float*)p)[i];
}

// Sniff dtype of u_features (bf16 vs fp32) + zero red[0:256].
__global__ void k_sniff(const unsigned short* __restrict__ h,
                        int* __restrict__ flag, float* __restrict__ red)
{
    __shared__ int cs[256];
    int t = threadIdx.x;
    int cnt = 0;
    for (int i = t; i < 1024; i += 256) {
        int e = (h[2 * i] >> 7) & 0xFF;
        cnt += (e >= 100 && e <= 140) ? 1 : 0;
    }
    cs[t] = cnt;
    __syncthreads();
    for (int s = 128; s > 0; s >>= 1) {
        if (t < s) cs[t] += cs[t + s];
        __syncthreads();
    }
    if (t == 0) flag[0] = (cs[0] > 512) ? 1 : 0;
    red[t] = 0.f;
}

__global__ void k_zeroi(int* __restrict__ p, int n) {
    int i = blockIdx.x * 256 + threadIdx.x;
    if (i < n) p[i] = 0;
}

// ---- CSR build (destination-sorted edges), done once per launch ----
__global__ void k_hist(const int* __restrict__ ee, int* __restrict__ cnt, int E) {
    int e = blockIdx.x * 256 + threadIdx.x;
    if (e < E) atomicAdd(&cnt[ee[e]], 1);
}

__global__ void k_scan1(const int* __restrict__ cnt, int* __restrict__ incl,
                        int* __restrict__ bsum)
{
    __shared__ int sd[256];
    int i = blockIdx.x * 256 + threadIdx.x;
    int val = (i < NNODES) ? cnt[i] : 0;
    sd[threadIdx.x] = val;
    __syncthreads();
    for (int off = 1; off < 256; off <<= 1) {
        int t = (threadIdx.x >= off) ? sd[threadIdx.x - off] : 0;
        __syncthreads();
        sd[threadIdx.x] += t;
        __syncthreads();
    }
    if (i < NNODES) incl[i] = sd[threadIdx.x];
    if (threadIdx.x == 255) bsum[blockIdx.x] = sd[255];
}

__global__ void k_scan2(int* __restrict__ bsum) {  // in-place inclusive scan, NB<=512
    __shared__ int sd[512];
    int t = threadIdx.x;
    sd[t] = (t < NB) ? bsum[t] : 0;
    __syncthreads();
    for (int off = 1; off < 512; off <<= 1) {
        int x = (t >= off) ? sd[t - off] : 0;
        __syncthreads();
        sd[t] += x;
        __syncthreads();
    }
    if (t < NB) bsum[t] = sd[t];
}

__global__ void k_scan3(const int* __restrict__ cnt, const int* __restrict__ incl,
                        const int* __restrict__ bsum, int* __restrict__ rowptr,
                        int* __restrict__ fill)
{
    int i = blockIdx.x * 256 + threadIdx.x;
    if (i >= NNODES) return;
    int boff = (blockIdx.x == 0) ? 0 : bsum[blockIdx.x - 1];
    int start = boff + incl[i] - cnt[i];
    rowptr[i] = start;
    fill[i] = start;
    if (i == NNODES - 1) rowptr[NNODES] = boff + incl[i];
}

__global__ void k_scatter(const int* __restrict__ es, const int* __restrict__ ee,
                          int* __restrict__ fill, int* __restrict__ srcidx, int E)
{
    int e = blockIdx.x * 256 + threadIdx.x;
    if (e < E) {
        int pos = atomicAdd(&fill[ee[e]], 1);
        srcidx[pos] = es[e];
    }
}

// ---- Fused 2-GEMM pass: out0 = x@W0+b0 (fp32), out1 = x@W1+b1 (bf16) ----
// MODE 0: x rows from concat(u,v), dtype per flag. MODE 1: x = relu(ab*A+ab').
template <int MODE>
__global__ __launch_bounds__(256) void k_mm2(
    const void* __restrict__ u, const void* __restrict__ v,
    const float* __restrict__ Aacc, const float* __restrict__ ab,
    const void* __restrict__ W0, const void* __restrict__ W1,
    const void* __restrict__ b0, const void* __restrict__ b1,
    const int* __restrict__ flag,
    float* out0, bf16* __restrict__ out1)
{
    __shared__ float Ws[2][DD][DD];
    __shared__ float xs[4][DD];
    const int bf = flag[0];
    const int tid = threadIdx.x;
    for (int i = tid; i < DD * DD; i += 256) {
        Ws[0][i >> 6][i & 63] = ldf(W0, i, bf);
        Ws[1][i >> 6][i & 63] = ldf(W1, i, bf);
    }
    const int c = tid & 63, rg = tid >> 6;
    const float bias0 = b0 ? ldf(b0, c, bf) : 0.f;
    const float bias1 = b1 ? ldf(b1, c, bf) : 0.f;
    float a_c = 0.f, b_c = 0.f;
    if (MODE == 1) { a_c = ab[c]; b_c = ab[64 + c]; }
    __syncthreads();
    for (int base = blockIdx.x * 4; base < NNODES; base += gridDim.x * 4) {
        int row = base + rg;
        size_t o = (size_t)row * DD + c;
        if (row < NNODES) {
            float xv;
            if (MODE == 0) {
                xv = (row < NUSERS) ? ldf(u, (size_t)row * DD + c, bf)
                                    : ldf(v, (size_t)(row - NUSERS) * DD + c, bf);
            } else {
                float t = a_c * Aacc[o] + b_c;
                xv = t > 0.f ? t : 0.f;
            }
            xs[rg][c] = xv;
        }
        __syncthreads();
        if (row < NNODES) {
            float s0 = bias0, s1 = bias1;
#pragma unroll
            for (int k = 0; k < DD; k++) {
                float xv = xs[rg][k];
                s0 += xv * Ws[0][k][c];
                s1 += xv * Ws[1][k][c];
            }
            out0[o] = s0;
            out1[o] = f2b(s1);
        }
        __syncthreads();
    }
}

// ---- Fused 2-GEMM writing interleaved uint: T = bits(x@W0) | bits(x@W1)<<16 ----
template <int MODE>
__global__ __launch_bounds__(256) void k_mmT(
    const void* __restrict__ u, const void* __restrict__ v,
    const float* __restrict__ Aacc, const float* __restrict__ ab,
    const void* __restrict__ W0, const void* __restrict__ W1,
    const int* __restrict__ flag, unsigned* __restrict__ T)
{
    __shared__ float Ws[2][DD][DD];
    __shared__ float xs[4][DD];
    const int bf = flag[0];
    const int tid = threadIdx.x;
    for (int i = tid; i < DD * DD; i += 256) {
        Ws[0][i >> 6][i & 63] = ldf(W0, i, bf);
        Ws[1][i >> 6][i & 63] = ldf(W1, i, bf);
    }
    const int c = tid & 63, rg = tid >> 6;
    float a_c = 0.f, b_c = 0.f;
    if (MODE == 1) { a_c = ab[c]; b_c = ab[64 + c]; }
    __syncthreads();
    for (int base = blockIdx.x * 4; base < NNODES; base += gridDim.x * 4) {
        int row = base + rg;
        size_t o = (size_t)row * DD + c;
        if (row < NNODES) {
            float xv;
            if (MODE == 0) {
                xv = (row < NUSERS) ? ldf(u, (size_t)row * DD + c, bf)
                                    : ldf(v, (size_t)(row - NUSERS) * DD + c, bf);
            } else {
                float t = a_c * Aacc[o] + b_c;
                xv = t > 0.f ? t : 0.f;
            }
            xs[rg][c] = xv;
        }
        __syncthreads();
        if (row < NNODES) {
            float s0 = 0.f, s1 = 0.f;
#pragma unroll
            for (int k = 0; k < DD; k++) {
                float xv = xs[rg][k];
                s0 += xv * Ws[0][k][c];
                s1 += xv * Ws[1][k][c];
            }
            T[o] = (unsigned)fbits(s0) | ((unsigned)fbits(s1) << 16);
        }
        __syncthreads();
    }
}

// ---- Gather-accumulate: one wave per destination node, no atomics ----
// A[d][c] += sum_e sigmoid(gVe[d][c] + hi(T[src])) * lo(T[src])
__global__ __launch_bounds__(256) void k_accum(
    const int* __restrict__ rowptr, const int* __restrict__ srcidx,
    const unsigned* __restrict__ T, const bf16* __restrict__ gVe,
    float* __restrict__ A)
{
    int d = blockIdx.x * 4 + (threadIdx.x >> 6);
    if (d >= NNODES) return;
    int c = threadIdx.x & 63;
    int r0 = rowptr[d], r1 = rowptr[d + 1];
    float gv = b2f(gVe[(size_t)d * DD + c]);
    float sum = 0.f;
    for (int i = r0; i < r1; i++) {
        int s = srcidx[i];
        unsigned t = T[(size_t)s * DD + c];
        float gate = gv + hi_bf16(t);
        sum += lo_bf16(t) / (1.f + __expf(-gate));
    }
    size_t o = (size_t)d * DD + c;
    A[o] += sum;
}

// Column sums + sumsq over fp32 [NNODES,64]
__global__ __launch_bounds__(256) void k_reduce(
    const float* __restrict__ x, float* __restrict__ red)
{
    __shared__ float s1[256], s2[256];
    const int c = threadIdx.x & 63, rg = threadIdx.x >> 6;
    float sum = 0.f, sq = 0.f;
    for (int row = blockIdx.x * 4 + rg; row < NNODES; row += gridDim.x * 4) {
        float vv = x[(size_t)row * DD + c];
        sum += vv;
        sq += vv * vv;
    }
    s1[threadIdx.x] = sum;
    s2[threadIdx.x] = sq;
    __syncthreads();
    if (threadIdx.x < 64) {
        sum = s1[c] + s1[64 + c] + s1[128 + c] + s1[192 + c];
        sq = s2[c] + s2[64 + c] + s2[128 + c] + s2[192 + c];
        unsafeAtomicAdd(&red[c], sum);
        unsafeAtomicAdd(&red[64 + c], sq);
    }
}

__global__ void k_stats(const float* __restrict__ red,
                        const void* __restrict__ gamma,
                        const void* __restrict__ beta,
                        const int* __restrict__ flag,
                        float* __restrict__ ab)
{
    int c = threadIdx.x;  // 64 threads
    int bf = flag[0];
    float mean = red[c] * (1.f / NNODES);
    float var = red[64 + c] * (1.f / NNODES) - mean * mean;
    float rstd = rsqrtf(var + 1e-3f);
    float a = ldf(gamma, c, bf) * rstd;
    ab[c] = a;
    ab[64 + c] = ldf(beta, c, bf) - mean * a;
}

// out = relu(ab[c]*A + ab[64+c] + x_in@R), stored per flag dtype.
__global__ __launch_bounds__(256) void k_final(
    const float* __restrict__ A, const float* __restrict__ ab,
    const void* __restrict__ u, const void* __restrict__ v,
    const void* __restrict__ R, const int* __restrict__ flag,
    void* __restrict__ out)
{
    __shared__ float Rw[DD][DD];
    __shared__ float xs[4][DD];
    const int bf = flag[0];
    const int tid = threadIdx.x;
    for (int i = tid; i < DD * DD; i += 256)
        Rw[i >> 6][i & 63] = ldf(R, i, bf);
    const int c = tid & 63, rg = tid >> 6;
    const float a_c = ab[c], b_c = ab[64 + c];
    __syncthreads();
    for (int base = blockIdx.x * 4; base < NNODES; base += gridDim.x * 4) {
        int row = base + rg;
        size_t o = (size_t)row * DD + c;
        if (row < NNODES) {
            xs[rg][c] = (row < NUSERS) ? ldf(u, (size_t)row * DD + c, bf)
                                       : ldf(v, (size_t)(row - NUSERS) * DD + c, bf);
        }
        __syncthreads();
        if (row < NNODES) {
            float s = 0.f;
#pragma unroll
            for (int k = 0; k < DD; k++)
                s += xs[rg][k] * Rw[k][c];
            float vv = a_c * A[o] + b_c + s;
            vv = vv > 0.f ? vv : 0.f;
            if (bf) ((bf16*)out)[o] = f2b(vv);
            else    ((float*)out)[o] = vv;
        }
        __syncthreads();
    }
}

extern "C" void kernel_launch(void* const* d_in, const int* in_sizes, int n_in,
                              void* d_out, int out_size, void* d_ws, size_t ws_size,
                              hipStream_t stream)
{
    const void* u   = d_in[0];
    const void* v   = d_in[1];
    const int* es   = (const int*)d_in[2];
    const int* ee   = (const int*)d_in[3];
    const void* Ui1 = d_in[4];
    const void* Uj1 = d_in[5];
    const void* Vi1 = d_in[6];
    const void* Vj1 = d_in[7];
    const void* bu1 = d_in[8];
    const void* bv1 = d_in[9];
    const void* Ui2 = d_in[10];
    const void* Uj2 = d_in[11];
    const void* Vi2 = d_in[12];
    const void* Vj2 = d_in[13];
    const void* bu2 = d_in[14];
    const void* bv2 = d_in[15];
    const void* R   = d_in[16];
    const void* g1  = d_in[17];
    const void* be1 = d_in[18];
    const void* g2  = d_in[19];
    const void* be2 = d_in[20];
    const int E = in_sizes[2];

    // Workspace layout (~56.8 MB). gVe lives in d_out (>=12.8 MB both dtypes;
    // last gVe read precedes k_final's overwrite).
    char* ws = (char*)d_ws;
    float* A      = (float*)(ws);                  // 25.6 MB fp32 accumulator
    unsigned* T   = (unsigned*)(ws + 25600000);    // 25.6 MB interleaved (Vj<<16|Ui)
    int* srcidx   = (int*)(ws + 51200000);         // 4 MB (E<=1M)
    int* cnt      = (int*)(ws + 55200000);         // 400 KB
    int* incl     = (int*)(ws + 55600000);         // 400 KB
    int* rowptr   = (int*)(ws + 56000000);         // 400,004 B
    int* fill     = (int*)(ws + 56400128);         // 400 KB
    int* bsum     = (int*)(ws + 56800128);         // 2 KB
    float* red    = (float*)(ws + 56802176);       // red1[128] red2[128] ab1[128] ab2[128]
    int* flag     = (int*)(ws + 56804224);
    float* red1 = red, *red2 = red + 128, *ab1 = red + 256, *ab2 = red + 384;
    bf16* gVe = (bf16*)d_out;

    // ---- dtype sniff + CSR build (edges shared by both stages) ----
    k_sniff<<<1, 256, 0, stream>>>((const unsigned short*)u, flag, red);
    k_zeroi<<<NB, 256, 0, stream>>>(cnt, NNODES);
    k_hist<<<(E + 255) / 256, 256, 0, stream>>>(ee, cnt, E);
    k_scan1<<<NB, 256, 0, stream>>>(cnt, incl, bsum);
    k_scan2<<<1, 512, 0, stream>>>(bsum);
    k_scan3<<<NB, 256, 0, stream>>>(cnt, incl, bsum, rowptr, fill);
    k_scatter<<<(E + 255) / 256, 256, 0, stream>>>(es, ee, fill, srcidx, E);

    // ---- stage 1 ----
    k_mm2<0><<<1024, 256, 0, stream>>>(u, v, nullptr, nullptr,
                                       Uj1, Vi1, bu1, bv1, flag, A, gVe);
    k_mmT<0><<<1024, 256, 0, stream>>>(u, v, nullptr, nullptr,
                                       Ui1, Vj1, flag, T);
    k_accum<<<(NNODES + 3) / 4, 256, 0, stream>>>(rowptr, srcidx, T, gVe, A);
    k_reduce<<<512, 256, 0, stream>>>(A, red1);
    k_stats<<<1, 64, 0, stream>>>(red1, g1, be1, flag, ab1);

    // ---- stage 2 (BN1+relu fused into row loads; T before in-place A update) ----
    k_mmT<1><<<1024, 256, 0, stream>>>(nullptr, nullptr, A, ab1,
                                       Ui2, Vj2, flag, T);
    k_mm2<1><<<1024, 256, 0, stream>>>(nullptr, nullptr, A, ab1,
                                       Uj2, Vi2, bu2, bv2, flag, A, gVe);
    k_accum<<<(NNODES + 3) / 4, 256, 0, stream>>>(rowptr, srcidx, T, gVe, A);
    k_reduce<<<512, 256, 0, stream>>>(A, red2);
    k_stats<<<1, 64, 0, stream>>>(red2, g2, be2, flag, ab2);

    // ---- BN2 + residual (x_in@R recomputed) + relu -> out ----
    k_final<<<1024, 256, 0, stream>>>(A, ab2, u, v, R, flag, d_out);
}

// Round 6
// 651.862 us; speedup vs baseline: 2.0726x; 1.3259x over previous
//
#include <hip/hip_runtime.h>
#include <hip/hip_bf16.h>

#define NUSERS 60000
#define NNODES 100000
#define DD 64
#define NB 391  // ceil(NNODES/256)

typedef __hip_bfloat16 bf16;

__device__ __forceinline__ float b2f(bf16 x) { return __bfloat162float(x); }
__device__ __forceinline__ bf16 f2b(float x) { return __float2bfloat16(x); }
__device__ __forceinline__ unsigned short fbits(float x) {
    union { bf16 b; unsigned short u; } cv; cv.b = f2b(x); return cv.u;
}
__device__ __forceinline__ float lo_bf16(unsigned w) {
    union { unsigned u; float f; } t; t.u = w << 16; return t.f;
}
__device__ __forceinline__ float hi_bf16(unsigned w) {
    union { unsigned u; float f; } t; t.u = w & 0xFFFF0000u; return t.f;
}
// Runtime-dtype float load: isbf ? bf16[i] : f32[i]
__device__ __forceinline__ float ldf(const void* p, size_t i, int isbf) {
    if (isbf) return b2f(((const bf16*)p)[i]);
    return ((const float*)p)[i];
}
// sigmoid via fast rcp (v_rcp_f32, ~1 ulp) instead of exact div sequence
__device__ __forceinline__ float fsig(float g) {
    return __builtin_amdgcn_rcpf(1.f + __expf(-g));
}

// Sniff dtype of u_features (bf16 vs fp32) + zero red[0:256].
__global__ void k_sniff(const unsigned short* __restrict__ h,
                        int* __restrict__ flag, float* __restrict__ red)
{
    __shared__ int cs[256];
    int t = threadIdx.x;
    int cnt = 0;
    for (int i = t; i < 1024; i += 256) {
        int e = (h[2 * i] >> 7) & 0xFF;
        cnt += (e >= 100 && e <= 140) ? 1 : 0;
    }
    cs[t] = cnt;
    __syncthreads();
    for (int s = 128; s > 0; s >>= 1) {
        if (t < s) cs[t] += cs[t + s];
        __syncthreads();
    }
    if (t == 0) flag[0] = (cs[0] > 512) ? 1 : 0;
    red[t] = 0.f;
}

__global__ void k_zeroi(int* __restrict__ p, int n) {
    int i = blockIdx.x * 256 + threadIdx.x;
    if (i < n) p[i] = 0;
}

// ---- CSR build (destination-sorted edges), once per launch ----
__global__ void k_hist(const int* __restrict__ ee, int* __restrict__ cnt, int E) {
    int e = blockIdx.x * 256 + threadIdx.x;
    if (e < E) atomicAdd(&cnt[ee[e]], 1);
}

__global__ void k_scan1(const int* __restrict__ cnt, int* __restrict__ incl,
                        int* __restrict__ bsum)
{
    __shared__ int sd[256];
    int i = blockIdx.x * 256 + threadIdx.x;
    int val = (i < NNODES) ? cnt[i] : 0;
    sd[threadIdx.x] = val;
    __syncthreads();
    for (int off = 1; off < 256; off <<= 1) {
        int t = (threadIdx.x >= off) ? sd[threadIdx.x - off] : 0;
        __syncthreads();
        sd[threadIdx.x] += t;
        __syncthreads();
    }
    if (i < NNODES) incl[i] = sd[threadIdx.x];
    if (threadIdx.x == 255) bsum[blockIdx.x] = sd[255];
}

__global__ void k_scan2(int* __restrict__ bsum) {  // inclusive scan, NB<=512
    __shared__ int sd[512];
    int t = threadIdx.x;
    sd[t] = (t < NB) ? bsum[t] : 0;
    __syncthreads();
    for (int off = 1; off < 512; off <<= 1) {
        int x = (t >= off) ? sd[t - off] : 0;
        __syncthreads();
        sd[t] += x;
        __syncthreads();
    }
    if (t < NB) bsum[t] = sd[t];
}

__global__ void k_scan3(const int* __restrict__ cnt, const int* __restrict__ incl,
                        const int* __restrict__ bsum, int* __restrict__ rowptr,
                        int* __restrict__ fill)
{
    int i = blockIdx.x * 256 + threadIdx.x;
    if (i >= NNODES) return;
    int boff = (blockIdx.x == 0) ? 0 : bsum[blockIdx.x - 1];
    int start = boff + incl[i] - cnt[i];
    rowptr[i] = start;
    fill[i] = start;
    if (i == NNODES - 1) rowptr[NNODES] = boff + incl[i];
}

__global__ void k_scatter(const int* __restrict__ es, const int* __restrict__ ee,
                          int* __restrict__ fill, int* __restrict__ srcidx, int E)
{
    int e = blockIdx.x * 256 + threadIdx.x;
    if (e < E) {
        int pos = atomicAdd(&fill[ee[e]], 1);
        srcidx[pos] = es[e];
    }
}

// ---- Fused 4-GEMM pass over x [NNODES,64]:
//   A   = x@W0 + b0   (fp32; MODE 1 updates A in place — row-local, race-free)
//   gVe = x@W1 + b1   (bf16)
//   T   = bits(x@W2) | bits(x@W3)<<16   (interleaved Ui|Vj)
// Weights packed as bf16 quads in 32 KB LDS.
// MODE 0: x rows from concat(u,v), dtype per flag. MODE 1: x = relu(ab*A+ab').
template <int MODE>
__global__ __launch_bounds__(256) void k_mm4(
    const void* __restrict__ u, const void* __restrict__ v,
    const float* __restrict__ ab,
    const void* __restrict__ W0, const void* __restrict__ W1,
    const void* __restrict__ W2, const void* __restrict__ W3,
    const void* __restrict__ b0, const void* __restrict__ b1,
    const int* __restrict__ flag,
    float* A, bf16* __restrict__ gVe, unsigned* __restrict__ T)
{
    __shared__ uint2 Wq[DD][DD];   // 32 KB
    __shared__ float xs[4][DD];
    const int bf = flag[0];
    const int tid = threadIdx.x;
    for (int i = tid; i < DD * DD; i += 256) {
        unsigned w01 = (unsigned)fbits(ldf(W0, i, bf)) |
                       ((unsigned)fbits(ldf(W1, i, bf)) << 16);
        unsigned w23 = (unsigned)fbits(ldf(W2, i, bf)) |
                       ((unsigned)fbits(ldf(W3, i, bf)) << 16);
        Wq[i >> 6][i & 63] = make_uint2(w01, w23);
    }
    const int c = tid & 63, rg = tid >> 6;
    const float bias0 = ldf(b0, c, bf);
    const float bias1 = ldf(b1, c, bf);
    float a_c = 0.f, b_c = 0.f;
    if (MODE == 1) { a_c = ab[c]; b_c = ab[64 + c]; }
    __syncthreads();
    for (int base = blockIdx.x * 4; base < NNODES; base += gridDim.x * 4) {
        int row = base + rg;
        size_t o = (size_t)row * DD + c;
        if (row < NNODES) {
            float xv;
            if (MODE == 0) {
                xv = (row < NUSERS) ? ldf(u, (size_t)row * DD + c, bf)
                                    : ldf(v, (size_t)(row - NUSERS) * DD + c, bf);
            } else {
                float t = a_c * A[o] + b_c;
                xv = t > 0.f ? t : 0.f;
            }
            xs[rg][c] = xv;
        }
        __syncthreads();
        if (row < NNODES) {
            float s0 = bias0, s1 = bias1, s2 = 0.f, s3 = 0.f;
#pragma unroll
            for (int k = 0; k < DD; k++) {
                float xv = xs[rg][k];
                uint2 w = Wq[k][c];
                s0 += xv * lo_bf16(w.x);
                s1 += xv * hi_bf16(w.x);
                s2 += xv * lo_bf16(w.y);
                s3 += xv * hi_bf16(w.y);
            }
            A[o] = s0;
            gVe[o] = f2b(s1);
            T[o] = (unsigned)fbits(s2) | ((unsigned)fbits(s3) << 16);
        }
        __syncthreads();
    }
}

// ---- Gather-accumulate: one wave per dst node (round-4 geometry, no stats),
// fsig + x4 unroll. No barriers, no cross-block communication.
__global__ __launch_bounds__(256) void k_accum(
    const int* __restrict__ rowptr, const int* __restrict__ srcidx,
    const unsigned* __restrict__ T, const bf16* __restrict__ gVe,
    float* __restrict__ A)
{
    int d = blockIdx.x * 4 + (threadIdx.x >> 6);
    if (d >= NNODES) return;
    int c = threadIdx.x & 63;
    int r0 = rowptr[d], r1 = rowptr[d + 1];
    size_t o = (size_t)d * DD + c;
    float gv = b2f(gVe[o]);
    float sum = A[o];
    int i = r0;
    for (; i + 3 < r1; i += 4) {
        int s0 = srcidx[i], s1 = srcidx[i + 1];
        int s2 = srcidx[i + 2], s3 = srcidx[i + 3];
        unsigned t0 = T[(size_t)s0 * DD + c];
        unsigned t1 = T[(size_t)s1 * DD + c];
        unsigned t2 = T[(size_t)s2 * DD + c];
        unsigned t3 = T[(size_t)s3 * DD + c];
        sum += lo_bf16(t0) * fsig(gv + hi_bf16(t0));
        sum += lo_bf16(t1) * fsig(gv + hi_bf16(t1));
        sum += lo_bf16(t2) * fsig(gv + hi_bf16(t2));
        sum += lo_bf16(t3) * fsig(gv + hi_bf16(t3));
    }
    for (; i < r1; i++) {
        int s = srcidx[i];
        unsigned t = T[(size_t)s * DD + c];
        sum += lo_bf16(t) * fsig(gv + hi_bf16(t));
    }
    A[o] = sum;
}

// Column sums + sumsq over fp32 [NNODES,64] — exact round-4 version (proven).
__global__ __launch_bounds__(256) void k_reduce(
    const float* __restrict__ x, float* __restrict__ red)
{
    __shared__ float s1[256], s2[256];
    const int c = threadIdx.x & 63, rg = threadIdx.x >> 6;
    float sum = 0.f, sq = 0.f;
    for (int row = blockIdx.x * 4 + rg; row < NNODES; row += gridDim.x * 4) {
        float vv = x[(size_t)row * DD + c];
        sum += vv;
        sq += vv * vv;
    }
    s1[threadIdx.x] = sum;
    s2[threadIdx.x] = sq;
    __syncthreads();
    if (threadIdx.x < 64) {
        sum = s1[c] + s1[64 + c] + s1[128 + c] + s1[192 + c];
        sq = s2[c] + s2[64 + c] + s2[128 + c] + s2[192 + c];
        unsafeAtomicAdd(&red[c], sum);
        unsafeAtomicAdd(&red[64 + c], sq);
    }
}

__global__ void k_stats(const float* __restrict__ red,
                        const void* __restrict__ gamma,
                        const void* __restrict__ beta,
                        const int* __restrict__ flag,
                        float* __restrict__ ab)
{
    int c = threadIdx.x;  // 64 threads
    int bf = flag[0];
    float mean = red[c] * (1.f / NNODES);
    float var = red[64 + c] * (1.f / NNODES) - mean * mean;
    float rstd = rsqrtf(var + 1e-3f);
    float a = ldf(gamma, c, bf) * rstd;
    ab[c] = a;
    ab[64 + c] = ldf(beta, c, bf) - mean * a;
}

// out = relu(ab[c]*A + ab[64+c] + x_in@R), stored per flag dtype.
__global__ __launch_bounds__(256) void k_final(
    const float* __restrict__ A, const float* __restrict__ ab,
    const void* __restrict__ u, const void* __restrict__ v,
    const void* __restrict__ R, const int* __restrict__ flag,
    void* __restrict__ out)
{
    __shared__ float Rw[DD][DD];
    __shared__ float xs[4][DD];
    const int bf = flag[0];
    const int tid = threadIdx.x;
    for (int i = tid; i < DD * DD; i += 256)
        Rw[i >> 6][i & 63] = ldf(R, i, bf);
    const int c = tid & 63, rg = tid >> 6;
    const float a_c = ab[c], b_c = ab[64 + c];
    __syncthreads();
    for (int base = blockIdx.x * 4; base < NNODES; base += gridDim.x * 4) {
        int row = base + rg;
        size_t o = (size_t)row * DD + c;
        if (row < NNODES) {
            xs[rg][c] = (row < NUSERS) ? ldf(u, (size_t)row * DD + c, bf)
                                       : ldf(v, (size_t)(row - NUSERS) * DD + c, bf);
        }
        __syncthreads();
        if (row < NNODES) {
            float s = 0.f;
#pragma unroll
            for (int k = 0; k < DD; k++)
                s += xs[rg][k] * Rw[k][c];
            float vv = a_c * A[o] + b_c + s;
            vv = vv > 0.f ? vv : 0.f;
            if (bf) ((bf16*)out)[o] = f2b(vv);
            else    ((float*)out)[o] = vv;
        }
        __syncthreads();
    }
}

extern "C" void kernel_launch(void* const* d_in, const int* in_sizes, int n_in,
                              void* d_out, int out_size, void* d_ws, size_t ws_size,
                              hipStream_t stream)
{
    const void* u   = d_in[0];
    const void* v   = d_in[1];
    const int* es   = (const int*)d_in[2];
    const int* ee   = (const int*)d_in[3];
    const void* Ui1 = d_in[4];
    const void* Uj1 = d_in[5];
    const void* Vi1 = d_in[6];
    const void* Vj1 = d_in[7];
    const void* bu1 = d_in[8];
    const void* bv1 = d_in[9];
    const void* Ui2 = d_in[10];
    const void* Uj2 = d_in[11];
    const void* Vi2 = d_in[12];
    const void* Vj2 = d_in[13];
    const void* bu2 = d_in[14];
    const void* bv2 = d_in[15];
    const void* R   = d_in[16];
    const void* g1  = d_in[17];
    const void* be1 = d_in[18];
    const void* g2  = d_in[19];
    const void* be2 = d_in[20];
    const int E = in_sizes[2];

    // Workspace (~57 MB; layout identical to passing round 4). gVe in d_out.
    char* ws = (char*)d_ws;
    float* A      = (float*)(ws);                  // 25.6 MB fp32 accumulator
    unsigned* T   = (unsigned*)(ws + 25600000);    // 25.6 MB interleaved (Ui | Vj<<16)
    int* srcidx   = (int*)(ws + 51200000);         // 4 MB
    int* cnt      = (int*)(ws + 55200000);         // 400 KB
    int* incl     = (int*)(ws + 55600000);         // 400 KB
    int* rowptr   = (int*)(ws + 56000000);         // 400,004 B
    int* fill     = (int*)(ws + 56400128);         // 400 KB
    int* bsum     = (int*)(ws + 56800128);         // 2 KB
    float* red    = (float*)(ws + 56802176);       // red1[128] red2[128] ab1[128] ab2[128]
    int* flag     = (int*)(ws + 56804224);
    float* red1 = red, *red2 = red + 128, *ab1 = red + 256, *ab2 = red + 384;
    bf16* gVe = (bf16*)d_out;

    // ---- dtype sniff + CSR build ----
    k_sniff<<<1, 256, 0, stream>>>((const unsigned short*)u, flag, red);
    k_zeroi<<<NB, 256, 0, stream>>>(cnt, NNODES);
    k_hist<<<(E + 255) / 256, 256, 0, stream>>>(ee, cnt, E);
    k_scan1<<<NB, 256, 0, stream>>>(cnt, incl, bsum);
    k_scan2<<<1, 512, 0, stream>>>(bsum);
    k_scan3<<<NB, 256, 0, stream>>>(cnt, incl, bsum, rowptr, fill);
    k_scatter<<<(E + 255) / 256, 256, 0, stream>>>(es, ee, fill, srcidx, E);

    // ---- stage 1 ----
    k_mm4<0><<<1024, 256, 0, stream>>>(u, v, nullptr,
                                       Uj1, Vi1, Ui1, Vj1, bu1, bv1, flag,
                                       A, gVe, T);
    k_accum<<<(NNODES + 3) / 4, 256, 0, stream>>>(rowptr, srcidx, T, gVe, A);
    k_reduce<<<512, 256, 0, stream>>>(A, red1);
    k_stats<<<1, 64, 0, stream>>>(red1, g1, be1, flag, ab1);

    // ---- stage 2 (BN1+relu fused into row loads; A updated in place) ----
    k_mm4<1><<<1024, 256, 0, stream>>>(nullptr, nullptr, ab1,
                                       Uj2, Vi2, Ui2, Vj2, bu2, bv2, flag,
                                       A, gVe, T);
    k_accum<<<(NNODES + 3) / 4, 256, 0, stream>>>(rowptr, srcidx, T, gVe, A);
    k_reduce<<<512, 256, 0, stream>>>(A, red2);
    k_stats<<<1, 64, 0, stream>>>(red2, g2, be2, flag, ab2);

    // ---- BN2 + residual (x_in@R recomputed) + relu -> out ----
    k_final<<<1024, 256, 0, stream>>>(A, ab2, u, v, R, flag, d_out);
}

// Round 7
// 586.574 us; speedup vs baseline: 2.3033x; 1.1113x over previous
//
#include <hip/hip_runtime.h>
#include <hip/hip_bf16.h>

#define NUSERS 60000
#define NNODES 100000
#define DD 64
#define NB 391    // ceil(NNODES/256)
#define NGB 1563  // ceil(NNODES/64) — one 64-row tile per block

typedef __hip_bfloat16 bf16;
using bf16x8 = __attribute__((ext_vector_type(8))) short;
using f32x4  = __attribute__((ext_vector_type(4))) float;

__device__ __forceinline__ float b2f(bf16 x) { return __bfloat162float(x); }
__device__ __forceinline__ bf16 f2b(float x) { return __float2bfloat16(x); }
__device__ __forceinline__ unsigned short fbits(float x) {
    union { bf16 b; unsigned short u; } cv; cv.b = f2b(x); return cv.u;
}
__device__ __forceinline__ float lo_bf16(unsigned w) {
    union { unsigned u; float f; } t; t.u = w << 16; return t.f;
}
__device__ __forceinline__ float hi_bf16(unsigned w) {
    union { unsigned u; float f; } t; t.u = w & 0xFFFF0000u; return t.f;
}
__device__ __forceinline__ float ldf(const void* p, size_t i, int isbf) {
    if (isbf) return b2f(((const bf16*)p)[i]);
    return ((const float*)p)[i];
}
__device__ __forceinline__ float fsig(float g) {
    return __builtin_amdgcn_rcpf(1.f + __expf(-g));
}
__device__ __forceinline__ unsigned pack2(float a, float b) {
    return (unsigned)fbits(a) | ((unsigned)fbits(b) << 16);
}
__device__ __forceinline__ unsigned pr2(float x0, float x1, float a0, float a1,
                                        float b0, float b1) {
    float t0 = a0 * x0 + b0, t1 = a1 * x1 + b1;
    t0 = t0 > 0.f ? t0 : 0.f;
    t1 = t1 > 0.f ? t1 : 0.f;
    return pack2(t0, t1);
}

// Sniff dtype of u_features (bf16 vs fp32) + zero red[0:256].
__global__ void k_sniff(const unsigned short* __restrict__ h,
                        int* __restrict__ flag, float* __restrict__ red)
{
    __shared__ int cs[256];
    int t = threadIdx.x;
    int cnt = 0;
    for (int i = t; i < 1024; i += 256) {
        int e = (h[2 * i] >> 7) & 0xFF;
        cnt += (e >= 100 && e <= 140) ? 1 : 0;
    }
    cs[t] = cnt;
    __syncthreads();
    for (int s = 128; s > 0; s >>= 1) {
        if (t < s) cs[t] += cs[t + s];
        __syncthreads();
    }
    if (t == 0) flag[0] = (cs[0] > 512) ? 1 : 0;
    red[t] = 0.f;
}

__global__ void k_zeroi(int* __restrict__ p, int n) {
    int i = blockIdx.x * 256 + threadIdx.x;
    if (i < n) p[i] = 0;
}

// ---- CSR build (destination-sorted edges), once per launch ----
__global__ void k_hist(const int* __restrict__ ee, int* __restrict__ cnt, int E) {
    int e = blockIdx.x * 256 + threadIdx.x;
    if (e < E) atomicAdd(&cnt[ee[e]], 1);
}

__global__ void k_scan1(const int* __restrict__ cnt, int* __restrict__ incl,
                        int* __restrict__ bsum)
{
    __shared__ int sd[256];
    int i = blockIdx.x * 256 + threadIdx.x;
    int val = (i < NNODES) ? cnt[i] : 0;
    sd[threadIdx.x] = val;
    __syncthreads();
    for (int off = 1; off < 256; off <<= 1) {
        int t = (threadIdx.x >= off) ? sd[threadIdx.x - off] : 0;
        __syncthreads();
        sd[threadIdx.x] += t;
        __syncthreads();
    }
    if (i < NNODES) incl[i] = sd[threadIdx.x];
    if (threadIdx.x == 255) bsum[blockIdx.x] = sd[255];
}

__global__ void k_scan2(int* __restrict__ bsum) {  // inclusive scan, NB<=512
    __shared__ int sd[512];
    int t = threadIdx.x;
    sd[t] = (t < NB) ? bsum[t] : 0;
    __syncthreads();
    for (int off = 1; off < 512; off <<= 1) {
        int x = (t >= off) ? sd[t - off] : 0;
        __syncthreads();
        sd[t] += x;
        __syncthreads();
    }
    if (t < NB) bsum[t] = sd[t];
}

__global__ void k_scan3(const int* __restrict__ cnt, const int* __restrict__ incl,
                        const int* __restrict__ bsum, int* __restrict__ rowptr,
                        int* __restrict__ fill)
{
    int i = blockIdx.x * 256 + threadIdx.x;
    if (i >= NNODES) return;
    int boff = (blockIdx.x == 0) ? 0 : bsum[blockIdx.x - 1];
    int start = boff + incl[i] - cnt[i];
    rowptr[i] = start;
    fill[i] = start;
    if (i == NNODES - 1) rowptr[NNODES] = boff + incl[i];
}

__global__ void k_scatter(const int* __restrict__ es, const int* __restrict__ ee,
                          int* __restrict__ fill, int* __restrict__ srcidx, int E)
{
    int e = blockIdx.x * 256 + threadIdx.x;
    if (e < E) {
        int pos = atomicAdd(&fill[ee[e]], 1);
        srcidx[pos] = es[e];
    }
}

// Stage 64 rows of x into LDS as bf16 (padded stride 72).
// MODE 0: rows from concat(u,v), dtype per bfflag. MODE 1: relu(ab*A+ab').
template <int MODE>
__device__ __forceinline__ void stage_x(
    unsigned short (*xls)[72], int row0, int tid, int bfflag,
    const void* u, const void* v, const float* Aacc, const float* ab)
{
    int r = tid >> 2, c0 = (tid & 3) * 16;
    int row = row0 + r;
    int rowc = row < NNODES ? row : NNODES - 1;
    uint4 w0, w1;
    if (MODE == 0) {
        const void* src = (rowc < NUSERS) ? u : v;
        size_t off = (rowc < NUSERS) ? ((size_t)rowc * DD + c0)
                                     : ((size_t)(rowc - NUSERS) * DD + c0);
        if (bfflag) {
            const uint4* p = (const uint4*)((const unsigned short*)src + off);
            w0 = p[0];
            w1 = p[1];
        } else {
            const float4* p = (const float4*)((const float*)src + off);
            float4 f0 = p[0], f1 = p[1], f2 = p[2], f3 = p[3];
            w0 = make_uint4(pack2(f0.x, f0.y), pack2(f0.z, f0.w),
                            pack2(f1.x, f1.y), pack2(f1.z, f1.w));
            w1 = make_uint4(pack2(f2.x, f2.y), pack2(f2.z, f2.w),
                            pack2(f3.x, f3.y), pack2(f3.z, f3.w));
        }
    } else {
        const float4* p  = (const float4*)(Aacc + (size_t)rowc * DD + c0);
        const float4* pa = (const float4*)(ab + c0);
        const float4* pb = (const float4*)(ab + 64 + c0);
        float4 f0 = p[0], f1 = p[1], f2 = p[2], f3 = p[3];
        float4 a0 = pa[0], a1 = pa[1], a2 = pa[2], a3 = pa[3];
        float4 g0 = pb[0], g1 = pb[1], g2 = pb[2], g3 = pb[3];
        w0 = make_uint4(pr2(f0.x, f0.y, a0.x, a0.y, g0.x, g0.y),
                        pr2(f0.z, f0.w, a0.z, a0.w, g0.z, g0.w),
                        pr2(f1.x, f1.y, a1.x, a1.y, g1.x, g1.y),
                        pr2(f1.z, f1.w, a1.z, a1.w, g1.z, g1.w));
        w1 = make_uint4(pr2(f2.x, f2.y, a2.x, a2.y, g2.x, g2.y),
                        pr2(f2.z, f2.w, a2.z, a2.w, g2.z, g2.w),
                        pr2(f3.x, f3.y, a3.x, a3.y, g3.x, g3.y),
                        pr2(f3.z, f3.w, a3.z, a3.w, g3.z, g3.w));
    }
    *(uint4*)&xls[r][c0] = w0;
    *((uint4*)&xls[r][c0] + 1) = w1;
}

// ---- MFMA fused 4-GEMM: one 64-row tile per block; wave w = matrix w.
//   wave0: A = x@W0 + b0 (fp32)   wave1: gVe = x@W1 + b1 (bf16)
//   wave2: T.lo = x@W2            wave3: T.hi = x@W3   (disjoint u16 halves)
template <int MODE>
__global__ __launch_bounds__(256) void k_mm4_mfma(
    const void* __restrict__ u, const void* __restrict__ v,
    const float* __restrict__ ab,
    const void* __restrict__ W0, const void* __restrict__ W1,
    const void* __restrict__ W2, const void* __restrict__ W3,
    const void* __restrict__ b0, const void* __restrict__ b1,
    const int* __restrict__ flag,
    float* __restrict__ A, unsigned short* __restrict__ gVe,
    unsigned short* __restrict__ T2)
{
    __shared__ unsigned short Wls[4][DD][66];  // 33,792 B
    __shared__ unsigned short xls[DD][72];     //  9,216 B
    const int bfflag = flag[0];
    const int tid = threadIdx.x;
    for (int i = tid; i < DD * DD; i += 256) {
        int k = i >> 6, n = i & 63;
        Wls[0][k][n] = fbits(ldf(W0, i, bfflag));
        Wls[1][k][n] = fbits(ldf(W1, i, bfflag));
        Wls[2][k][n] = fbits(ldf(W2, i, bfflag));
        Wls[3][k][n] = fbits(ldf(W3, i, bfflag));
    }
    const int row0 = blockIdx.x * DD;
    stage_x<MODE>(xls, row0, tid, bfflag, u, v, A, ab);
    __syncthreads();

    const int wv = tid >> 6, lane = tid & 63;
    const int quad = lane >> 4, ln = lane & 15;
    // B-frags: B[k = ks*32+quad*8+j][n = nt*16+ln]  (m120-verified layout)
    bf16x8 bfr[2][4];
#pragma unroll
    for (int ks = 0; ks < 2; ks++)
#pragma unroll
        for (int nt = 0; nt < 4; nt++)
#pragma unroll
            for (int j = 0; j < 8; j++)
                bfr[ks][nt][j] = (short)Wls[wv][ks * 32 + quad * 8 + j][nt * 16 + ln];
    float bias[4];
#pragma unroll
    for (int nt = 0; nt < 4; nt++)
        bias[nt] = (wv == 0) ? ldf(b0, nt * 16 + ln, bfflag)
                 : (wv == 1) ? ldf(b1, nt * 16 + ln, bfflag) : 0.f;

#pragma unroll
    for (int rt = 0; rt < 4; rt++) {
        int m = rt * 16 + ln;  // A[m=lane&15][k=quad*8+j]
        bf16x8 af0 = *(const bf16x8*)&xls[m][quad * 8];
        bf16x8 af1 = *(const bf16x8*)&xls[m][32 + quad * 8];
#pragma unroll
        for (int nt = 0; nt < 4; nt++) {
            f32x4 c = {0.f, 0.f, 0.f, 0.f};
            c = __builtin_amdgcn_mfma_f32_16x16x32_bf16(af0, bfr[0][nt], c, 0, 0, 0);
            c = __builtin_amdgcn_mfma_f32_16x16x32_bf16(af1, bfr[1][nt], c, 0, 0, 0);
            int col = nt * 16 + ln;  // C/D: col=lane&15, row=quad*4+reg
#pragma unroll
            for (int r = 0; r < 4; r++) {
                int row = row0 + rt * 16 + quad * 4 + r;
                if (row < NNODES) {
                    size_t o = (size_t)row * DD + col;
                    if (wv == 0)      A[o] = c[r] + bias[nt];
                    else if (wv == 1) gVe[o] = fbits(c[r] + bias[nt]);
                    else if (wv == 2) T2[2 * o] = fbits(c[r]);
                    else              T2[2 * o + 1] = fbits(c[r]);
                }
            }
        }
    }
}

// ---- MFMA final: out = relu(ab*A + ab' + x_in@R); wave w = rowtile w.
__global__ __launch_bounds__(256) void k_final_mfma(
    const float* __restrict__ A, const float* __restrict__ ab,
    const void* __restrict__ u, const void* __restrict__ v,
    const void* __restrict__ R, const int* __restrict__ flag,
    void* __restrict__ out)
{
    __shared__ unsigned short Wls[DD][66];
    __shared__ unsigned short xls[DD][72];
    const int bfflag = flag[0];
    const int tid = threadIdx.x;
    for (int i = tid; i < DD * DD; i += 256)
        Wls[i >> 6][i & 63] = fbits(ldf(R, i, bfflag));
    const int row0 = blockIdx.x * DD;
    stage_x<0>(xls, row0, tid, bfflag, u, v, nullptr, nullptr);
    __syncthreads();

    const int wv = tid >> 6, lane = tid & 63;
    const int quad = lane >> 4, ln = lane & 15;
    bf16x8 bfr[2][4];
#pragma unroll
    for (int ks = 0; ks < 2; ks++)
#pragma unroll
        for (int nt = 0; nt < 4; nt++)
#pragma unroll
            for (int j = 0; j < 8; j++)
                bfr[ks][nt][j] = (short)Wls[ks * 32 + quad * 8 + j][nt * 16 + ln];
    float av[4], bv[4];
#pragma unroll
    for (int nt = 0; nt < 4; nt++) {
        av[nt] = ab[nt * 16 + ln];
        bv[nt] = ab[64 + nt * 16 + ln];
    }
    const int rt = wv;
    int m = rt * 16 + ln;
    bf16x8 af0 = *(const bf16x8*)&xls[m][quad * 8];
    bf16x8 af1 = *(const bf16x8*)&xls[m][32 + quad * 8];
#pragma unroll
    for (int nt = 0; nt < 4; nt++) {
        f32x4 c = {0.f, 0.f, 0.f, 0.f};
        c = __builtin_amdgcn_mfma_f32_16x16x32_bf16(af0, bfr[0][nt], c, 0, 0, 0);
        c = __builtin_amdgcn_mfma_f32_16x16x32_bf16(af1, bfr[1][nt], c, 0, 0, 0);
        int col = nt * 16 + ln;
#pragma unroll
        for (int r = 0; r < 4; r++) {
            int row = row0 + rt * 16 + quad * 4 + r;
            if (row < NNODES) {
                size_t o = (size_t)row * DD + col;
                float vv = av[nt] * A[o] + bv[nt] + c[r];
                vv = vv > 0.f ? vv : 0.f;
                if (bfflag) ((unsigned short*)out)[o] = fbits(vv);
                else        ((float*)out)[o] = vv;
            }
        }
    }
}

// ---- Gather-accumulate: one wave per dst node, fsig + x4 unroll ----
__global__ __launch_bounds__(256) void k_accum(
    const int* __restrict__ rowptr, const int* __restrict__ srcidx,
    const unsigned* __restrict__ T, const bf16* __restrict__ gVe,
    float* __restrict__ A)
{
    int d = blockIdx.x * 4 + (threadIdx.x >> 6);
    if (d >= NNODES) return;
    int c = threadIdx.x & 63;
    int r0 = rowptr[d], r1 = rowptr[d + 1];
    size_t o = (size_t)d * DD + c;
    float gv = b2f(gVe[o]);
    float sum = A[o];
    int i = r0;
    for (; i + 3 < r1; i += 4) {
        int s0 = srcidx[i], s1 = srcidx[i + 1];
        int s2 = srcidx[i + 2], s3 = srcidx[i + 3];
        unsigned t0 = T[(size_t)s0 * DD + c];
        unsigned t1 = T[(size_t)s1 * DD + c];
        unsigned t2 = T[(size_t)s2 * DD + c];
        unsigned t3 = T[(size_t)s3 * DD + c];
        sum += lo_bf16(t0) * fsig(gv + hi_bf16(t0));
        sum += lo_bf16(t1) * fsig(gv + hi_bf16(t1));
        sum += lo_bf16(t2) * fsig(gv + hi_bf16(t2));
        sum += lo_bf16(t3) * fsig(gv + hi_bf16(t3));
    }
    for (; i < r1; i++) {
        int s = srcidx[i];
        unsigned t = T[(size_t)s * DD + c];
        sum += lo_bf16(t) * fsig(gv + hi_bf16(t));
    }
    A[o] = sum;
}

// Column sums + sumsq over fp32 [NNODES,64]
__global__ __launch_bounds__(256) void k_reduce(
    const float* __restrict__ x, float* __restrict__ red)
{
    __shared__ float s1[256], s2[256];
    const int c = threadIdx.x & 63, rg = threadIdx.x >> 6;
    float sum = 0.f, sq = 0.f;
    for (int row = blockIdx.x * 4 + rg; row < NNODES; row += gridDim.x * 4) {
        float vv = x[(size_t)row * DD + c];
        sum += vv;
        sq += vv * vv;
    }
    s1[threadIdx.x] = sum;
    s2[threadIdx.x] = sq;
    __syncthreads();
    if (threadIdx.x < 64) {
        sum = s1[c] + s1[64 + c] + s1[128 + c] + s1[192 + c];
        sq = s2[c] + s2[64 + c] + s2[128 + c] + s2[192 + c];
        unsafeAtomicAdd(&red[c], sum);
        unsafeAtomicAdd(&red[64 + c], sq);
    }
}

__global__ void k_stats(const float* __restrict__ red,
                        const void* __restrict__ gamma,
                        const void* __restrict__ beta,
                        const int* __restrict__ flag,
                        float* __restrict__ ab)
{
    int c = threadIdx.x;  // 64 threads
    int bf = flag[0];
    float mean = red[c] * (1.f / NNODES);
    float var = red[64 + c] * (1.f / NNODES) - mean * mean;
    float rstd = rsqrtf(var + 1e-3f);
    float a = ldf(gamma, c, bf) * rstd;
    ab[c] = a;
    ab[64 + c] = ldf(beta, c, bf) - mean * a;
}

extern "C" void kernel_launch(void* const* d_in, const int* in_sizes, int n_in,
                              void* d_out, int out_size, void* d_ws, size_t ws_size,
                              hipStream_t stream)
{
    const void* u   = d_in[0];
    const void* v   = d_in[1];
    const int* es   = (const int*)d_in[2];
    const int* ee   = (const int*)d_in[3];
    const void* Ui1 = d_in[4];
    const void* Uj1 = d_in[5];
    const void* Vi1 = d_in[6];
    const void* Vj1 = d_in[7];
    const void* bu1 = d_in[8];
    const void* bv1 = d_in[9];
    const void* Ui2 = d_in[10];
    const void* Uj2 = d_in[11];
    const void* Vi2 = d_in[12];
    const void* Vj2 = d_in[13];
    const void* bu2 = d_in[14];
    const void* bv2 = d_in[15];
    const void* R   = d_in[16];
    const void* g1  = d_in[17];
    const void* be1 = d_in[18];
    const void* g2  = d_in[19];
    const void* be2 = d_in[20];
    const int E = in_sizes[2];

    // Workspace (~57 MB; layout identical to passing rounds 4/6). gVe in d_out.
    char* ws = (char*)d_ws;
    float* A      = (float*)(ws);                  // 25.6 MB fp32 accumulator
    unsigned* T   = (unsigned*)(ws + 25600000);    // 25.6 MB interleaved (Ui | Vj<<16)
    int* srcidx   = (int*)(ws + 51200000);         // 4 MB
    int* cnt      = (int*)(ws + 55200000);         // 400 KB
    int* incl     = (int*)(ws + 55600000);         // 400 KB
    int* rowptr   = (int*)(ws + 56000000);         // 400,004 B
    int* fill     = (int*)(ws + 56400128);         // 400 KB
    int* bsum     = (int*)(ws + 56800128);         // 2 KB
    float* red    = (float*)(ws + 56802176);       // red1[128] red2[128] ab1[128] ab2[128]
    int* flag     = (int*)(ws + 56804224);
    float* red1 = red, *red2 = red + 128, *ab1 = red + 256, *ab2 = red + 384;
    bf16* gVe = (bf16*)d_out;

    // ---- dtype sniff + CSR build ----
    k_sniff<<<1, 256, 0, stream>>>((const unsigned short*)u, flag, red);
    k_zeroi<<<NB, 256, 0, stream>>>(cnt, NNODES);
    k_hist<<<(E + 255) / 256, 256, 0, stream>>>(ee, cnt, E);
    k_scan1<<<NB, 256, 0, stream>>>(cnt, incl, bsum);
    k_scan2<<<1, 512, 0, stream>>>(bsum);
    k_scan3<<<NB, 256, 0, stream>>>(cnt, incl, bsum, rowptr, fill);
    k_scatter<<<(E + 255) / 256, 256, 0, stream>>>(es, ee, fill, srcidx, E);

    // ---- stage 1 ----
    k_mm4_mfma<0><<<NGB, 256, 0, stream>>>(u, v, nullptr,
                                           Uj1, Vi1, Ui1, Vj1, bu1, bv1, flag,
                                           A, (unsigned short*)gVe,
                                           (unsigned short*)T);
    k_accum<<<(NNODES + 3) / 4, 256, 0, stream>>>(rowptr, srcidx, T, gVe, A);
    k_reduce<<<512, 256, 0, stream>>>(A, red1);
    k_stats<<<1, 64, 0, stream>>>(red1, g1, be1, flag, ab1);

    // ---- stage 2 (BN1+relu fused into staging; A updated in place) ----
    k_mm4_mfma<1><<<NGB, 256, 0, stream>>>(nullptr, nullptr, ab1,
                                           Uj2, Vi2, Ui2, Vj2, bu2, bv2, flag,
                                           A, (unsigned short*)gVe,
                                           (unsigned short*)T);
    k_accum<<<(NNODES + 3) / 4, 256, 0, stream>>>(rowptr, srcidx, T, gVe, A);
    k_reduce<<<512, 256, 0, stream>>>(A, red2);
    k_stats<<<1, 64, 0, stream>>>(red2, g2, be2, flag, ab2);

    // ---- BN2 + residual (x_in@R via MFMA) + relu -> out ----
    k_final_mfma<<<NGB, 256, 0, stream>>>(A, ab2, u, v, R, flag, d_out);
}

// Round 8
// 516.177 us; speedup vs baseline: 2.6174x; 1.1364x over previous
//
#include <hip/hip_runtime.h>
#include <hip/hip_bf16.h>

#define NUSERS 60000
#define NNODES 100000
#define DD 64
#define NB 391    // ceil(NNODES/256)
#define NGB 1563  // ceil(NNODES/64) — 64-row tiles
#define GMM 782   // k_mm4 grid: 2 tiles/block, ~3 blocks/CU (LDS cap)

typedef __hip_bfloat16 bf16;
using bf16x8 = __attribute__((ext_vector_type(8))) short;
using f32x4  = __attribute__((ext_vector_type(4))) float;

__device__ __forceinline__ float b2f(bf16 x) { return __bfloat162float(x); }
__device__ __forceinline__ bf16 f2b(float x) { return __float2bfloat16(x); }
__device__ __forceinline__ unsigned short fbits(float x) {
    union { bf16 b; unsigned short u; } cv; cv.b = f2b(x); return cv.u;
}
__device__ __forceinline__ float lo_bf16(unsigned w) {
    union { unsigned u; float f; } t; t.u = w << 16; return t.f;
}
__device__ __forceinline__ float hi_bf16(unsigned w) {
    union { unsigned u; float f; } t; t.u = w & 0xFFFF0000u; return t.f;
}
__device__ __forceinline__ float ldf(const void* p, size_t i, int isbf) {
    if (isbf) return b2f(((const bf16*)p)[i]);
    return ((const float*)p)[i];
}
__device__ __forceinline__ float fsig(float g) {
    return __builtin_amdgcn_rcpf(1.f + __expf(-g));
}
__device__ __forceinline__ unsigned pack2(float a, float b) {
    return (unsigned)fbits(a) | ((unsigned)fbits(b) << 16);
}
__device__ __forceinline__ unsigned pr2(float x0, float x1, float a0, float a1,
                                        float b0, float b1) {
    float t0 = a0 * x0 + b0, t1 = a1 * x1 + b1;
    t0 = t0 > 0.f ? t0 : 0.f;
    t1 = t1 > 0.f ? t1 : 0.f;
    return pack2(t0, t1);
}

// Sniff dtype of u_features (bf16 vs fp32) + zero red[0:256].
__global__ void k_sniff(const unsigned short* __restrict__ h,
                        int* __restrict__ flag, float* __restrict__ red)
{
    __shared__ int cs[256];
    int t = threadIdx.x;
    int cnt = 0;
    for (int i = t; i < 1024; i += 256) {
        int e = (h[2 * i] >> 7) & 0xFF;
        cnt += (e >= 100 && e <= 140) ? 1 : 0;
    }
    cs[t] = cnt;
    __syncthreads();
    for (int s = 128; s > 0; s >>= 1) {
        if (t < s) cs[t] += cs[t + s];
        __syncthreads();
    }
    if (t == 0) flag[0] = (cs[0] > 512) ? 1 : 0;
    red[t] = 0.f;
}

__global__ void k_zeroi(int* __restrict__ p, int n) {
    int i = blockIdx.x * 256 + threadIdx.x;
    if (i < n) p[i] = 0;
}

// ---- CSR build (destination-sorted edges), once per launch ----
__global__ void k_hist(const int* __restrict__ ee, int* __restrict__ cnt, int E) {
    int e = blockIdx.x * 256 + threadIdx.x;
    if (e < E) atomicAdd(&cnt[ee[e]], 1);
}

__global__ void k_scan1(const int* __restrict__ cnt, int* __restrict__ incl,
                        int* __restrict__ bsum)
{
    __shared__ int sd[256];
    int i = blockIdx.x * 256 + threadIdx.x;
    int val = (i < NNODES) ? cnt[i] : 0;
    sd[threadIdx.x] = val;
    __syncthreads();
    for (int off = 1; off < 256; off <<= 1) {
        int t = (threadIdx.x >= off) ? sd[threadIdx.x - off] : 0;
        __syncthreads();
        sd[threadIdx.x] += t;
        __syncthreads();
    }
    if (i < NNODES) incl[i] = sd[threadIdx.x];
    if (threadIdx.x == 255) bsum[blockIdx.x] = sd[255];
}

__global__ void k_scan2(int* __restrict__ bsum) {  // inclusive scan, NB<=512
    __shared__ int sd[512];
    int t = threadIdx.x;
    sd[t] = (t < NB) ? bsum[t] : 0;
    __syncthreads();
    for (int off = 1; off < 512; off <<= 1) {
        int x = (t >= off) ? sd[t - off] : 0;
        __syncthreads();
        sd[t] += x;
        __syncthreads();
    }
    if (t < NB) bsum[t] = sd[t];
}

__global__ void k_scan3(const int* __restrict__ cnt, const int* __restrict__ incl,
                        const int* __restrict__ bsum, int* __restrict__ rowptr,
                        int* __restrict__ fill)
{
    int i = blockIdx.x * 256 + threadIdx.x;
    if (i >= NNODES) return;
    int boff = (blockIdx.x == 0) ? 0 : bsum[blockIdx.x - 1];
    int start = boff + incl[i] - cnt[i];
    rowptr[i] = start;
    fill[i] = start;
    if (i == NNODES - 1) rowptr[NNODES] = boff + incl[i];
}

__global__ void k_scatter(const int* __restrict__ es, const int* __restrict__ ee,
                          int* __restrict__ fill, int* __restrict__ srcidx, int E)
{
    int e = blockIdx.x * 256 + threadIdx.x;
    if (e < E) {
        int pos = atomicAdd(&fill[ee[e]], 1);
        srcidx[pos] = es[e];
    }
}

// Stage 64 rows of x into LDS as bf16 (padded stride 72).
// MODE 0: rows from concat(u,v), dtype per bfflag. MODE 1: relu(ab*A+ab').
template <int MODE>
__device__ __forceinline__ void stage_x(
    unsigned short (*xls)[72], int row0, int tid, int bfflag,
    const void* u, const void* v, const float* Aacc, const float* ab)
{
    int r = tid >> 2, c0 = (tid & 3) * 16;
    int row = row0 + r;
    int rowc = row < NNODES ? row : NNODES - 1;
    uint4 w0, w1;
    if (MODE == 0) {
        const void* src = (rowc < NUSERS) ? u : v;
        size_t off = (rowc < NUSERS) ? ((size_t)rowc * DD + c0)
                                     : ((size_t)(rowc - NUSERS) * DD + c0);
        if (bfflag) {
            const uint4* p = (const uint4*)((const unsigned short*)src + off);
            w0 = p[0];
            w1 = p[1];
        } else {
            const float4* p = (const float4*)((const float*)src + off);
            float4 f0 = p[0], f1 = p[1], f2 = p[2], f3 = p[3];
            w0 = make_uint4(pack2(f0.x, f0.y), pack2(f0.z, f0.w),
                            pack2(f1.x, f1.y), pack2(f1.z, f1.w));
            w1 = make_uint4(pack2(f2.x, f2.y), pack2(f2.z, f2.w),
                            pack2(f3.x, f3.y), pack2(f3.z, f3.w));
        }
    } else {
        const float4* p  = (const float4*)(Aacc + (size_t)rowc * DD + c0);
        const float4* pa = (const float4*)(ab + c0);
        const float4* pb = (const float4*)(ab + 64 + c0);
        float4 f0 = p[0], f1 = p[1], f2 = p[2], f3 = p[3];
        float4 a0 = pa[0], a1 = pa[1], a2 = pa[2], a3 = pa[3];
        float4 g0 = pb[0], g1 = pb[1], g2 = pb[2], g3 = pb[3];
        w0 = make_uint4(pr2(f0.x, f0.y, a0.x, a0.y, g0.x, g0.y),
                        pr2(f0.z, f0.w, a0.z, a0.w, g0.z, g0.w),
                        pr2(f1.x, f1.y, a1.x, a1.y, g1.x, g1.y),
                        pr2(f1.z, f1.w, a1.z, a1.w, g1.z, g1.w));
        w1 = make_uint4(pr2(f2.x, f2.y, a2.x, a2.y, g2.x, g2.y),
                        pr2(f2.z, f2.w, a2.z, a2.w, g2.z, g2.w),
                        pr2(f3.x, f3.y, a3.x, a3.y, g3.x, g3.y),
                        pr2(f3.z, f3.w, a3.z, a3.w, g3.z, g3.w));
    }
    *(uint4*)&xls[r][c0] = w0;
    *((uint4*)&xls[r][c0] + 1) = w1;
}

// ---- MFMA fused 4-GEMM, tile-looped: wave w = matrix w.
//   wave0: A = x@W0 + b0 (fp32)   wave1: gVe = x@W1 + b1 (bf16)
//   wave2: T.lo = x@W2            wave3: T.hi = x@W3   (disjoint u16 halves)
template <int MODE>
__global__ __launch_bounds__(256) void k_mm4_mfma(
    const void* __restrict__ u, const void* __restrict__ v,
    const float* __restrict__ ab,
    const void* __restrict__ W0, const void* __restrict__ W1,
    const void* __restrict__ W2, const void* __restrict__ W3,
    const void* __restrict__ b0, const void* __restrict__ b1,
    const int* __restrict__ flag,
    float* __restrict__ A, unsigned short* __restrict__ gVe,
    unsigned short* __restrict__ T2)
{
    __shared__ unsigned short Wls[4][DD][72];  // 36,864 B (stride 72: b128-aligned)
    __shared__ unsigned short xls[DD][72];     //  9,216 B
    const int bfflag = flag[0];
    const int tid = threadIdx.x;
    const void* Wm[4] = {W0, W1, W2, W3};
    if (bfflag) {
        // 4 matrices x 512 uint4 (8 bf16 each) = 2048 loads, 8 per thread
        for (int i = tid; i < 2048; i += 256) {
            int m = i >> 9;
            int e0 = (i & 511) * 8;
            uint4 w = ((const uint4*)Wm[m])[i & 511];
            *(uint4*)&Wls[m][e0 >> 6][e0 & 63] = w;
        }
    } else {
        // 4 matrices x 1024 float4 (4 f32 each) = 4096 loads, 16 per thread
        for (int i = tid; i < 4096; i += 256) {
            int m = i >> 10;
            int e0 = (i & 1023) * 4;
            float4 f = ((const float4*)Wm[m])[i & 1023];
            *(uint2*)&Wls[m][e0 >> 6][e0 & 63] =
                make_uint2(pack2(f.x, f.y), pack2(f.z, f.w));
        }
    }
    __syncthreads();

    const int wv = tid >> 6, lane = tid & 63;
    const int quad = lane >> 4, ln = lane & 15;
    // B-frags: B[k = ks*32+quad*8+j][n = nt*16+ln]
    bf16x8 bfr[2][4];
#pragma unroll
    for (int ks = 0; ks < 2; ks++)
#pragma unroll
        for (int nt = 0; nt < 4; nt++)
#pragma unroll
            for (int j = 0; j < 8; j++)
                bfr[ks][nt][j] = (short)Wls[wv][ks * 32 + quad * 8 + j][nt * 16 + ln];
    float bias[4];
#pragma unroll
    for (int nt = 0; nt < 4; nt++)
        bias[nt] = (wv == 0) ? ldf(b0, nt * 16 + ln, bfflag)
                 : (wv == 1) ? ldf(b1, nt * 16 + ln, bfflag) : 0.f;

    for (int t = blockIdx.x; t < NGB; t += gridDim.x) {
        const int row0 = t * DD;
        stage_x<MODE>(xls, row0, tid, bfflag, u, v, A, ab);
        __syncthreads();
#pragma unroll
        for (int rt = 0; rt < 4; rt++) {
            int m = rt * 16 + ln;  // A[m=lane&15][k=quad*8+j]
            bf16x8 af0 = *(const bf16x8*)&xls[m][quad * 8];
            bf16x8 af1 = *(const bf16x8*)&xls[m][32 + quad * 8];
#pragma unroll
            for (int nt = 0; nt < 4; nt++) {
                f32x4 c = {0.f, 0.f, 0.f, 0.f};
                c = __builtin_amdgcn_mfma_f32_16x16x32_bf16(af0, bfr[0][nt], c, 0, 0, 0);
                c = __builtin_amdgcn_mfma_f32_16x16x32_bf16(af1, bfr[1][nt], c, 0, 0, 0);
                int col = nt * 16 + ln;  // C/D: col=lane&15, row=quad*4+reg
#pragma unroll
                for (int r = 0; r < 4; r++) {
                    int row = row0 + rt * 16 + quad * 4 + r;
                    if (row < NNODES) {
                        size_t o = (size_t)row * DD + col;
                        if (wv == 0)      A[o] = c[r] + bias[nt];
                        else if (wv == 1) gVe[o] = fbits(c[r] + bias[nt]);
                        else if (wv == 2) T2[2 * o] = fbits(c[r]);
                        else              T2[2 * o + 1] = fbits(c[r]);
                    }
                }
            }
        }
        __syncthreads();  // xls reused next tile
    }
}

// ---- MFMA final: out = relu(ab*A + ab' + x_in@R); wave w = rowtile w.
__global__ __launch_bounds__(256) void k_final_mfma(
    const float* __restrict__ A, const float* __restrict__ ab,
    const void* __restrict__ u, const void* __restrict__ v,
    const void* __restrict__ R, const int* __restrict__ flag,
    void* __restrict__ out)
{
    __shared__ unsigned short Wls[DD][72];
    __shared__ unsigned short xls[DD][72];
    const int bfflag = flag[0];
    const int tid = threadIdx.x;
    if (bfflag) {
        for (int i = tid; i < 512; i += 256) {
            int e0 = i * 8;
            *(uint4*)&Wls[e0 >> 6][e0 & 63] = ((const uint4*)R)[i];
        }
    } else {
        for (int i = tid; i < 1024; i += 256) {
            int e0 = i * 4;
            float4 f = ((const float4*)R)[i];
            *(uint2*)&Wls[e0 >> 6][e0 & 63] =
                make_uint2(pack2(f.x, f.y), pack2(f.z, f.w));
        }
    }
    const int row0 = blockIdx.x * DD;
    stage_x<0>(xls, row0, tid, bfflag, u, v, nullptr, nullptr);
    __syncthreads();

    const int wv = tid >> 6, lane = tid & 63;
    const int quad = lane >> 4, ln = lane & 15;
    bf16x8 bfr[2][4];
#pragma unroll
    for (int ks = 0; ks < 2; ks++)
#pragma unroll
        for (int nt = 0; nt < 4; nt++)
#pragma unroll
            for (int j = 0; j < 8; j++)
                bfr[ks][nt][j] = (short)Wls[ks * 32 + quad * 8 + j][nt * 16 + ln];
    float av[4], bv[4];
#pragma unroll
    for (int nt = 0; nt < 4; nt++) {
        av[nt] = ab[nt * 16 + ln];
        bv[nt] = ab[64 + nt * 16 + ln];
    }
    const int rt = wv;
    int m = rt * 16 + ln;
    bf16x8 af0 = *(const bf16x8*)&xls[m][quad * 8];
    bf16x8 af1 = *(const bf16x8*)&xls[m][32 + quad * 8];
#pragma unroll
    for (int nt = 0; nt < 4; nt++) {
        f32x4 c = {0.f, 0.f, 0.f, 0.f};
        c = __builtin_amdgcn_mfma_f32_16x16x32_bf16(af0, bfr[0][nt], c, 0, 0, 0);
        c = __builtin_amdgcn_mfma_f32_16x16x32_bf16(af1, bfr[1][nt], c, 0, 0, 0);
        int col = nt * 16 + ln;
#pragma unroll
        for (int r = 0; r < 4; r++) {
            int row = row0 + rt * 16 + quad * 4 + r;
            if (row < NNODES) {
                size_t o = (size_t)row * DD + col;
                float vv = av[nt] * A[o] + bv[nt] + c[r];
                vv = vv > 0.f ? vv : 0.f;
                if (bfflag) ((unsigned short*)out)[o] = fbits(vv);
                else        ((float*)out)[o] = vv;
            }
        }
    }
}

// ---- Gather-accumulate: one wave per dst node, fsig + x4 unroll ----
__global__ __launch_bounds__(256) void k_accum(
    const int* __restrict__ rowptr, const int* __restrict__ srcidx,
    const unsigned* __restrict__ T, const bf16* __restrict__ gVe,
    float* __restrict__ A)
{
    int d = blockIdx.x * 4 + (threadIdx.x >> 6);
    if (d >= NNODES) return;
    int c = threadIdx.x & 63;
    int r0 = rowptr[d], r1 = rowptr[d + 1];
    size_t o = (size_t)d * DD + c;
    float gv = b2f(gVe[o]);
    float sum = A[o];
    int i = r0;
    for (; i + 3 < r1; i += 4) {
        int s0 = srcidx[i], s1 = srcidx[i + 1];
        int s2 = srcidx[i + 2], s3 = srcidx[i + 3];
        unsigned t0 = T[(size_t)s0 * DD + c];
        unsigned t1 = T[(size_t)s1 * DD + c];
        unsigned t2 = T[(size_t)s2 * DD + c];
        unsigned t3 = T[(size_t)s3 * DD + c];
        sum += lo_bf16(t0) * fsig(gv + hi_bf16(t0));
        sum += lo_bf16(t1) * fsig(gv + hi_bf16(t1));
        sum += lo_bf16(t2) * fsig(gv + hi_bf16(t2));
        sum += lo_bf16(t3) * fsig(gv + hi_bf16(t3));
    }
    for (; i < r1; i++) {
        int s = srcidx[i];
        unsigned t = T[(size_t)s * DD + c];
        sum += lo_bf16(t) * fsig(gv + hi_bf16(t));
    }
    A[o] = sum;
}

// Column sums + sumsq over fp32 [NNODES,64]
__global__ __launch_bounds__(256) void k_reduce(
    const float* __restrict__ x, float* __restrict__ red)
{
    __shared__ float s1[256], s2[256];
    const int c = threadIdx.x & 63, rg = threadIdx.x >> 6;
    float sum = 0.f, sq = 0.f;
    for (int row = blockIdx.x * 4 + rg; row < NNODES; row += gridDim.x * 4) {
        float vv = x[(size_t)row * DD + c];
        sum += vv;
        sq += vv * vv;
    }
    s1[threadIdx.x] = sum;
    s2[threadIdx.x] = sq;
    __syncthreads();
    if (threadIdx.x < 64) {
        sum = s1[c] + s1[64 + c] + s1[128 + c] + s1[192 + c];
        sq = s2[c] + s2[64 + c] + s2[128 + c] + s2[192 + c];
        unsafeAtomicAdd(&red[c], sum);
        unsafeAtomicAdd(&red[64 + c], sq);
    }
}

__global__ void k_stats(const float* __restrict__ red,
                        const void* __restrict__ gamma,
                        const void* __restrict__ beta,
                        const int* __restrict__ flag,
                        float* __restrict__ ab)
{
    int c = threadIdx.x;  // 64 threads
    int bf = flag[0];
    float mean = red[c] * (1.f / NNODES);
    float var = red[64 + c] * (1.f / NNODES) - mean * mean;
    float rstd = rsqrtf(var + 1e-3f);
    float a = ldf(gamma, c, bf) * rstd;
    ab[c] = a;
    ab[64 + c] = ldf(beta, c, bf) - mean * a;
}

extern "C" void kernel_launch(void* const* d_in, const int* in_sizes, int n_in,
                              void* d_out, int out_size, void* d_ws, size_t ws_size,
                              hipStream_t stream)
{
    const void* u   = d_in[0];
    const void* v   = d_in[1];
    const int* es   = (const int*)d_in[2];
    const int* ee   = (const int*)d_in[3];
    const void* Ui1 = d_in[4];
    const void* Uj1 = d_in[5];
    const void* Vi1 = d_in[6];
    const void* Vj1 = d_in[7];
    const void* bu1 = d_in[8];
    const void* bv1 = d_in[9];
    const void* Ui2 = d_in[10];
    const void* Uj2 = d_in[11];
    const void* Vi2 = d_in[12];
    const void* Vj2 = d_in[13];
    const void* bu2 = d_in[14];
    const void* bv2 = d_in[15];
    const void* R   = d_in[16];
    const void* g1  = d_in[17];
    const void* be1 = d_in[18];
    const void* g2  = d_in[19];
    const void* be2 = d_in[20];
    const int E = in_sizes[2];

    // Workspace (~57 MB; proven layout). gVe in d_out until k_final overwrites.
    char* ws = (char*)d_ws;
    float* A      = (float*)(ws);                  // 25.6 MB fp32 accumulator
    unsigned* T   = (unsigned*)(ws + 25600000);    // 25.6 MB interleaved (Ui | Vj<<16)
    int* srcidx   = (int*)(ws + 51200000);         // 4 MB
    int* cnt      = (int*)(ws + 55200000);         // 400 KB
    int* incl     = (int*)(ws + 55600000);         // 400 KB
    int* rowptr   = (int*)(ws + 56000000);         // 400,004 B
    int* fill     = (int*)(ws + 56400128);         // 400 KB
    int* bsum     = (int*)(ws + 56800128);         // 2 KB
    float* red    = (float*)(ws + 56802176);       // red1[128] red2[128] ab1[128] ab2[128]
    int* flag     = (int*)(ws + 56804224);
    float* red1 = red, *red2 = red + 128, *ab1 = red + 256, *ab2 = red + 384;
    bf16* gVe = (bf16*)d_out;

    // ---- dtype sniff + CSR build ----
    k_sniff<<<1, 256, 0, stream>>>((const unsigned short*)u, flag, red);
    k_zeroi<<<NB, 256, 0, stream>>>(cnt, NNODES);
    k_hist<<<(E + 255) / 256, 256, 0, stream>>>(ee, cnt, E);
    k_scan1<<<NB, 256, 0, stream>>>(cnt, incl, bsum);
    k_scan2<<<1, 512, 0, stream>>>(bsum);
    k_scan3<<<NB, 256, 0, stream>>>(cnt, incl, bsum, rowptr, fill);
    k_scatter<<<(E + 255) / 256, 256, 0, stream>>>(es, ee, fill, srcidx, E);

    // ---- stage 1 ----
    k_mm4_mfma<0><<<GMM, 256, 0, stream>>>(u, v, nullptr,
                                           Uj1, Vi1, Ui1, Vj1, bu1, bv1, flag,
                                           A, (unsigned short*)gVe,
                                           (unsigned short*)T);
    k_accum<<<(NNODES + 3) / 4, 256, 0, stream>>>(rowptr, srcidx, T, gVe, A);
    k_reduce<<<512, 256, 0, stream>>>(A, red1);
    k_stats<<<1, 64, 0, stream>>>(red1, g1, be1, flag, ab1);

    // ---- stage 2 (BN1+relu fused into staging; A updated in place) ----
    k_mm4_mfma<1><<<GMM, 256, 0, stream>>>(nullptr, nullptr, ab1,
                                           Uj2, Vi2, Ui2, Vj2, bu2, bv2, flag,
                                           A, (unsigned short*)gVe,
                                           (unsigned short*)T);
    k_accum<<<(NNODES + 3) / 4, 256, 0, stream>>>(rowptr, srcidx, T, gVe, A);
    k_reduce<<<512, 256, 0, stream>>>(A, red2);
    k_stats<<<1, 64, 0, stream>>>(red2, g2, be2, flag, ab2);

    // ---- BN2 + residual (x_in@R via MFMA) + relu -> out ----
    k_final_mfma<<<NGB, 256, 0, stream>>>(A, ab2, u, v, R, flag, d_out);
}

// Round 10
// 463.139 us; speedup vs baseline: 2.9172x; 1.1145x over previous
//
#include <hip/hip_runtime.h>
#include <hip/hip_bf16.h>

#define NUSERS 60000
#define NNODES 100000
#define DD 64
#define NGB 1563  // ceil(NNODES/64) — 64-row tiles
#define GMM 782   // k_mm4 grid: 2 tiles/block, ~3 blocks/CU (LDS cap)
#define NBUK 196  // ceil(NNODES/512) coarse buckets (dst>>9)
#define ESB 2048  // edges per k_bscatter block

typedef __hip_bfloat16 bf16;
using bf16x8 = __attribute__((ext_vector_type(8))) short;
using f32x4  = __attribute__((ext_vector_type(4))) float;

__device__ __forceinline__ float b2f(bf16 x) { return __bfloat162float(x); }
__device__ __forceinline__ bf16 f2b(float x) { return __float2bfloat16(x); }
__device__ __forceinline__ unsigned short fbits(float x) {
    union { bf16 b; unsigned short u; } cv; cv.b = f2b(x); return cv.u;
}
__device__ __forceinline__ float lo_bf16(unsigned w) {
    union { unsigned u; float f; } t; t.u = w << 16; return t.f;
}
__device__ __forceinline__ float hi_bf16(unsigned w) {
    union { unsigned u; float f; } t; t.u = w & 0xFFFF0000u; return t.f;
}
__device__ __forceinline__ float ldf(const void* p, size_t i, int isbf) {
    if (isbf) return b2f(((const bf16*)p)[i]);
    return ((const float*)p)[i];
}
__device__ __forceinline__ float fsig(float g) {
    return __builtin_amdgcn_rcpf(1.f + __expf(-g));
}
__device__ __forceinline__ unsigned pack2(float a, float b) {
    return (unsigned)fbits(a) | ((unsigned)fbits(b) << 16);
}
__device__ __forceinline__ unsigned pr2(float x0, float x1, float a0, float a1,
                                        float b0, float b1) {
    float t0 = a0 * x0 + b0, t1 = a1 * x1 + b1;
    t0 = t0 > 0.f ? t0 : 0.f;
    t1 = t1 > 0.f ? t1 : 0.f;
    return pack2(t0, t1);
}

// Sniff dtype of u_features (bf16 vs fp32) + zero red[0:256] and btot[0:256].
__global__ void k_sniff(const unsigned short* __restrict__ h,
                        int* __restrict__ flag, float* __restrict__ red,
                        int* __restrict__ btot)
{
    __shared__ int cs[256];
    int t = threadIdx.x;
    int cnt = 0;
    for (int i = t; i < 1024; i += 256) {
        int e = (h[2 * i] >> 7) & 0xFF;
        cnt += (e >= 100 && e <= 140) ? 1 : 0;
    }
    cs[t] = cnt;
    __syncthreads();
    for (int s = 128; s > 0; s >>= 1) {
        if (t < s) cs[t] += cs[t + s];
        __syncthreads();
    }
    if (t == 0) flag[0] = (cs[0] > 512) ? 1 : 0;
    red[t] = 0.f;
    btot[t] = 0;
}

// ---- Bucketed CSR build (dst-sorted edges), once per launch ----
// B1: coarse bucket histogram (bucket = dst>>9), LDS-aggregated.
__global__ __launch_bounds__(256) void k_bhist(const int* __restrict__ ee,
                                               int* __restrict__ btot, int E)
{
    __shared__ int h[256];
    int t = threadIdx.x;
    h[t] = 0;
    __syncthreads();
    for (int e = blockIdx.x * 256 + t; e < E; e += gridDim.x * 256)
        atomicAdd(&h[ee[e] >> 9], 1);
    __syncthreads();
    if (h[t]) atomicAdd(&btot[t], h[t]);
}

// B2: scan 256 bucket totals -> bbase (exclusive) + bcursor.
// NOTE: no bbase[256] — buckets >= NBUK have zero count, so the exclusive
// scan already gives bbase[NBUK] == E at index NBUK (< 256). A bbase[256]
// write would alias bcursor[0] in the ws layout (round-9 fault).
__global__ void k_bscan(const int* __restrict__ btot, int* __restrict__ bbase,
                        int* __restrict__ bcursor)
{
    __shared__ int sd[256];
    int t = threadIdx.x;
    int v = btot[t];
    sd[t] = v;
    __syncthreads();
    for (int off = 1; off < 256; off <<= 1) {
        int x = (t >= off) ? sd[t - off] : 0;
        __syncthreads();
        sd[t] += x;
        __syncthreads();
    }
    int excl = sd[t] - v;
    bbase[t] = excl;
    bcursor[t] = excl;
}

// B3: bucket scatter. Per block: LDS hist of its 2048 edges, ONE global atomic
// per (block,bucket) to reserve a contiguous range, then packed writes.
// Entry = (dst&511)<<20 | src  (src < 2^17).
__global__ __launch_bounds__(256) void k_bscatter(
    const int* __restrict__ es, const int* __restrict__ ee,
    int* __restrict__ bcursor, unsigned* __restrict__ ebuf, int E)
{
    __shared__ int h[256], gb[256], lr[256];
    int t = threadIdx.x;
    h[t] = 0;
    lr[t] = 0;
    __syncthreads();
    int base = blockIdx.x * ESB;
    unsigned ent[8];
    int bk[8];
#pragma unroll
    for (int i = 0; i < 8; i++) {
        int e = base + t + i * 256;
        if (e < E) {
            int s = es[e], d = ee[e];
            bk[i] = d >> 9;
            ent[i] = (unsigned)s | ((unsigned)(d & 511) << 20);
            atomicAdd(&h[bk[i]], 1);
        } else bk[i] = -1;
    }
    __syncthreads();
    if (h[t]) gb[t] = atomicAdd(&bcursor[t], h[t]);
    __syncthreads();
#pragma unroll
    for (int i = 0; i < 8; i++) {
        if (bk[i] >= 0) {
            int r = atomicAdd(&lr[bk[i]], 1);
            ebuf[gb[bk[i]] + r] = ent[i];
        }
    }
}

// B4: per-bucket fine grouping: LDS node hist + LDS scan -> rowptr window
// + fine scatter of srcidx into a ~20 KB contiguous (L2-resident) window.
__global__ __launch_bounds__(256) void k_group(
    const int* __restrict__ bbase, const unsigned* __restrict__ ebuf,
    int* __restrict__ rowptr, int* __restrict__ srcidx)
{
    __shared__ int h[512], sc[512];
    int b = blockIdx.x, t = threadIdx.x;
    int lo = bbase[b], hi = bbase[b + 1];
    h[t] = 0;
    h[t + 256] = 0;
    __syncthreads();
    for (int i = lo + t; i < hi; i += 256)
        atomicAdd(&h[ebuf[i] >> 20], 1);
    __syncthreads();
    sc[t] = h[t];
    sc[t + 256] = h[t + 256];
    __syncthreads();
    for (int off = 1; off < 512; off <<= 1) {
        int v0 = (t >= off) ? sc[t - off] : 0;
        int v1 = (t + 256 >= off) ? sc[t + 256 - off] : 0;
        __syncthreads();
        sc[t] += v0;
        sc[t + 256] += v1;
        __syncthreads();
    }
    int n0 = b * 512 + t, n1 = b * 512 + t + 256;
    int e0 = lo + sc[t] - h[t];
    int e1 = lo + sc[t + 256] - h[t + 256];
    if (n0 < NNODES) rowptr[n0] = e0;
    if (n1 < NNODES) rowptr[n1] = e1;
    if (b == NBUK - 1 && t == 0) rowptr[NNODES] = hi;
    h[t] = e0;           // repurpose as fill cursors
    h[t + 256] = e1;
    __syncthreads();
    for (int i = lo + t; i < hi; i += 256) {
        unsigned en = ebuf[i];
        int pos = atomicAdd(&h[en >> 20], 1);
        int s = (int)(en & 0xFFFFF);
        srcidx[pos] = s < NNODES ? s : 0;  // clamp: degrade, never fault
    }
}

// Stage 64 rows of x into LDS as bf16 (padded stride 72).
// MODE 0: rows from concat(u,v), dtype per bfflag. MODE 1: relu(ab*A+ab').
template <int MODE>
__device__ __forceinline__ void stage_x(
    unsigned short (*xls)[72], int row0, int tid, int bfflag,
    const void* u, const void* v, const float* Aacc, const float* ab)
{
    int r = tid >> 2, c0 = (tid & 3) * 16;
    int row = row0 + r;
    int rowc = row < NNODES ? row : NNODES - 1;
    uint4 w0, w1;
    if (MODE == 0) {
        const void* src = (rowc < NUSERS) ? u : v;
        size_t off = (rowc < NUSERS) ? ((size_t)rowc * DD + c0)
                                     : ((size_t)(rowc - NUSERS) * DD + c0);
        if (bfflag) {
            const uint4* p = (const uint4*)((const unsigned short*)src + off);
            w0 = p[0];
            w1 = p[1];
        } else {
            const float4* p = (const float4*)((const float*)src + off);
            float4 f0 = p[0], f1 = p[1], f2 = p[2], f3 = p[3];
            w0 = make_uint4(pack2(f0.x, f0.y), pack2(f0.z, f0.w),
                            pack2(f1.x, f1.y), pack2(f1.z, f1.w));
            w1 = make_uint4(pack2(f2.x, f2.y), pack2(f2.z, f2.w),
                            pack2(f3.x, f3.y), pack2(f3.z, f3.w));
        }
    } else {
        const float4* p  = (const float4*)(Aacc + (size_t)rowc * DD + c0);
        const float4* pa = (const float4*)(ab + c0);
        const float4* pb = (const float4*)(ab + 64 + c0);
        float4 f0 = p[0], f1 = p[1], f2 = p[2], f3 = p[3];
        float4 a0 = pa[0], a1 = pa[1], a2 = pa[2], a3 = pa[3];
        float4 g0 = pb[0], g1 = pb[1], g2 = pb[2], g3 = pb[3];
        w0 = make_uint4(pr2(f0.x, f0.y, a0.x, a0.y, g0.x, g0.y),
                        pr2(f0.z, f0.w, a0.z, a0.w, g0.z, g0.w),
                        pr2(f1.x, f1.y, a1.x, a1.y, g1.x, g1.y),
                        pr2(f1.z, f1.w, a1.z, a1.w, g1.z, g1.w));
        w1 = make_uint4(pr2(f2.x, f2.y, a2.x, a2.y, g2.x, g2.y),
                        pr2(f2.z, f2.w, a2.z, a2.w, g2.z, g2.w),
                        pr2(f3.x, f3.y, a3.x, a3.y, g3.x, g3.y),
                        pr2(f3.z, f3.w, a3.z, a3.w, g3.z, g3.w));
    }
    *(uint4*)&xls[r][c0] = w0;
    *((uint4*)&xls[r][c0] + 1) = w1;
}

// ---- MFMA fused 4-GEMM, tile-looped: wave w = matrix w.
template <int MODE>
__global__ __launch_bounds__(256) void k_mm4_mfma(
    const void* __restrict__ u, const void* __restrict__ v,
    const float* __restrict__ ab,
    const void* __restrict__ W0, const void* __restrict__ W1,
    const void* __restrict__ W2, const void* __restrict__ W3,
    const void* __restrict__ b0, const void* __restrict__ b1,
    const int* __restrict__ flag,
    float* __restrict__ A, unsigned short* __restrict__ gVe,
    unsigned short* __restrict__ T2)
{
    __shared__ unsigned short Wls[4][DD][72];
    __shared__ unsigned short xls[DD][72];
    const int bfflag = flag[0];
    const int tid = threadIdx.x;
    const void* Wm[4] = {W0, W1, W2, W3};
    if (bfflag) {
        for (int i = tid; i < 2048; i += 256) {
            int m = i >> 9;
            int e0 = (i & 511) * 8;
            uint4 w = ((const uint4*)Wm[m])[i & 511];
            *(uint4*)&Wls[m][e0 >> 6][e0 & 63] = w;
        }
    } else {
        for (int i = tid; i < 4096; i += 256) {
            int m = i >> 10;
            int e0 = (i & 1023) * 4;
            float4 f = ((const float4*)Wm[m])[i & 1023];
            *(uint2*)&Wls[m][e0 >> 6][e0 & 63] =
                make_uint2(pack2(f.x, f.y), pack2(f.z, f.w));
        }
    }
    __syncthreads();

    const int wv = tid >> 6, lane = tid & 63;
    const int quad = lane >> 4, ln = lane & 15;
    bf16x8 bfr[2][4];
#pragma unroll
    for (int ks = 0; ks < 2; ks++)
#pragma unroll
        for (int nt = 0; nt < 4; nt++)
#pragma unroll
            for (int j = 0; j < 8; j++)
                bfr[ks][nt][j] = (short)Wls[wv][ks * 32 + quad * 8 + j][nt * 16 + ln];
    float bias[4];
#pragma unroll
    for (int nt = 0; nt < 4; nt++)
        bias[nt] = (wv == 0) ? ldf(b0, nt * 16 + ln, bfflag)
                 : (wv == 1) ? ldf(b1, nt * 16 + ln, bfflag) : 0.f;

    for (int t = blockIdx.x; t < NGB; t += gridDim.x) {
        const int row0 = t * DD;
        stage_x<MODE>(xls, row0, tid, bfflag, u, v, A, ab);
        __syncthreads();
#pragma unroll
        for (int rt = 0; rt < 4; rt++) {
            int m = rt * 16 + ln;
            bf16x8 af0 = *(const bf16x8*)&xls[m][quad * 8];
            bf16x8 af1 = *(const bf16x8*)&xls[m][32 + quad * 8];
#pragma unroll
            for (int nt = 0; nt < 4; nt++) {
                f32x4 c = {0.f, 0.f, 0.f, 0.f};
                c = __builtin_amdgcn_mfma_f32_16x16x32_bf16(af0, bfr[0][nt], c, 0, 0, 0);
                c = __builtin_amdgcn_mfma_f32_16x16x32_bf16(af1, bfr[1][nt], c, 0, 0, 0);
                int col = nt * 16 + ln;
#pragma unroll
                for (int r = 0; r < 4; r++) {
                    int row = row0 + rt * 16 + quad * 4 + r;
                    if (row < NNODES) {
                        size_t o = (size_t)row * DD + col;
                        if (wv == 0)      A[o] = c[r] + bias[nt];
                        else if (wv == 1) gVe[o] = fbits(c[r] + bias[nt]);
                        else if (wv == 2) T2[2 * o] = fbits(c[r]);
                        else              T2[2 * o + 1] = fbits(c[r]);
                    }
                }
            }
        }
        __syncthreads();
    }
}

// ---- MFMA final: out = relu(ab*A + ab' + x_in@R); wave w = rowtile w.
__global__ __launch_bounds__(256) void k_final_mfma(
    const float* __restrict__ A, const float* __restrict__ ab,
    const void* __restrict__ u, const void* __restrict__ v,
    const void* __restrict__ R, const int* __restrict__ flag,
    void* __restrict__ out)
{
    __shared__ unsigned short Wls[DD][72];
    __shared__ unsigned short xls[DD][72];
    const int bfflag = flag[0];
    const int tid = threadIdx.x;
    if (bfflag) {
        for (int i = tid; i < 512; i += 256) {
            int e0 = i * 8;
            *(uint4*)&Wls[e0 >> 6][e0 & 63] = ((const uint4*)R)[i];
        }
    } else {
        for (int i = tid; i < 1024; i += 256) {
            int e0 = i * 4;
            float4 f = ((const float4*)R)[i];
            *(uint2*)&Wls[e0 >> 6][e0 & 63] =
                make_uint2(pack2(f.x, f.y), pack2(f.z, f.w));
        }
    }
    const int row0 = blockIdx.x * DD;
    stage_x<0>(xls, row0, tid, bfflag, u, v, nullptr, nullptr);
    __syncthreads();

    const int wv = tid >> 6, lane = tid & 63;
    const int quad = lane >> 4, ln = lane & 15;
    bf16x8 bfr[2][4];
#pragma unroll
    for (int ks = 0; ks < 2; ks++)
#pragma unroll
        for (int nt = 0; nt < 4; nt++)
#pragma unroll
            for (int j = 0; j < 8; j++)
                bfr[ks][nt][j] = (short)Wls[ks * 32 + quad * 8 + j][nt * 16 + ln];
    float av[4], bv[4];
#pragma unroll
    for (int nt = 0; nt < 4; nt++) {
        av[nt] = ab[nt * 16 + ln];
        bv[nt] = ab[64 + nt * 16 + ln];
    }
    const int rt = wv;
    int m = rt * 16 + ln;
    bf16x8 af0 = *(const bf16x8*)&xls[m][quad * 8];
    bf16x8 af1 = *(const bf16x8*)&xls[m][32 + quad * 8];
#pragma unroll
    for (int nt = 0; nt < 4; nt++) {
        f32x4 c = {0.f, 0.f, 0.f, 0.f};
        c = __builtin_amdgcn_mfma_f32_16x16x32_bf16(af0, bfr[0][nt], c, 0, 0, 0);
        c = __builtin_amdgcn_mfma_f32_16x16x32_bf16(af1, bfr[1][nt], c, 0, 0, 0);
        int col = nt * 16 + ln;
#pragma unroll
        for (int r = 0; r < 4; r++) {
            int row = row0 + rt * 16 + quad * 4 + r;
            if (row < NNODES) {
                size_t o = (size_t)row * DD + col;
                float vv = av[nt] * A[o] + bv[nt] + c[r];
                vv = vv > 0.f ? vv : 0.f;
                if (bfflag) ((unsigned short*)out)[o] = fbits(vv);
                else        ((float*)out)[o] = vv;
            }
        }
    }
}

// ---- Gather-accumulate: one wave per dst node, fsig + x8 unroll ----
__global__ __launch_bounds__(256) void k_accum(
    const int* __restrict__ rowptr, const int* __restrict__ srcidx,
    const unsigned* __restrict__ T, const bf16* __restrict__ gVe,
    float* __restrict__ A)
{
    int d = blockIdx.x * 4 + (threadIdx.x >> 6);
    if (d >= NNODES) return;
    int c = threadIdx.x & 63;
    int r0 = rowptr[d], r1 = rowptr[d + 1];
    size_t o = (size_t)d * DD + c;
    float gv = b2f(gVe[o]);
    float sum = A[o];
    int i = r0;
    for (; i + 7 < r1; i += 8) {
        unsigned t0 = T[(size_t)srcidx[i] * DD + c];
        unsigned t1 = T[(size_t)srcidx[i + 1] * DD + c];
        unsigned t2 = T[(size_t)srcidx[i + 2] * DD + c];
        unsigned t3 = T[(size_t)srcidx[i + 3] * DD + c];
        unsigned t4 = T[(size_t)srcidx[i + 4] * DD + c];
        unsigned t5 = T[(size_t)srcidx[i + 5] * DD + c];
        unsigned t6 = T[(size_t)srcidx[i + 6] * DD + c];
        unsigned t7 = T[(size_t)srcidx[i + 7] * DD + c];
        sum += lo_bf16(t0) * fsig(gv + hi_bf16(t0));
        sum += lo_bf16(t1) * fsig(gv + hi_bf16(t1));
        sum += lo_bf16(t2) * fsig(gv + hi_bf16(t2));
        sum += lo_bf16(t3) * fsig(gv + hi_bf16(t3));
        sum += lo_bf16(t4) * fsig(gv + hi_bf16(t4));
        sum += lo_bf16(t5) * fsig(gv + hi_bf16(t5));
        sum += lo_bf16(t6) * fsig(gv + hi_bf16(t6));
        sum += lo_bf16(t7) * fsig(gv + hi_bf16(t7));
    }
    for (; i + 3 < r1; i += 4) {
        unsigned t0 = T[(size_t)srcidx[i] * DD + c];
        unsigned t1 = T[(size_t)srcidx[i + 1] * DD + c];
        unsigned t2 = T[(size_t)srcidx[i + 2] * DD + c];
        unsigned t3 = T[(size_t)srcidx[i + 3] * DD + c];
        sum += lo_bf16(t0) * fsig(gv + hi_bf16(t0));
        sum += lo_bf16(t1) * fsig(gv + hi_bf16(t1));
        sum += lo_bf16(t2) * fsig(gv + hi_bf16(t2));
        sum += lo_bf16(t3) * fsig(gv + hi_bf16(t3));
    }
    for (; i < r1; i++) {
        unsigned t = T[(size_t)srcidx[i] * DD + c];
        sum += lo_bf16(t) * fsig(gv + hi_bf16(t));
    }
    A[o] = sum;
}

// Column sums + sumsq over fp32 [NNODES,64]
__global__ __launch_bounds__(256) void k_reduce(
    const float* __restrict__ x, float* __restrict__ red)
{
    __shared__ float s1[256], s2[256];
    const int c = threadIdx.x & 63, rg = threadIdx.x >> 6;
    float sum = 0.f, sq = 0.f;
    for (int row = blockIdx.x * 4 + rg; row < NNODES; row += gridDim.x * 4) {
        float vv = x[(size_t)row * DD + c];
        sum += vv;
        sq += vv * vv;
    }
    s1[threadIdx.x] = sum;
    s2[threadIdx.x] = sq;
    __syncthreads();
    if (threadIdx.x < 64) {
        sum = s1[c] + s1[64 + c] + s1[128 + c] + s1[192 + c];
        sq = s2[c] + s2[64 + c] + s2[128 + c] + s2[192 + c];
        unsafeAtomicAdd(&red[c], sum);
        unsafeAtomicAdd(&red[64 + c], sq);
    }
}

__global__ void k_stats(const float* __restrict__ red,
                        const void* __restrict__ gamma,
                        const void* __restrict__ beta,
                        const int* __restrict__ flag,
                        float* __restrict__ ab)
{
    int c = threadIdx.x;  // 64 threads
    int bf = flag[0];
    float mean = red[c] * (1.f / NNODES);
    float var = red[64 + c] * (1.f / NNODES) - mean * mean;
    float rstd = rsqrtf(var + 1e-3f);
    float a = ldf(gamma, c, bf) * rstd;
    ab[c] = a;
    ab[64 + c] = ldf(beta, c, bf) - mean * a;
}

extern "C" void kernel_launch(void* const* d_in, const int* in_sizes, int n_in,
                              void* d_out, int out_size, void* d_ws, size_t ws_size,
                              hipStream_t stream)
{
    const void* u   = d_in[0];
    const void* v   = d_in[1];
    const int* es   = (const int*)d_in[2];
    const int* ee   = (const int*)d_in[3];
    const void* Ui1 = d_in[4];
    const void* Uj1 = d_in[5];
    const void* Vi1 = d_in[6];
    const void* Vj1 = d_in[7];
    const void* bu1 = d_in[8];
    const void* bv1 = d_in[9];
    const void* Ui2 = d_in[10];
    const void* Uj2 = d_in[11];
    const void* Vi2 = d_in[12];
    const void* Vj2 = d_in[13];
    const void* bu2 = d_in[14];
    const void* bv2 = d_in[15];
    const void* R   = d_in[16];
    const void* g1  = d_in[17];
    const void* be1 = d_in[18];
    const void* g2  = d_in[19];
    const void* be2 = d_in[20];
    const int E = in_sizes[2];

    // Workspace (~56.8 MB; proven layout). ebuf aliases T (CSR build fully
    // precedes k_mm4<0>'s T writes). gVe lives in d_out until k_final.
    // NOTE: bbase is 256 ints (no [256] element) — round-9's bbase[256]
    // aliased bcursor[0] and caused a GPU fault.
    char* ws = (char*)d_ws;
    float* A       = (float*)(ws);                  // 25.6 MB fp32 accumulator
    unsigned* T    = (unsigned*)(ws + 25600000);    // 25.6 MB (Ui | Vj<<16)
    unsigned* ebuf = (unsigned*)(ws + 25600000);    // 4 MB, aliases T
    int* srcidx    = (int*)(ws + 51200000);         // 4 MB
    int* rowptr    = (int*)(ws + 56000000);         // 400,004 B
    float* red     = (float*)(ws + 56802176);       // red1/red2/ab1/ab2 (2 KB)
    int* flag      = (int*)(ws + 56804224);
    int* btot      = (int*)(ws + 56804352);         // 256 ints
    int* bbase     = (int*)(ws + 56805376);         // 256 ints (ends 56806400)
    int* bcursor   = (int*)(ws + 56806400);         // 256 ints
    float* red1 = red, *red2 = red + 128, *ab1 = red + 256, *ab2 = red + 384;
    bf16* gVe = (bf16*)d_out;

    // ---- dtype sniff + bucketed CSR build ----
    k_sniff<<<1, 256, 0, stream>>>((const unsigned short*)u, flag, red, btot);
    k_bhist<<<400, 256, 0, stream>>>(ee, btot, E);
    k_bscan<<<1, 256, 0, stream>>>(btot, bbase, bcursor);
    k_bscatter<<<(E + ESB - 1) / ESB, 256, 0, stream>>>(es, ee, bcursor, ebuf, E);
    k_group<<<NBUK, 256, 0, stream>>>(bbase, ebuf, rowptr, srcidx);

    // ---- stage 1 ----
    k_mm4_mfma<0><<<GMM, 256, 0, stream>>>(u, v, nullptr,
                                           Uj1, Vi1, Ui1, Vj1, bu1, bv1, flag,
                                           A, (unsigned short*)gVe,
                                           (unsigned short*)T);
    k_accum<<<(NNODES + 3) / 4, 256, 0, stream>>>(rowptr, srcidx, T, gVe, A);
    k_reduce<<<1024, 256, 0, stream>>>(A, red1);
    k_stats<<<1, 64, 0, stream>>>(red1, g1, be1, flag, ab1);

    // ---- stage 2 (BN1+relu fused into staging; A updated in place) ----
    k_mm4_mfma<1><<<GMM, 256, 0, stream>>>(nullptr, nullptr, ab1,
                                           Uj2, Vi2, Ui2, Vj2, bu2, bv2, flag,
                                           A, (unsigned short*)gVe,
                                           (unsigned short*)T);
    k_accum<<<(NNODES + 3) / 4, 256, 0, stream>>>(rowptr, srcidx, T, gVe, A);
    k_reduce<<<1024, 256, 0, stream>>>(A, red2);
    k_stats<<<1, 64, 0, stream>>>(red2, g2, be2, flag, ab2);

    // ---- BN2 + residual (x_in@R via MFMA) + relu -> out ----
    k_final_mfma<<<NGB, 256, 0, stream>>>(A, ab2, u, v, R, flag, d_out);
}

// Round 11
// 420.271 us; speedup vs baseline: 3.2147x; 1.1020x over previous
//
#include <hip/hip_runtime.h>
#include <hip/hip_bf16.h>

#define NUSERS 60000
#define NNODES 100000
#define DD 64
#define NGB 1563  // ceil(NNODES/64) — 64-row tiles
#define GMM 1024  // k_mm4 grid (4 blocks/CU at 36,864 B LDS)
#define NBUK 196  // ceil(NNODES/512) coarse buckets (dst>>9)
#define ESB 2048  // edges per k_bscatter block

typedef __hip_bfloat16 bf16;
using bf16x8 = __attribute__((ext_vector_type(8))) short;
using f32x4  = __attribute__((ext_vector_type(4))) float;

__device__ __forceinline__ float b2f(bf16 x) { return __bfloat162float(x); }
__device__ __forceinline__ bf16 f2b(float x) { return __float2bfloat16(x); }
__device__ __forceinline__ unsigned short fbits(float x) {
    union { bf16 b; unsigned short u; } cv; cv.b = f2b(x); return cv.u;
}
__device__ __forceinline__ float lo_bf16(unsigned w) {
    union { unsigned u; float f; } t; t.u = w << 16; return t.f;
}
__device__ __forceinline__ float hi_bf16(unsigned w) {
    union { unsigned u; float f; } t; t.u = w & 0xFFFF0000u; return t.f;
}
__device__ __forceinline__ float ldf(const void* p, size_t i, int isbf) {
    if (isbf) return b2f(((const bf16*)p)[i]);
    return ((const float*)p)[i];
}
__device__ __forceinline__ float fsig(float g) {
    return __builtin_amdgcn_rcpf(1.f + __expf(-g));
}
__device__ __forceinline__ unsigned pack2(float a, float b) {
    return (unsigned)fbits(a) | ((unsigned)fbits(b) << 16);
}
__device__ __forceinline__ unsigned pr2(float x0, float x1, float a0, float a1,
                                        float b0, float b1) {
    float t0 = a0 * x0 + b0, t1 = a1 * x1 + b1;
    t0 = t0 > 0.f ? t0 : 0.f;
    t1 = t1 > 0.f ? t1 : 0.f;
    return pack2(t0, t1);
}

// Sniff dtype of u_features (bf16 vs fp32) + zero red[0:256] and btot[0:256].
__global__ void k_sniff(const unsigned short* __restrict__ h,
                        int* __restrict__ flag, float* __restrict__ red,
                        int* __restrict__ btot)
{
    __shared__ int cs[256];
    int t = threadIdx.x;
    int cnt = 0;
    for (int i = t; i < 1024; i += 256) {
        int e = (h[2 * i] >> 7) & 0xFF;
        cnt += (e >= 100 && e <= 140) ? 1 : 0;
    }
    cs[t] = cnt;
    __syncthreads();
    for (int s = 128; s > 0; s >>= 1) {
        if (t < s) cs[t] += cs[t + s];
        __syncthreads();
    }
    if (t == 0) flag[0] = (cs[0] > 512) ? 1 : 0;
    red[t] = 0.f;
    btot[t] = 0;
}

// ---- Bucketed CSR build (dst-sorted edges), once per launch ----
__global__ __launch_bounds__(256) void k_bhist(const int* __restrict__ ee,
                                               int* __restrict__ btot, int E)
{
    __shared__ int h[256];
    int t = threadIdx.x;
    h[t] = 0;
    __syncthreads();
    for (int e = blockIdx.x * 256 + t; e < E; e += gridDim.x * 256)
        atomicAdd(&h[ee[e] >> 9], 1);
    __syncthreads();
    if (h[t]) atomicAdd(&btot[t], h[t]);
}

// NOTE: no bbase[256] — a [256] write would alias bcursor[0] (round-9 fault).
__global__ void k_bscan(const int* __restrict__ btot, int* __restrict__ bbase,
                        int* __restrict__ bcursor)
{
    __shared__ int sd[256];
    int t = threadIdx.x;
    int v = btot[t];
    sd[t] = v;
    __syncthreads();
    for (int off = 1; off < 256; off <<= 1) {
        int x = (t >= off) ? sd[t - off] : 0;
        __syncthreads();
        sd[t] += x;
        __syncthreads();
    }
    int excl = sd[t] - v;
    bbase[t] = excl;
    bcursor[t] = excl;
}

// Entry = (dst&511)<<20 | src  (src < 2^17).
__global__ __launch_bounds__(256) void k_bscatter(
    const int* __restrict__ es, const int* __restrict__ ee,
    int* __restrict__ bcursor, unsigned* __restrict__ ebuf, int E)
{
    __shared__ int h[256], gb[256], lr[256];
    int t = threadIdx.x;
    h[t] = 0;
    lr[t] = 0;
    __syncthreads();
    int base = blockIdx.x * ESB;
    unsigned ent[8];
    int bk[8];
#pragma unroll
    for (int i = 0; i < 8; i++) {
        int e = base + t + i * 256;
        if (e < E) {
            int s = es[e], d = ee[e];
            bk[i] = d >> 9;
            ent[i] = (unsigned)s | ((unsigned)(d & 511) << 20);
            atomicAdd(&h[bk[i]], 1);
        } else bk[i] = -1;
    }
    __syncthreads();
    if (h[t]) gb[t] = atomicAdd(&bcursor[t], h[t]);
    __syncthreads();
#pragma unroll
    for (int i = 0; i < 8; i++) {
        if (bk[i] >= 0) {
            int r = atomicAdd(&lr[bk[i]], 1);
            ebuf[gb[bk[i]] + r] = ent[i];
        }
    }
}

__global__ __launch_bounds__(256) void k_group(
    const int* __restrict__ bbase, const unsigned* __restrict__ ebuf,
    int* __restrict__ rowptr, int* __restrict__ srcidx)
{
    __shared__ int h[512], sc[512];
    int b = blockIdx.x, t = threadIdx.x;
    int lo = bbase[b], hi = bbase[b + 1];
    h[t] = 0;
    h[t + 256] = 0;
    __syncthreads();
    for (int i = lo + t; i < hi; i += 256)
        atomicAdd(&h[ebuf[i] >> 20], 1);
    __syncthreads();
    sc[t] = h[t];
    sc[t + 256] = h[t + 256];
    __syncthreads();
    for (int off = 1; off < 512; off <<= 1) {
        int v0 = (t >= off) ? sc[t - off] : 0;
        int v1 = (t + 256 >= off) ? sc[t + 256 - off] : 0;
        __syncthreads();
        sc[t] += v0;
        sc[t + 256] += v1;
        __syncthreads();
    }
    int n0 = b * 512 + t, n1 = b * 512 + t + 256;
    int e0 = lo + sc[t] - h[t];
    int e1 = lo + sc[t + 256] - h[t + 256];
    if (n0 < NNODES) rowptr[n0] = e0;
    if (n1 < NNODES) rowptr[n1] = e1;
    if (b == NBUK - 1 && t == 0) rowptr[NNODES] = hi;
    h[t] = e0;           // repurpose as fill cursors
    h[t + 256] = e1;
    __syncthreads();
    for (int i = lo + t; i < hi; i += 256) {
        unsigned en = ebuf[i];
        int pos = atomicAdd(&h[en >> 20], 1);
        int s = (int)(en & 0xFFFFF);
        srcidx[pos] = s < NNODES ? s : 0;  // clamp: degrade, never fault
    }
}

// Load one 64-row x tile slice (16 bf16) into registers.
// MODE 0: rows from concat(u,v), dtype per bfflag. MODE 1: relu(ab*A+ab').
template <int MODE>
__device__ __forceinline__ void stage_load(
    int tile, int tid, int bfflag,
    const void* u, const void* v, const float* Aacc, const float* ab,
    uint4& w0, uint4& w1)
{
    int r = tid >> 2, c0 = (tid & 3) * 16;
    int row = tile * DD + r;
    int rowc = row < NNODES ? row : NNODES - 1;
    if (MODE == 0) {
        const void* src = (rowc < NUSERS) ? u : v;
        size_t off = (rowc < NUSERS) ? ((size_t)rowc * DD + c0)
                                     : ((size_t)(rowc - NUSERS) * DD + c0);
        if (bfflag) {
            const uint4* p = (const uint4*)((const unsigned short*)src + off);
            w0 = p[0];
            w1 = p[1];
        } else {
            const float4* p = (const float4*)((const float*)src + off);
            float4 f0 = p[0], f1 = p[1], f2 = p[2], f3 = p[3];
            w0 = make_uint4(pack2(f0.x, f0.y), pack2(f0.z, f0.w),
                            pack2(f1.x, f1.y), pack2(f1.z, f1.w));
            w1 = make_uint4(pack2(f2.x, f2.y), pack2(f2.z, f2.w),
                            pack2(f3.x, f3.y), pack2(f3.z, f3.w));
        }
    } else {
        const float4* p  = (const float4*)(Aacc + (size_t)rowc * DD + c0);
        const float4* pa = (const float4*)(ab + c0);
        const float4* pb = (const float4*)(ab + 64 + c0);
        float4 f0 = p[0], f1 = p[1], f2 = p[2], f3 = p[3];
        float4 a0 = pa[0], a1 = pa[1], a2 = pa[2], a3 = pa[3];
        float4 g0 = pb[0], g1 = pb[1], g2 = pb[2], g3 = pb[3];
        w0 = make_uint4(pr2(f0.x, f0.y, a0.x, a0.y, g0.x, g0.y),
                        pr2(f0.z, f0.w, a0.z, a0.w, g0.z, g0.w),
                        pr2(f1.x, f1.y, a1.x, a1.y, g1.x, g1.y),
                        pr2(f1.z, f1.w, a1.z, a1.w, g1.z, g1.w));
        w1 = make_uint4(pr2(f2.x, f2.y, a2.x, a2.y, g2.x, g2.y),
                        pr2(f2.z, f2.w, a2.z, a2.w, g2.z, g2.w),
                        pr2(f3.x, f3.y, a3.x, a3.y, g3.x, g3.y),
                        pr2(f3.z, f3.w, a3.z, a3.w, g3.z, g3.w));
    }
}

__device__ __forceinline__ void stage_store(unsigned short* xbuf, int tid,
                                            const uint4& w0, const uint4& w1)
{
    int r = tid >> 2, c0 = (tid & 3) * 16;
    *(uint4*)&xbuf[r * 72 + c0] = w0;
    *((uint4*)&xbuf[r * 72 + c0] + 1) = w1;
}

// ---- MFMA fused 4-GEMM, double-buffered + pipelined.
// wave0: A = x@W0 + b0 (fp32)   wave1: gVe = x@W1 + b1 (bf16)
// waves 2/3: 2 rowtiles each, BOTH W2,W3 -> full-dword packed T stores.
// LDS: weight region (36,864 B) is reused after B-frag extraction as a
// double-buffered x tile (2 x 9,216 B).
template <int MODE>
__global__ __launch_bounds__(256, 4) void k_mm4_mfma(
    const void* __restrict__ u, const void* __restrict__ v,
    const float* __restrict__ ab,
    const void* __restrict__ W0, const void* __restrict__ W1,
    const void* __restrict__ W2, const void* __restrict__ W3,
    const void* __restrict__ b0, const void* __restrict__ b1,
    const int* __restrict__ flag,
    float* __restrict__ A, unsigned short* __restrict__ gVe,
    unsigned* __restrict__ Tw)
{
    __shared__ __align__(16) unsigned short lsd[4 * DD * 72];  // 36,864 B
    const int bfflag = flag[0];
    const int tid = threadIdx.x;

    // Issue first x-tile load ASAP (hidden behind weight staging).
    int t = blockIdx.x;
    uint4 xa, xb;
    stage_load<MODE>(t, tid, bfflag, u, v, A, ab, xa, xb);

    // Stage 4 weight matrices (compile-time matrix index — no scratch array).
    if (bfflag) {
#define WSTG_BF(m, src)                                                   \
        _Pragma("unroll")                                                 \
        for (int j = 0; j < 2; j++) {                                     \
            int i = tid + j * 256; int e0 = i * 8;                        \
            *(uint4*)&lsd[(m) * 4608 + (e0 >> 6) * 72 + (e0 & 63)] =      \
                ((const uint4*)(src))[i];                                 \
        }
        WSTG_BF(0, W0) WSTG_BF(1, W1) WSTG_BF(2, W2) WSTG_BF(3, W3)
    } else {
#define WSTG_F32(m, src)                                                  \
        _Pragma("unroll")                                                 \
        for (int j = 0; j < 4; j++) {                                     \
            int i = tid + j * 256; int e0 = i * 4;                        \
            float4 f = ((const float4*)(src))[i];                         \
            *(uint2*)&lsd[(m) * 4608 + (e0 >> 6) * 72 + (e0 & 63)] =      \
                make_uint2(pack2(f.x, f.y), pack2(f.z, f.w));             \
        }
        WSTG_F32(0, W0) WSTG_F32(1, W1) WSTG_F32(2, W2) WSTG_F32(3, W3)
    }
    __syncthreads();

    const int wv = tid >> 6, lane = tid & 63;
    const int quad = lane >> 4, ln = lane & 15;
    // B-frags: B[k = ks*32+quad*8+j][n = nt*16+ln]
    const int mA = (wv < 2) ? wv : 2;
    bf16x8 bfrA[2][4], bfrB[2][4];
#pragma unroll
    for (int ks = 0; ks < 2; ks++)
#pragma unroll
        for (int nt = 0; nt < 4; nt++)
#pragma unroll
            for (int j = 0; j < 8; j++)
                bfrA[ks][nt][j] = (short)lsd[mA * 4608 +
                    (ks * 32 + quad * 8 + j) * 72 + nt * 16 + ln];
    if (wv >= 2) {
#pragma unroll
        for (int ks = 0; ks < 2; ks++)
#pragma unroll
            for (int nt = 0; nt < 4; nt++)
#pragma unroll
                for (int j = 0; j < 8; j++)
                    bfrB[ks][nt][j] = (short)lsd[3 * 4608 +
                        (ks * 32 + quad * 8 + j) * 72 + nt * 16 + ln];
    }
    float bias[4];
#pragma unroll
    for (int nt = 0; nt < 4; nt++)
        bias[nt] = (wv == 0) ? ldf(b0, nt * 16 + ln, bfflag)
                 : (wv == 1) ? ldf(b1, nt * 16 + ln, bfflag) : 0.f;
    __syncthreads();  // weights fully consumed; region becomes x buffers

    auto compute = [&](const unsigned short* xt, int row0) {
        if (wv < 2) {
#pragma unroll
            for (int rt = 0; rt < 4; rt++) {
                int m = rt * 16 + ln;
                bf16x8 af0 = *(const bf16x8*)&xt[m * 72 + quad * 8];
                bf16x8 af1 = *(const bf16x8*)&xt[m * 72 + 32 + quad * 8];
#pragma unroll
                for (int nt = 0; nt < 4; nt++) {
                    f32x4 c = {0.f, 0.f, 0.f, 0.f};
                    c = __builtin_amdgcn_mfma_f32_16x16x32_bf16(af0, bfrA[0][nt], c, 0, 0, 0);
                    c = __builtin_amdgcn_mfma_f32_16x16x32_bf16(af1, bfrA[1][nt], c, 0, 0, 0);
                    int col = nt * 16 + ln;
#pragma unroll
                    for (int r = 0; r < 4; r++) {
                        int row = row0 + rt * 16 + quad * 4 + r;
                        if (row < NNODES) {
                            size_t o = (size_t)row * DD + col;
                            if (wv == 0) A[o] = c[r] + bias[nt];
                            else         gVe[o] = fbits(c[r] + bias[nt]);
                        }
                    }
                }
            }
        } else {
            const int rtb = (wv - 2) * 2;
#pragma unroll
            for (int rr = 0; rr < 2; rr++) {
                int rt = rtb + rr;
                int m = rt * 16 + ln;
                bf16x8 af0 = *(const bf16x8*)&xt[m * 72 + quad * 8];
                bf16x8 af1 = *(const bf16x8*)&xt[m * 72 + 32 + quad * 8];
#pragma unroll
                for (int nt = 0; nt < 4; nt++) {
                    f32x4 c2 = {0.f, 0.f, 0.f, 0.f};
                    f32x4 c3 = {0.f, 0.f, 0.f, 0.f};
                    c2 = __builtin_amdgcn_mfma_f32_16x16x32_bf16(af0, bfrA[0][nt], c2, 0, 0, 0);
                    c2 = __builtin_amdgcn_mfma_f32_16x16x32_bf16(af1, bfrA[1][nt], c2, 0, 0, 0);
                    c3 = __builtin_amdgcn_mfma_f32_16x16x32_bf16(af0, bfrB[0][nt], c3, 0, 0, 0);
                    c3 = __builtin_amdgcn_mfma_f32_16x16x32_bf16(af1, bfrB[1][nt], c3, 0, 0, 0);
                    int col = nt * 16 + ln;
#pragma unroll
                    for (int r = 0; r < 4; r++) {
                        int row = row0 + rt * 16 + quad * 4 + r;
                        if (row < NNODES)
                            Tw[(size_t)row * DD + col] = pack2(
                                hi_bf16((unsigned)fbits(c2[r]) << 16) * 0.f + c2[r],
                                c3[r]);
                    }
                }
            }
        }
    };

    // Pipelined tile loop (double-buffered x in the reclaimed weight LDS).
    stage_store(lsd, tid, xa, xb);
    int tn = t + GMM;
    if (tn < NGB)
        stage_load<MODE>(tn, tid, bfflag, u, v, A, ab, xa, xb);
    __syncthreads();
    int buf = 0;
    while (true) {
        compute(lsd + buf * 4608, t * DD);
        if (tn >= NGB) break;
        t = tn;
        tn += GMM;
        stage_store(lsd + (buf ^ 1) * 4608, tid, xa, xb);
        if (tn < NGB)
            stage_load<MODE>(tn, tid, bfflag, u, v, A, ab, xa, xb);
        __syncthreads();
        buf ^= 1;
    }
}

// ---- MFMA final: out = relu(ab*A + ab' + x_in@R); wave w = rowtile w.
__global__ __launch_bounds__(256) void k_final_mfma(
    const float* __restrict__ A, const float* __restrict__ ab,
    const void* __restrict__ u, const void* __restrict__ v,
    const void* __restrict__ R, const int* __restrict__ flag,
    void* __restrict__ out)
{
    __shared__ __align__(16) unsigned short Wls[DD][72];
    __shared__ __align__(16) unsigned short xls[DD][72];
    const int bfflag = flag[0];
    const int tid = threadIdx.x;
    if (bfflag) {
        for (int i = tid; i < 512; i += 256) {
            int e0 = i * 8;
            *(uint4*)&Wls[e0 >> 6][e0 & 63] = ((const uint4*)R)[i];
        }
    } else {
        for (int i = tid; i < 1024; i += 256) {
            int e0 = i * 4;
            float4 f = ((const float4*)R)[i];
            *(uint2*)&Wls[e0 >> 6][e0 & 63] =
                make_uint2(pack2(f.x, f.y), pack2(f.z, f.w));
        }
    }
    uint4 w0, w1;
    stage_load<0>(blockIdx.x, tid, bfflag, u, v, nullptr, nullptr, w0, w1);
    stage_store(&xls[0][0], tid, w0, w1);
    __syncthreads();

    const int row0 = blockIdx.x * DD;
    const int wv = tid >> 6, lane = tid & 63;
    const int quad = lane >> 4, ln = lane & 15;
    bf16x8 bfr[2][4];
#pragma unroll
    for (int ks = 0; ks < 2; ks++)
#pragma unroll
        for (int nt = 0; nt < 4; nt++)
#pragma unroll
            for (int j = 0; j < 8; j++)
                bfr[ks][nt][j] = (short)Wls[ks * 32 + quad * 8 + j][nt * 16 + ln];
    float av[4], bv[4];
#pragma unroll
    for (int nt = 0; nt < 4; nt++) {
        av[nt] = ab[nt * 16 + ln];
        bv[nt] = ab[64 + nt * 16 + ln];
    }
    const int rt = wv;
    int m = rt * 16 + ln;
    bf16x8 af0 = *(const bf16x8*)&xls[m][quad * 8];
    bf16x8 af1 = *(const bf16x8*)&xls[m][32 + quad * 8];
#pragma unroll
    for (int nt = 0; nt < 4; nt++) {
        f32x4 c = {0.f, 0.f, 0.f, 0.f};
        c = __builtin_amdgcn_mfma_f32_16x16x32_bf16(af0, bfr[0][nt], c, 0, 0, 0);
        c = __builtin_amdgcn_mfma_f32_16x16x32_bf16(af1, bfr[1][nt], c, 0, 0, 0);
        int col = nt * 16 + ln;
#pragma unroll
        for (int r = 0; r < 4; r++) {
            int row = row0 + rt * 16 + quad * 4 + r;
            if (row < NNODES) {
                size_t o = (size_t)row * DD + col;
                float vv = av[nt] * A[o] + bv[nt] + c[r];
                vv = vv > 0.f ? vv : 0.f;
                if (bfflag) ((unsigned short*)out)[o] = fbits(vv);
                else        ((float*)out)[o] = vv;
            }
        }
    }
}

// ---- Gather-accumulate: one wave per dst node, fsig + x8 unroll ----
__global__ __launch_bounds__(256) void k_accum(
    const int* __restrict__ rowptr, const int* __restrict__ srcidx,
    const unsigned* __restrict__ T, const bf16* __restrict__ gVe,
    float* __restrict__ A)
{
    int d = blockIdx.x * 4 + (threadIdx.x >> 6);
    if (d >= NNODES) return;
    int c = threadIdx.x & 63;
    int r0 = rowptr[d], r1 = rowptr[d + 1];
    size_t o = (size_t)d * DD + c;
    float gv = b2f(gVe[o]);
    float sum = A[o];
    int i = r0;
    for (; i + 7 < r1; i += 8) {
        unsigned t0 = T[(size_t)srcidx[i] * DD + c];
        unsigned t1 = T[(size_t)srcidx[i + 1] * DD + c];
        unsigned t2 = T[(size_t)srcidx[i + 2] * DD + c];
        unsigned t3 = T[(size_t)srcidx[i + 3] * DD + c];
        unsigned t4 = T[(size_t)srcidx[i + 4] * DD + c];
        unsigned t5 = T[(size_t)srcidx[i + 5] * DD + c];
        unsigned t6 = T[(size_t)srcidx[i + 6] * DD + c];
        unsigned t7 = T[(size_t)srcidx[i + 7] * DD + c];
        sum += lo_bf16(t0) * fsig(gv + hi_bf16(t0));
        sum += lo_bf16(t1) * fsig(gv + hi_bf16(t1));
        sum += lo_bf16(t2) * fsig(gv + hi_bf16(t2));
        sum += lo_bf16(t3) * fsig(gv + hi_bf16(t3));
        sum += lo_bf16(t4) * fsig(gv + hi_bf16(t4));
        sum += lo_bf16(t5) * fsig(gv + hi_bf16(t5));
        sum += lo_bf16(t6) * fsig(gv + hi_bf16(t6));
        sum += lo_bf16(t7) * fsig(gv + hi_bf16(t7));
    }
    for (; i + 3 < r1; i += 4) {
        unsigned t0 = T[(size_t)srcidx[i] * DD + c];
        unsigned t1 = T[(size_t)srcidx[i + 1] * DD + c];
        unsigned t2 = T[(size_t)srcidx[i + 2] * DD + c];
        unsigned t3 = T[(size_t)srcidx[i + 3] * DD + c];
        sum += lo_bf16(t0) * fsig(gv + hi_bf16(t0));
        sum += lo_bf16(t1) * fsig(gv + hi_bf16(t1));
        sum += lo_bf16(t2) * fsig(gv + hi_bf16(t2));
        sum += lo_bf16(t3) * fsig(gv + hi_bf16(t3));
    }
    for (; i < r1; i++) {
        unsigned t = T[(size_t)srcidx[i] * DD + c];
        sum += lo_bf16(t) * fsig(gv + hi_bf16(t));
    }
    A[o] = sum;
}

// Column sums + sumsq over fp32 [NNODES,64]
__global__ __launch_bounds__(256) void k_reduce(
    const float* __restrict__ x, float* __restrict__ red)
{
    __shared__ float s1[256], s2[256];
    const int c = threadIdx.x & 63, rg = threadIdx.x >> 6;
    float sum = 0.f, sq = 0.f;
    for (int row = blockIdx.x * 4 + rg; row < NNODES; row += gridDim.x * 4) {
        float vv = x[(size_t)row * DD + c];
        sum += vv;
        sq += vv * vv;
    }
    s1[threadIdx.x] = sum;
    s2[threadIdx.x] = sq;
    __syncthreads();
    if (threadIdx.x < 64) {
        sum = s1[c] + s1[64 + c] + s1[128 + c] + s1[192 + c];
        sq = s2[c] + s2[64 + c] + s2[128 + c] + s2[192 + c];
        unsafeAtomicAdd(&red[c], sum);
        unsafeAtomicAdd(&red[64 + c], sq);
    }
}

__global__ void k_stats(const float* __restrict__ red,
                        const void* __restrict__ gamma,
                        const void* __restrict__ beta,
                        const int* __restrict__ flag,
                        float* __restrict__ ab)
{
    int c = threadIdx.x;  // 64 threads
    int bf = flag[0];
    float mean = red[c] * (1.f / NNODES);
    float var = red[64 + c] * (1.f / NNODES) - mean * mean;
    float rstd = rsqrtf(var + 1e-3f);
    float a = ldf(gamma, c, bf) * rstd;
    ab[c] = a;
    ab[64 + c] = ldf(beta, c, bf) - mean * a;
}

extern "C" void kernel_launch(void* const* d_in, const int* in_sizes, int n_in,
                              void* d_out, int out_size, void* d_ws, size_t ws_size,
                              hipStream_t stream)
{
    const void* u   = d_in[0];
    const void* v   = d_in[1];
    const int* es   = (const int*)d_in[2];
    const int* ee   = (const int*)d_in[3];
    const void* Ui1 = d_in[4];
    const void* Uj1 = d_in[5];
    const void* Vi1 = d_in[6];
    const void* Vj1 = d_in[7];
    const void* bu1 = d_in[8];
    const void* bv1 = d_in[9];
    const void* Ui2 = d_in[10];
    const void* Uj2 = d_in[11];
    const void* Vi2 = d_in[12];
    const void* Vj2 = d_in[13];
    const void* bu2 = d_in[14];
    const void* bv2 = d_in[15];
    const void* R   = d_in[16];
    const void* g1  = d_in[17];
    const void* be1 = d_in[18];
    const void* g2  = d_in[19];
    const void* be2 = d_in[20];
    const int E = in_sizes[2];

    // Workspace (~56.8 MB; proven layout). ebuf aliases T (CSR build fully
    // precedes k_mm4<0>'s T writes). gVe lives in d_out until k_final.
    char* ws = (char*)d_ws;
    float* A       = (float*)(ws);                  // 25.6 MB fp32 accumulator
    unsigned* T    = (unsigned*)(ws + 25600000);    // 25.6 MB (Ui | Vj<<16)
    unsigned* ebuf = (unsigned*)(ws + 25600000);    // 4 MB, aliases T
    int* srcidx    = (int*)(ws + 51200000);         // 4 MB
    int* rowptr    = (int*)(ws + 56000000);         // 400,004 B
    float* red     = (float*)(ws + 56802176);       // red1/red2/ab1/ab2 (2 KB)
    int* flag      = (int*)(ws + 56804224);
    int* btot      = (int*)(ws + 56804352);         // 256 ints
    int* bbase     = (int*)(ws + 56805376);         // 256 ints (ends 56806400)
    int* bcursor   = (int*)(ws + 56806400);         // 256 ints
    float* red1 = red, *red2 = red + 128, *ab1 = red + 256, *ab2 = red + 384;
    bf16* gVe = (bf16*)d_out;

    // ---- dtype sniff + bucketed CSR build ----
    k_sniff<<<1, 256, 0, stream>>>((const unsigned short*)u, flag, red, btot);
    k_bhist<<<400, 256, 0, stream>>>(ee, btot, E);
    k_bscan<<<1, 256, 0, stream>>>(btot, bbase, bcursor);
    k_bscatter<<<(E + ESB - 1) / ESB, 256, 0, stream>>>(es, ee, bcursor, ebuf, E);
    k_group<<<NBUK, 256, 0, stream>>>(bbase, ebuf, rowptr, srcidx);

    // ---- stage 1 ----
    k_mm4_mfma<0><<<GMM, 256, 0, stream>>>(u, v, nullptr,
                                           Uj1, Vi1, Ui1, Vj1, bu1, bv1, flag,
                                           A, (unsigned short*)gVe, T);
    k_accum<<<(NNODES + 3) / 4, 256, 0, stream>>>(rowptr, srcidx, T, gVe, A);
    k_reduce<<<1024, 256, 0, stream>>>(A, red1);
    k_stats<<<1, 64, 0, stream>>>(red1, g1, be1, flag, ab1);

    // ---- stage 2 (BN1+relu fused into staging; A updated in place) ----
    k_mm4_mfma<1><<<GMM, 256, 0, stream>>>(nullptr, nullptr, ab1,
                                           Uj2, Vi2, Ui2, Vj2, bu2, bv2, flag,
                                           A, (unsigned short*)gVe, T);
    k_accum<<<(NNODES + 3) / 4, 256, 0, stream>>>(rowptr, srcidx, T, gVe, A);
    k_reduce<<<1024, 256, 0, stream>>>(A, red2);
    k_stats<<<1, 64, 0, stream>>>(red2, g2, be2, flag, ab2);

    // ---- BN2 + residual (x_in@R via MFMA) + relu -> out ----
    k_final_mfma<<<NGB, 256, 0, stream>>>(A, ab2, u, v, R, flag, d_out);
}

// Round 12
// 419.053 us; speedup vs baseline: 3.2241x; 1.0029x over previous
//
#include <hip/hip_runtime.h>
#include <hip/hip_bf16.h>

#define NUSERS 60000
#define NNODES 100000
#define DD 64
#define NGB 1563  // ceil(NNODES/64) — 64-row tiles
#define GMM 1024  // k_mm4 grid (4 blocks/CU at 36,864 B LDS)
#define NBUK 196  // ceil(NNODES/512) coarse buckets (dst>>9)
#define ESB 2048  // edges per k_bscatter block

typedef __hip_bfloat16 bf16;
using bf16x8 = __attribute__((ext_vector_type(8))) short;
using f32x4  = __attribute__((ext_vector_type(4))) float;

__device__ __forceinline__ float b2f(bf16 x) { return __bfloat162float(x); }
__device__ __forceinline__ bf16 f2b(float x) { return __float2bfloat16(x); }
__device__ __forceinline__ unsigned short fbits(float x) {
    union { bf16 b; unsigned short u; } cv; cv.b = f2b(x); return cv.u;
}
__device__ __forceinline__ float lo_bf16(unsigned w) {
    union { unsigned u; float f; } t; t.u = w << 16; return t.f;
}
__device__ __forceinline__ float hi_bf16(unsigned w) {
    union { unsigned u; float f; } t; t.u = w & 0xFFFF0000u; return t.f;
}
__device__ __forceinline__ float ldf(const void* p, size_t i, int isbf) {
    if (isbf) return b2f(((const bf16*)p)[i]);
    return ((const float*)p)[i];
}
__device__ __forceinline__ unsigned pack2(float a, float b) {
    return (unsigned)fbits(a) | ((unsigned)fbits(b) << 16);
}
__device__ __forceinline__ unsigned pr2(float x0, float x1, float a0, float a1,
                                        float b0, float b1) {
    float t0 = a0 * x0 + b0, t1 = a1 * x1 + b1;
    t0 = t0 > 0.f ? t0 : 0.f;
    t1 = t1 > 0.f ? t1 : 0.f;
    return pack2(t0, t1);
}

// Sniff dtype of u_features (bf16 vs fp32) + zero red[0:256] and btot[0:256].
__global__ void k_sniff(const unsigned short* __restrict__ h,
                        int* __restrict__ flag, float* __restrict__ red,
                        int* __restrict__ btot)
{
    __shared__ int cs[256];
    int t = threadIdx.x;
    int cnt = 0;
    for (int i = t; i < 1024; i += 256) {
        int e = (h[2 * i] >> 7) & 0xFF;
        cnt += (e >= 100 && e <= 140) ? 1 : 0;
    }
    cs[t] = cnt;
    __syncthreads();
    for (int s = 128; s > 0; s >>= 1) {
        if (t < s) cs[t] += cs[t + s];
        __syncthreads();
    }
    if (t == 0) flag[0] = (cs[0] > 512) ? 1 : 0;
    red[t] = 0.f;
    btot[t] = 0;
}

// ---- Bucketed CSR build (dst-sorted edges), once per launch ----
__global__ __launch_bounds__(256) void k_bhist(const int* __restrict__ ee,
                                               int* __restrict__ btot, int E)
{
    __shared__ int h[256];
    int t = threadIdx.x;
    h[t] = 0;
    __syncthreads();
    for (int e = blockIdx.x * 256 + t; e < E; e += gridDim.x * 256)
        atomicAdd(&h[ee[e] >> 9], 1);
    __syncthreads();
    if (h[t]) atomicAdd(&btot[t], h[t]);
}

// NOTE: no bbase[256] — a [256] write would alias bcursor[0] (round-9 fault).
__global__ void k_bscan(const int* __restrict__ btot, int* __restrict__ bbase,
                        int* __restrict__ bcursor)
{
    __shared__ int sd[256];
    int t = threadIdx.x;
    int v = btot[t];
    sd[t] = v;
    __syncthreads();
    for (int off = 1; off < 256; off <<= 1) {
        int x = (t >= off) ? sd[t - off] : 0;
        __syncthreads();
        sd[t] += x;
        __syncthreads();
    }
    int excl = sd[t] - v;
    bbase[t] = excl;
    bcursor[t] = excl;
}

// Entry = (dst&511)<<20 | src  (src < 2^17).
__global__ __launch_bounds__(256) void k_bscatter(
    const int* __restrict__ es, const int* __restrict__ ee,
    int* __restrict__ bcursor, unsigned* __restrict__ ebuf, int E)
{
    __shared__ int h[256], gb[256], lr[256];
    int t = threadIdx.x;
    h[t] = 0;
    lr[t] = 0;
    __syncthreads();
    int base = blockIdx.x * ESB;
    unsigned ent[8];
    int bk[8];
#pragma unroll
    for (int i = 0; i < 8; i++) {
        int e = base + t + i * 256;
        if (e < E) {
            int s = es[e], d = ee[e];
            bk[i] = d >> 9;
            ent[i] = (unsigned)s | ((unsigned)(d & 511) << 20);
            atomicAdd(&h[bk[i]], 1);
        } else bk[i] = -1;
    }
    __syncthreads();
    if (h[t]) gb[t] = atomicAdd(&bcursor[t], h[t]);
    __syncthreads();
#pragma unroll
    for (int i = 0; i < 8; i++) {
        if (bk[i] >= 0) {
            int r = atomicAdd(&lr[bk[i]], 1);
            ebuf[gb[bk[i]] + r] = ent[i];
        }
    }
}

__global__ __launch_bounds__(256) void k_group(
    const int* __restrict__ bbase, const unsigned* __restrict__ ebuf,
    int* __restrict__ rowptr, int* __restrict__ srcidx)
{
    __shared__ int h[512], sc[512];
    int b = blockIdx.x, t = threadIdx.x;
    int lo = bbase[b], hi = bbase[b + 1];
    h[t] = 0;
    h[t + 256] = 0;
    __syncthreads();
    for (int i = lo + t; i < hi; i += 256)
        atomicAdd(&h[ebuf[i] >> 20], 1);
    __syncthreads();
    sc[t] = h[t];
    sc[t + 256] = h[t + 256];
    __syncthreads();
    for (int off = 1; off < 512; off <<= 1) {
        int v0 = (t >= off) ? sc[t - off] : 0;
        int v1 = (t + 256 >= off) ? sc[t + 256 - off] : 0;
        __syncthreads();
        sc[t] += v0;
        sc[t + 256] += v1;
        __syncthreads();
    }
    int n0 = b * 512 + t, n1 = b * 512 + t + 256;
    int e0 = lo + sc[t] - h[t];
    int e1 = lo + sc[t + 256] - h[t + 256];
    if (n0 < NNODES) rowptr[n0] = e0;
    if (n1 < NNODES) rowptr[n1] = e1;
    if (b == NBUK - 1 && t == 0) rowptr[NNODES] = hi;
    h[t] = e0;           // repurpose as fill cursors
    h[t + 256] = e1;
    __syncthreads();
    for (int i = lo + t; i < hi; i += 256) {
        unsigned en = ebuf[i];
        int pos = atomicAdd(&h[en >> 20], 1);
        int s = (int)(en & 0xFFFFF);
        srcidx[pos] = s < NNODES ? s : 0;  // clamp: degrade, never fault
    }
}

// Load one 64-row x tile slice (16 bf16) into registers.
// MODE 0: rows from concat(u,v), dtype per bfflag. MODE 1: relu(ab*A+ab').
template <int MODE>
__device__ __forceinline__ void stage_load(
    int tile, int tid, int bfflag,
    const void* u, const void* v, const float* Aacc, const float* ab,
    uint4& w0, uint4& w1)
{
    int r = tid >> 2, c0 = (tid & 3) * 16;
    int row = tile * DD + r;
    int rowc = row < NNODES ? row : NNODES - 1;
    if (MODE == 0) {
        const void* src = (rowc < NUSERS) ? u : v;
        size_t off = (rowc < NUSERS) ? ((size_t)rowc * DD + c0)
                                     : ((size_t)(rowc - NUSERS) * DD + c0);
        if (bfflag) {
            const uint4* p = (const uint4*)((const unsigned short*)src + off);
            w0 = p[0];
            w1 = p[1];
        } else {
            const float4* p = (const float4*)((const float*)src + off);
            float4 f0 = p[0], f1 = p[1], f2 = p[2], f3 = p[3];
            w0 = make_uint4(pack2(f0.x, f0.y), pack2(f0.z, f0.w),
                            pack2(f1.x, f1.y), pack2(f1.z, f1.w));
            w1 = make_uint4(pack2(f2.x, f2.y), pack2(f2.z, f2.w),
                            pack2(f3.x, f3.y), pack2(f3.z, f3.w));
        }
    } else {
        const float4* p  = (const float4*)(Aacc + (size_t)rowc * DD + c0);
        const float4* pa = (const float4*)(ab + c0);
        const float4* pb = (const float4*)(ab + 64 + c0);
        float4 f0 = p[0], f1 = p[1], f2 = p[2], f3 = p[3];
        float4 a0 = pa[0], a1 = pa[1], a2 = pa[2], a3 = pa[3];
        float4 g0 = pb[0], g1 = pb[1], g2 = pb[2], g3 = pb[3];
        w0 = make_uint4(pr2(f0.x, f0.y, a0.x, a0.y, g0.x, g0.y),
                        pr2(f0.z, f0.w, a0.z, a0.w, g0.z, g0.w),
                        pr2(f1.x, f1.y, a1.x, a1.y, g1.x, g1.y),
                        pr2(f1.z, f1.w, a1.z, a1.w, g1.z, g1.w));
        w1 = make_uint4(pr2(f2.x, f2.y, a2.x, a2.y, g2.x, g2.y),
                        pr2(f2.z, f2.w, a2.z, a2.w, g2.z, g2.w),
                        pr2(f3.x, f3.y, a3.x, a3.y, g3.x, g3.y),
                        pr2(f3.z, f3.w, a3.z, a3.w, g3.z, g3.w));
    }
}

__device__ __forceinline__ void stage_store(unsigned short* xbuf, int tid,
                                            const uint4& w0, const uint4& w1)
{
    int r = tid >> 2, c0 = (tid & 3) * 16;
    *(uint4*)&xbuf[r * 72 + c0] = w0;
    *((uint4*)&xbuf[r * 72 + c0] + 1) = w1;
}

// ---- MFMA fused 4-GEMM, double-buffered + pipelined.
// wave0: A = x@W0 + b0 (fp32)
// wave1: Ed = exp(-(x@W1 + b1)) (bf16)  — dst sigmoid factor
// waves 2/3: 2 rowtiles each, BOTH W2,W3:
//            T = bits(x@W2) | bits(exp(-(x@W3)))<<16  (msg | src sigmoid factor)
template <int MODE>
__global__ __launch_bounds__(256, 4) void k_mm4_mfma(
    const void* __restrict__ u, const void* __restrict__ v,
    const float* __restrict__ ab,
    const void* __restrict__ W0, const void* __restrict__ W1,
    const void* __restrict__ W2, const void* __restrict__ W3,
    const void* __restrict__ b0, const void* __restrict__ b1,
    const int* __restrict__ flag,
    float* __restrict__ A, unsigned short* __restrict__ Ed,
    unsigned* __restrict__ Tw)
{
    __shared__ __align__(16) unsigned short lsd[4 * DD * 72];  // 36,864 B
    const int bfflag = flag[0];
    const int tid = threadIdx.x;

    // Issue first x-tile load ASAP (hidden behind weight staging).
    int t = blockIdx.x;
    uint4 xa, xb;
    stage_load<MODE>(t, tid, bfflag, u, v, A, ab, xa, xb);

    if (bfflag) {
#define WSTG_BF(m, src)                                                   \
        _Pragma("unroll")                                                 \
        for (int j = 0; j < 2; j++) {                                     \
            int i = tid + j * 256; int e0 = i * 8;                        \
            *(uint4*)&lsd[(m) * 4608 + (e0 >> 6) * 72 + (e0 & 63)] =      \
                ((const uint4*)(src))[i];                                 \
        }
        WSTG_BF(0, W0) WSTG_BF(1, W1) WSTG_BF(2, W2) WSTG_BF(3, W3)
    } else {
#define WSTG_F32(m, src)                                                  \
        _Pragma("unroll")                                                 \
        for (int j = 0; j < 4; j++) {                                     \
            int i = tid + j * 256; int e0 = i * 4;                        \
            float4 f = ((const float4*)(src))[i];                         \
            *(uint2*)&lsd[(m) * 4608 + (e0 >> 6) * 72 + (e0 & 63)] =      \
                make_uint2(pack2(f.x, f.y), pack2(f.z, f.w));             \
        }
        WSTG_F32(0, W0) WSTG_F32(1, W1) WSTG_F32(2, W2) WSTG_F32(3, W3)
    }
    __syncthreads();

    const int wv = tid >> 6, lane = tid & 63;
    const int quad = lane >> 4, ln = lane & 15;
    const int mA = (wv < 2) ? wv : 2;
    bf16x8 bfrA[2][4], bfrB[2][4];
#pragma unroll
    for (int ks = 0; ks < 2; ks++)
#pragma unroll
        for (int nt = 0; nt < 4; nt++)
#pragma unroll
            for (int j = 0; j < 8; j++)
                bfrA[ks][nt][j] = (short)lsd[mA * 4608 +
                    (ks * 32 + quad * 8 + j) * 72 + nt * 16 + ln];
    if (wv >= 2) {
#pragma unroll
        for (int ks = 0; ks < 2; ks++)
#pragma unroll
            for (int nt = 0; nt < 4; nt++)
#pragma unroll
                for (int j = 0; j < 8; j++)
                    bfrB[ks][nt][j] = (short)lsd[3 * 4608 +
                        (ks * 32 + quad * 8 + j) * 72 + nt * 16 + ln];
    }
    float bias[4];
#pragma unroll
    for (int nt = 0; nt < 4; nt++)
        bias[nt] = (wv == 0) ? ldf(b0, nt * 16 + ln, bfflag)
                 : (wv == 1) ? ldf(b1, nt * 16 + ln, bfflag) : 0.f;
    __syncthreads();  // weights fully consumed; region becomes x buffers

    auto compute = [&](const unsigned short* xt, int row0) {
        if (wv < 2) {
#pragma unroll
            for (int rt = 0; rt < 4; rt++) {
                int m = rt * 16 + ln;
                bf16x8 af0 = *(const bf16x8*)&xt[m * 72 + quad * 8];
                bf16x8 af1 = *(const bf16x8*)&xt[m * 72 + 32 + quad * 8];
#pragma unroll
                for (int nt = 0; nt < 4; nt++) {
                    f32x4 c = {0.f, 0.f, 0.f, 0.f};
                    c = __builtin_amdgcn_mfma_f32_16x16x32_bf16(af0, bfrA[0][nt], c, 0, 0, 0);
                    c = __builtin_amdgcn_mfma_f32_16x16x32_bf16(af1, bfrA[1][nt], c, 0, 0, 0);
                    int col = nt * 16 + ln;
#pragma unroll
                    for (int r = 0; r < 4; r++) {
                        int row = row0 + rt * 16 + quad * 4 + r;
                        if (row < NNODES) {
                            size_t o = (size_t)row * DD + col;
                            if (wv == 0) A[o] = c[r] + bias[nt];
                            else         Ed[o] = fbits(__expf(-(c[r] + bias[nt])));
                        }
                    }
                }
            }
        } else {
            const int rtb = (wv - 2) * 2;
#pragma unroll
            for (int rr = 0; rr < 2; rr++) {
                int rt = rtb + rr;
                int m = rt * 16 + ln;
                bf16x8 af0 = *(const bf16x8*)&xt[m * 72 + quad * 8];
                bf16x8 af1 = *(const bf16x8*)&xt[m * 72 + 32 + quad * 8];
#pragma unroll
                for (int nt = 0; nt < 4; nt++) {
                    f32x4 c2 = {0.f, 0.f, 0.f, 0.f};
                    f32x4 c3 = {0.f, 0.f, 0.f, 0.f};
                    c2 = __builtin_amdgcn_mfma_f32_16x16x32_bf16(af0, bfrA[0][nt], c2, 0, 0, 0);
                    c2 = __builtin_amdgcn_mfma_f32_16x16x32_bf16(af1, bfrA[1][nt], c2, 0, 0, 0);
                    c3 = __builtin_amdgcn_mfma_f32_16x16x32_bf16(af0, bfrB[0][nt], c3, 0, 0, 0);
                    c3 = __builtin_amdgcn_mfma_f32_16x16x32_bf16(af1, bfrB[1][nt], c3, 0, 0, 0);
                    int col = nt * 16 + ln;
#pragma unroll
                    for (int r = 0; r < 4; r++) {
                        int row = row0 + rt * 16 + quad * 4 + r;
                        if (row < NNODES)
                            Tw[(size_t)row * DD + col] =
                                pack2(c2[r], __expf(-c3[r]));
                    }
                }
            }
        }
    };

    // Pipelined tile loop (double-buffered x in the reclaimed weight LDS).
    stage_store(lsd, tid, xa, xb);
    int tn = t + GMM;
    if (tn < NGB)
        stage_load<MODE>(tn, tid, bfflag, u, v, A, ab, xa, xb);
    __syncthreads();
    int buf = 0;
    while (true) {
        compute(lsd + buf * 4608, t * DD);
        if (tn >= NGB) break;
        t = tn;
        tn += GMM;
        stage_store(lsd + (buf ^ 1) * 4608, tid, xa, xb);
        if (tn < NGB)
            stage_load<MODE>(tn, tid, bfflag, u, v, A, ab, xa, xb);
        __syncthreads();
        buf ^= 1;
    }
}

// ---- MFMA final: out = relu(ab*A + ab' + x_in@R); wave w = rowtile w.
__global__ __launch_bounds__(256) void k_final_mfma(
    const float* __restrict__ A, const float* __restrict__ ab,
    const void* __restrict__ u, const void* __restrict__ v,
    const void* __restrict__ R, const int* __restrict__ flag,
    void* __restrict__ out)
{
    __shared__ __align__(16) unsigned short Wls[DD][72];
    __shared__ __align__(16) unsigned short xls[DD][72];
    const int bfflag = flag[0];
    const int tid = threadIdx.x;
    if (bfflag) {
        for (int i = tid; i < 512; i += 256) {
            int e0 = i * 8;
            *(uint4*)&Wls[e0 >> 6][e0 & 63] = ((const uint4*)R)[i];
        }
    } else {
        for (int i = tid; i < 1024; i += 256) {
            int e0 = i * 4;
            float4 f = ((const float4*)R)[i];
            *(uint2*)&Wls[e0 >> 6][e0 & 63] =
                make_uint2(pack2(f.x, f.y), pack2(f.z, f.w));
        }
    }
    uint4 w0, w1;
    stage_load<0>(blockIdx.x, tid, bfflag, u, v, nullptr, nullptr, w0, w1);
    stage_store(&xls[0][0], tid, w0, w1);
    __syncthreads();

    const int row0 = blockIdx.x * DD;
    const int wv = tid >> 6, lane = tid & 63;
    const int quad = lane >> 4, ln = lane & 15;
    bf16x8 bfr[2][4];
#pragma unroll
    for (int ks = 0; ks < 2; ks++)
#pragma unroll
        for (int nt = 0; nt < 4; nt++)
#pragma unroll
            for (int j = 0; j < 8; j++)
                bfr[ks][nt][j] = (short)Wls[ks * 32 + quad * 8 + j][nt * 16 + ln];
    float av[4], bv[4];
#pragma unroll
    for (int nt = 0; nt < 4; nt++) {
        av[nt] = ab[nt * 16 + ln];
        bv[nt] = ab[64 + nt * 16 + ln];
    }
    const int rt = wv;
    int m = rt * 16 + ln;
    bf16x8 af0 = *(const bf16x8*)&xls[m][quad * 8];
    bf16x8 af1 = *(const bf16x8*)&xls[m][32 + quad * 8];
#pragma unroll
    for (int nt = 0; nt < 4; nt++) {
        f32x4 c = {0.f, 0.f, 0.f, 0.f};
        c = __builtin_amdgcn_mfma_f32_16x16x32_bf16(af0, bfr[0][nt], c, 0, 0, 0);
        c = __builtin_amdgcn_mfma_f32_16x16x32_bf16(af1, bfr[1][nt], c, 0, 0, 0);
        int col = nt * 16 + ln;
#pragma unroll
        for (int r = 0; r < 4; r++) {
            int row = row0 + rt * 16 + quad * 4 + r;
            if (row < NNODES) {
                size_t o = (size_t)row * DD + col;
                float vv = av[nt] * A[o] + bv[nt] + c[r];
                vv = vv > 0.f ? vv : 0.f;
                if (bfflag) ((unsigned short*)out)[o] = fbits(vv);
                else        ((float*)out)[o] = vv;
            }
        }
    }
}

// ---- Gather-accumulate: one wave per dst node.
// sigma(gd+gs) = 1/(1 + e^-gd * e^-gs) = rcp(1 + Ed*Es) — no exp in the loop.
__global__ __launch_bounds__(256) void k_accum(
    const int* __restrict__ rowptr, const int* __restrict__ srcidx,
    const unsigned* __restrict__ T, const bf16* __restrict__ Ed,
    float* __restrict__ A)
{
    int d = blockIdx.x * 4 + (threadIdx.x >> 6);
    if (d >= NNODES) return;
    int c = threadIdx.x & 63;
    int r0 = rowptr[d], r1 = rowptr[d + 1];
    size_t o = (size_t)d * DD + c;
    float ed = b2f(Ed[o]);
    float sum = A[o];
    int i = r0;
#define EDGE(tv) sum += lo_bf16(tv) * \
    __builtin_amdgcn_rcpf(1.f + ed * hi_bf16(tv));
    for (; i + 7 < r1; i += 8) {
        unsigned t0 = T[(size_t)srcidx[i] * DD + c];
        unsigned t1 = T[(size_t)srcidx[i + 1] * DD + c];
        unsigned t2 = T[(size_t)srcidx[i + 2] * DD + c];
        unsigned t3 = T[(size_t)srcidx[i + 3] * DD + c];
        unsigned t4 = T[(size_t)srcidx[i + 4] * DD + c];
        unsigned t5 = T[(size_t)srcidx[i + 5] * DD + c];
        unsigned t6 = T[(size_t)srcidx[i + 6] * DD + c];
        unsigned t7 = T[(size_t)srcidx[i + 7] * DD + c];
        EDGE(t0) EDGE(t1) EDGE(t2) EDGE(t3)
        EDGE(t4) EDGE(t5) EDGE(t6) EDGE(t7)
    }
    for (; i + 3 < r1; i += 4) {
        unsigned t0 = T[(size_t)srcidx[i] * DD + c];
        unsigned t1 = T[(size_t)srcidx[i + 1] * DD + c];
        unsigned t2 = T[(size_t)srcidx[i + 2] * DD + c];
        unsigned t3 = T[(size_t)srcidx[i + 3] * DD + c];
        EDGE(t0) EDGE(t1) EDGE(t2) EDGE(t3)
    }
    for (; i < r1; i++) {
        unsigned t = T[(size_t)srcidx[i] * DD + c];
        EDGE(t)
    }
#undef EDGE
    A[o] = sum;
}

// Column sums + sumsq over fp32 [NNODES,64]
__global__ __launch_bounds__(256) void k_reduce(
    const float* __restrict__ x, float* __restrict__ red)
{
    __shared__ float s1[256], s2[256];
    const int c = threadIdx.x & 63, rg = threadIdx.x >> 6;
    float sum = 0.f, sq = 0.f;
    for (int row = blockIdx.x * 4 + rg; row < NNODES; row += gridDim.x * 4) {
        float vv = x[(size_t)row * DD + c];
        sum += vv;
        sq += vv * vv;
    }
    s1[threadIdx.x] = sum;
    s2[threadIdx.x] = sq;
    __syncthreads();
    if (threadIdx.x < 64) {
        sum = s1[c] + s1[64 + c] + s1[128 + c] + s1[192 + c];
        sq = s2[c] + s2[64 + c] + s2[128 + c] + s2[192 + c];
        unsafeAtomicAdd(&red[c], sum);
        unsafeAtomicAdd(&red[64 + c], sq);
    }
}

__global__ void k_stats(const float* __restrict__ red,
                        const void* __restrict__ gamma,
                        const void* __restrict__ beta,
                        const int* __restrict__ flag,
                        float* __restrict__ ab)
{
    int c = threadIdx.x;  // 64 threads
    int bf = flag[0];
    float mean = red[c] * (1.f / NNODES);
    float var = red[64 + c] * (1.f / NNODES) - mean * mean;
    float rstd = rsqrtf(var + 1e-3f);
    float a = ldf(gamma, c, bf) * rstd;
    ab[c] = a;
    ab[64 + c] = ldf(beta, c, bf) - mean * a;
}

extern "C" void kernel_launch(void* const* d_in, const int* in_sizes, int n_in,
                              void* d_out, int out_size, void* d_ws, size_t ws_size,
                              hipStream_t stream)
{
    const void* u   = d_in[0];
    const void* v   = d_in[1];
    const int* es   = (const int*)d_in[2];
    const int* ee   = (const int*)d_in[3];
    const void* Ui1 = d_in[4];
    const void* Uj1 = d_in[5];
    const void* Vi1 = d_in[6];
    const void* Vj1 = d_in[7];
    const void* bu1 = d_in[8];
    const void* bv1 = d_in[9];
    const void* Ui2 = d_in[10];
    const void* Uj2 = d_in[11];
    const void* Vi2 = d_in[12];
    const void* Vj2 = d_in[13];
    const void* bu2 = d_in[14];
    const void* bv2 = d_in[15];
    const void* R   = d_in[16];
    const void* g1  = d_in[17];
    const void* be1 = d_in[18];
    const void* g2  = d_in[19];
    const void* be2 = d_in[20];
    const int E = in_sizes[2];

    // Workspace (~56.8 MB; proven layout). ebuf aliases T (CSR build fully
    // precedes k_mm4<0>'s T writes). Ed table lives in d_out until k_final.
    char* ws = (char*)d_ws;
    float* A       = (float*)(ws);                  // 25.6 MB fp32 accumulator
    unsigned* T    = (unsigned*)(ws + 25600000);    // 25.6 MB (Ui | exp(-Vj)<<16)
    unsigned* ebuf = (unsigned*)(ws + 25600000);    // 4 MB, aliases T
    int* srcidx    = (int*)(ws + 51200000);         // 4 MB
    int* rowptr    = (int*)(ws + 56000000);         // 400,004 B
    float* red     = (float*)(ws + 56802176);       // red1/red2/ab1/ab2 (2 KB)
    int* flag      = (int*)(ws + 56804224);
    int* btot      = (int*)(ws + 56804352);         // 256 ints
    int* bbase     = (int*)(ws + 56805376);         // 256 ints (ends 56806400)
    int* bcursor   = (int*)(ws + 56806400);         // 256 ints
    float* red1 = red, *red2 = red + 128, *ab1 = red + 256, *ab2 = red + 384;
    bf16* Ed = (bf16*)d_out;

    // ---- dtype sniff + bucketed CSR build ----
    k_sniff<<<1, 256, 0, stream>>>((const unsigned short*)u, flag, red, btot);
    k_bhist<<<400, 256, 0, stream>>>(ee, btot, E);
    k_bscan<<<1, 256, 0, stream>>>(btot, bbase, bcursor);
    k_bscatter<<<(E + ESB - 1) / ESB, 256, 0, stream>>>(es, ee, bcursor, ebuf, E);
    k_group<<<NBUK, 256, 0, stream>>>(bbase, ebuf, rowptr, srcidx);

    // ---- stage 1 ----
    k_mm4_mfma<0><<<GMM, 256, 0, stream>>>(u, v, nullptr,
                                           Uj1, Vi1, Ui1, Vj1, bu1, bv1, flag,
                                           A, (unsigned short*)Ed, T);
    k_accum<<<(NNODES + 3) / 4, 256, 0, stream>>>(rowptr, srcidx, T, Ed, A);
    k_reduce<<<1024, 256, 0, stream>>>(A, red1);
    k_stats<<<1, 64, 0, stream>>>(red1, g1, be1, flag, ab1);

    // ---- stage 2 (BN1+relu fused into staging; A updated in place) ----
    k_mm4_mfma<1><<<GMM, 256, 0, stream>>>(nullptr, nullptr, ab1,
                                           Uj2, Vi2, Ui2, Vj2, bu2, bv2, flag,
                                           A, (unsigned short*)Ed, T);
    k_accum<<<(NNODES + 3) / 4, 256, 0, stream>>>(rowptr, srcidx, T, Ed, A);
    k_reduce<<<1024, 256, 0, stream>>>(A, red2);
    k_stats<<<1, 64, 0, stream>>>(red2, g2, be2, flag, ab2);

    // ---- BN2 + residual (x_in@R via MFMA) + relu -> out ----
    k_final_mfma<<<NGB, 256, 0, stream>>>(A, ab2, u, v, R, flag, d_out);
}

// Round 13
// 405.780 us; speedup vs baseline: 3.3295x; 1.0327x over previous
//
#include <hip/hip_runtime.h>
#include <hip/hip_bf16.h>

#define NUSERS 60000
#define NNODES 100000
#define DD 64
#define NGB 1563  // ceil(NNODES/64) — 64-row tiles
#define GMM 782   // k_mm4 grid: exactly 2 tiles per block (balanced)
#define NBUK 196  // ceil(NNODES/512) coarse buckets (dst>>9)
#define ESB 2048  // edges per k_bscatter block

typedef __hip_bfloat16 bf16;
using bf16x8 = __attribute__((ext_vector_type(8))) short;
using f32x4  = __attribute__((ext_vector_type(4))) float;

__device__ __forceinline__ float b2f(bf16 x) { return __bfloat162float(x); }
__device__ __forceinline__ bf16 f2b(float x) { return __float2bfloat16(x); }
__device__ __forceinline__ unsigned short fbits(float x) {
    union { bf16 b; unsigned short u; } cv; cv.b = f2b(x); return cv.u;
}
__device__ __forceinline__ float us2f(unsigned short h) {
    union { unsigned u; float f; } t; t.u = (unsigned)h << 16; return t.f;
}
__device__ __forceinline__ float lo_bf16(unsigned w) {
    union { unsigned u; float f; } t; t.u = w << 16; return t.f;
}
__device__ __forceinline__ float hi_bf16(unsigned w) {
    union { unsigned u; float f; } t; t.u = w & 0xFFFF0000u; return t.f;
}
__device__ __forceinline__ float ldf(const void* p, size_t i, int isbf) {
    if (isbf) return b2f(((const bf16*)p)[i]);
    return ((const float*)p)[i];
}
__device__ __forceinline__ unsigned pack2(float a, float b) {
    return (unsigned)fbits(a) | ((unsigned)fbits(b) << 16);
}
__device__ __forceinline__ unsigned pr2(float x0, float x1, float a0, float a1,
                                        float b0, float b1) {
    float t0 = a0 * x0 + b0, t1 = a1 * x1 + b1;
    t0 = t0 > 0.f ? t0 : 0.f;
    t1 = t1 > 0.f ? t1 : 0.f;
    return pack2(t0, t1);
}

// Sniff dtype of u_features (bf16 vs fp32) + zero red[0:256] and btot[0:256].
__global__ void k_sniff(const unsigned short* __restrict__ h,
                        int* __restrict__ flag, float* __restrict__ red,
                        int* __restrict__ btot)
{
    __shared__ int cs[256];
    int t = threadIdx.x;
    int cnt = 0;
    for (int i = t; i < 1024; i += 256) {
        int e = (h[2 * i] >> 7) & 0xFF;
        cnt += (e >= 100 && e <= 140) ? 1 : 0;
    }
    cs[t] = cnt;
    __syncthreads();
    for (int s = 128; s > 0; s >>= 1) {
        if (t < s) cs[t] += cs[t + s];
        __syncthreads();
    }
    if (t == 0) flag[0] = (cs[0] > 512) ? 1 : 0;
    red[t] = 0.f;
    btot[t] = 0;
}

// ---- Bucketed CSR build (dst-sorted edges), once per launch ----
__global__ __launch_bounds__(256) void k_bhist(const int* __restrict__ ee,
                                               int* __restrict__ btot, int E)
{
    __shared__ int h[256];
    int t = threadIdx.x;
    h[t] = 0;
    __syncthreads();
    for (int e = blockIdx.x * 256 + t; e < E; e += gridDim.x * 256)
        atomicAdd(&h[ee[e] >> 9], 1);
    __syncthreads();
    if (h[t]) atomicAdd(&btot[t], h[t]);
}

// NOTE: no bbase[256] — a [256] write would alias bcursor[0] (round-9 fault).
__global__ void k_bscan(const int* __restrict__ btot, int* __restrict__ bbase,
                        int* __restrict__ bcursor)
{
    __shared__ int sd[256];
    int t = threadIdx.x;
    int v = btot[t];
    sd[t] = v;
    __syncthreads();
    for (int off = 1; off < 256; off <<= 1) {
        int x = (t >= off) ? sd[t - off] : 0;
        __syncthreads();
        sd[t] += x;
        __syncthreads();
    }
    int excl = sd[t] - v;
    bbase[t] = excl;
    bcursor[t] = excl;
}

// Entry = (dst&511)<<20 | src  (src < 2^17).
__global__ __launch_bounds__(256) void k_bscatter(
    const int* __restrict__ es, const int* __restrict__ ee,
    int* __restrict__ bcursor, unsigned* __restrict__ ebuf, int E)
{
    __shared__ int h[256], gb[256], lr[256];
    int t = threadIdx.x;
    h[t] = 0;
    lr[t] = 0;
    __syncthreads();
    int base = blockIdx.x * ESB;
    unsigned ent[8];
    int bk[8];
#pragma unroll
    for (int i = 0; i < 8; i++) {
        int e = base + t + i * 256;
        if (e < E) {
            int s = es[e], d = ee[e];
            bk[i] = d >> 9;
            ent[i] = (unsigned)s | ((unsigned)(d & 511) << 20);
            atomicAdd(&h[bk[i]], 1);
        } else bk[i] = -1;
    }
    __syncthreads();
    if (h[t]) gb[t] = atomicAdd(&bcursor[t], h[t]);
    __syncthreads();
#pragma unroll
    for (int i = 0; i < 8; i++) {
        if (bk[i] >= 0) {
            int r = atomicAdd(&lr[bk[i]], 1);
            ebuf[gb[bk[i]] + r] = ent[i];
        }
    }
}

__global__ __launch_bounds__(256) void k_group(
    const int* __restrict__ bbase, const unsigned* __restrict__ ebuf,
    int* __restrict__ rowptr, int* __restrict__ srcidx)
{
    __shared__ int h[512], sc[512];
    int b = blockIdx.x, t = threadIdx.x;
    int lo = bbase[b], hi = bbase[b + 1];
    h[t] = 0;
    h[t + 256] = 0;
    __syncthreads();
    for (int i = lo + t; i < hi; i += 256)
        atomicAdd(&h[ebuf[i] >> 20], 1);
    __syncthreads();
    sc[t] = h[t];
    sc[t + 256] = h[t + 256];
    __syncthreads();
    for (int off = 1; off < 512; off <<= 1) {
        int v0 = (t >= off) ? sc[t - off] : 0;
        int v1 = (t + 256 >= off) ? sc[t + 256 - off] : 0;
        __syncthreads();
        sc[t] += v0;
        sc[t + 256] += v1;
        __syncthreads();
    }
    int n0 = b * 512 + t, n1 = b * 512 + t + 256;
    int e0 = lo + sc[t] - h[t];
    int e1 = lo + sc[t + 256] - h[t + 256];
    if (n0 < NNODES) rowptr[n0] = e0;
    if (n1 < NNODES) rowptr[n1] = e1;
    if (b == NBUK - 1 && t == 0) rowptr[NNODES] = hi;
    h[t] = e0;           // repurpose as fill cursors
    h[t + 256] = e1;
    __syncthreads();
    for (int i = lo + t; i < hi; i += 256) {
        unsigned en = ebuf[i];
        int pos = atomicAdd(&h[en >> 20], 1);
        int s = (int)(en & 0xFFFFF);
        srcidx[pos] = s < NNODES ? s : 0;  // clamp: degrade, never fault
    }
}

// Load one 64-row x tile slice (16 bf16) into registers.
// MODE 0: rows from concat(u,v), dtype per bfflag.
// MODE 1: x = relu(ab*A + ab') with A stored as bf16.
template <int MODE>
__device__ __forceinline__ void stage_load(
    int tile, int tid, int bfflag,
    const void* u, const void* v, const unsigned short* Aacc,
    const float* ab, uint4& w0, uint4& w1)
{
    int r = tid >> 2, c0 = (tid & 3) * 16;
    int row = tile * DD + r;
    int rowc = row < NNODES ? row : NNODES - 1;
    if (MODE == 0) {
        const void* src = (rowc < NUSERS) ? u : v;
        size_t off = (rowc < NUSERS) ? ((size_t)rowc * DD + c0)
                                     : ((size_t)(rowc - NUSERS) * DD + c0);
        if (bfflag) {
            const uint4* p = (const uint4*)((const unsigned short*)src + off);
            w0 = p[0];
            w1 = p[1];
        } else {
            const float4* p = (const float4*)((const float*)src + off);
            float4 f0 = p[0], f1 = p[1], f2 = p[2], f3 = p[3];
            w0 = make_uint4(pack2(f0.x, f0.y), pack2(f0.z, f0.w),
                            pack2(f1.x, f1.y), pack2(f1.z, f1.w));
            w1 = make_uint4(pack2(f2.x, f2.y), pack2(f2.z, f2.w),
                            pack2(f3.x, f3.y), pack2(f3.z, f3.w));
        }
    } else {
        const uint4* p = (const uint4*)(Aacc + (size_t)rowc * DD + c0);
        unsigned aw[8];
        *(uint4*)&aw[0] = p[0];
        *(uint4*)&aw[4] = p[1];
        const float4* pa = (const float4*)(ab + c0);
        const float4* pb = (const float4*)(ab + 64 + c0);
        float av[16], bv[16];
#pragma unroll
        for (int j = 0; j < 4; j++) {
            float4 fa = pa[j], fb = pb[j];
            av[4 * j] = fa.x; av[4 * j + 1] = fa.y;
            av[4 * j + 2] = fa.z; av[4 * j + 3] = fa.w;
            bv[4 * j] = fb.x; bv[4 * j + 1] = fb.y;
            bv[4 * j + 2] = fb.z; bv[4 * j + 3] = fb.w;
        }
        unsigned ow[8];
#pragma unroll
        for (int j = 0; j < 8; j++)
            ow[j] = pr2(lo_bf16(aw[j]), hi_bf16(aw[j]),
                        av[2 * j], av[2 * j + 1], bv[2 * j], bv[2 * j + 1]);
        w0 = *(uint4*)&ow[0];
        w1 = *(uint4*)&ow[4];
    }
}

__device__ __forceinline__ void stage_store(unsigned short* xbuf, int tid,
                                            const uint4& w0, const uint4& w1)
{
    int r = tid >> 2, c0 = (tid & 3) * 16;
    *(uint4*)&xbuf[r * 72 + c0] = w0;
    *((uint4*)&xbuf[r * 72 + c0] + 1) = w1;
}

// ---- MFMA fused 4-GEMM, double-buffered + pipelined. Balanced: 2 tiles/block.
// wave0: A = x@W0 + b0 (bf16 accumulator)
// wave1: Ed = exp(-(x@W1 + b1)) (bf16)  — dst sigmoid factor
// waves 2/3: 2 rowtiles each, BOTH W2,W3:
//            T = bits(x@W2) | bits(exp(-(x@W3)))<<16  (msg | src sigmoid factor)
template <int MODE>
__global__ __launch_bounds__(256, 4) void k_mm4_mfma(
    const void* __restrict__ u, const void* __restrict__ v,
    const float* __restrict__ ab,
    const void* __restrict__ W0, const void* __restrict__ W1,
    const void* __restrict__ W2, const void* __restrict__ W3,
    const void* __restrict__ b0, const void* __restrict__ b1,
    const int* __restrict__ flag,
    unsigned short* __restrict__ A, unsigned short* __restrict__ Ed,
    unsigned* __restrict__ Tw)
{
    __shared__ __align__(16) unsigned short lsd[4 * DD * 72];  // 36,864 B
    const int bfflag = flag[0];
    const int tid = threadIdx.x;

    // Issue first x-tile load ASAP (hidden behind weight staging).
    int t = blockIdx.x;
    uint4 xa, xb;
    stage_load<MODE>(t, tid, bfflag, u, v, A, ab, xa, xb);

    if (bfflag) {
#define WSTG_BF(m, src)                                                   \
        _Pragma("unroll")                                                 \
        for (int j = 0; j < 2; j++) {                                     \
            int i = tid + j * 256; int e0 = i * 8;                        \
            *(uint4*)&lsd[(m) * 4608 + (e0 >> 6) * 72 + (e0 & 63)] =      \
                ((const uint4*)(src))[i];                                 \
        }
        WSTG_BF(0, W0) WSTG_BF(1, W1) WSTG_BF(2, W2) WSTG_BF(3, W3)
    } else {
#define WSTG_F32(m, src)                                                  \
        _Pragma("unroll")                                                 \
        for (int j = 0; j < 4; j++) {                                     \
            int i = tid + j * 256; int e0 = i * 4;                        \
            float4 f = ((const float4*)(src))[i];                         \
            *(uint2*)&lsd[(m) * 4608 + (e0 >> 6) * 72 + (e0 & 63)] =      \
                make_uint2(pack2(f.x, f.y), pack2(f.z, f.w));             \
        }
        WSTG_F32(0, W0) WSTG_F32(1, W1) WSTG_F32(2, W2) WSTG_F32(3, W3)
    }
    __syncthreads();

    const int wv = tid >> 6, lane = tid & 63;
    const int quad = lane >> 4, ln = lane & 15;
    const int mA = (wv < 2) ? wv : 2;
    bf16x8 bfrA[2][4], bfrB[2][4];
#pragma unroll
    for (int ks = 0; ks < 2; ks++)
#pragma unroll
        for (int nt = 0; nt < 4; nt++)
#pragma unroll
            for (int j = 0; j < 8; j++)
                bfrA[ks][nt][j] = (short)lsd[mA * 4608 +
                    (ks * 32 + quad * 8 + j) * 72 + nt * 16 + ln];
    if (wv >= 2) {
#pragma unroll
        for (int ks = 0; ks < 2; ks++)
#pragma unroll
            for (int nt = 0; nt < 4; nt++)
#pragma unroll
                for (int j = 0; j < 8; j++)
                    bfrB[ks][nt][j] = (short)lsd[3 * 4608 +
                        (ks * 32 + quad * 8 + j) * 72 + nt * 16 + ln];
    }
    float bias[4];
#pragma unroll
    for (int nt = 0; nt < 4; nt++)
        bias[nt] = (wv == 0) ? ldf(b0, nt * 16 + ln, bfflag)
                 : (wv == 1) ? ldf(b1, nt * 16 + ln, bfflag) : 0.f;
    __syncthreads();  // weights fully consumed; region becomes x buffers

    auto compute = [&](const unsigned short* xt, int row0) {
        if (wv < 2) {
#pragma unroll
            for (int rt = 0; rt < 4; rt++) {
                int m = rt * 16 + ln;
                bf16x8 af0 = *(const bf16x8*)&xt[m * 72 + quad * 8];
                bf16x8 af1 = *(const bf16x8*)&xt[m * 72 + 32 + quad * 8];
#pragma unroll
                for (int nt = 0; nt < 4; nt++) {
                    f32x4 c = {0.f, 0.f, 0.f, 0.f};
                    c = __builtin_amdgcn_mfma_f32_16x16x32_bf16(af0, bfrA[0][nt], c, 0, 0, 0);
                    c = __builtin_amdgcn_mfma_f32_16x16x32_bf16(af1, bfrA[1][nt], c, 0, 0, 0);
                    int col = nt * 16 + ln;
#pragma unroll
                    for (int r = 0; r < 4; r++) {
                        int row = row0 + rt * 16 + quad * 4 + r;
                        if (row < NNODES) {
                            size_t o = (size_t)row * DD + col;
                            if (wv == 0) A[o] = fbits(c[r] + bias[nt]);
                            else         Ed[o] = fbits(__expf(-(c[r] + bias[nt])));
                        }
                    }
                }
            }
        } else {
            const int rtb = (wv - 2) * 2;
#pragma unroll
            for (int rr = 0; rr < 2; rr++) {
                int rt = rtb + rr;
                int m = rt * 16 + ln;
                bf16x8 af0 = *(const bf16x8*)&xt[m * 72 + quad * 8];
                bf16x8 af1 = *(const bf16x8*)&xt[m * 72 + 32 + quad * 8];
#pragma unroll
                for (int nt = 0; nt < 4; nt++) {
                    f32x4 c2 = {0.f, 0.f, 0.f, 0.f};
                    f32x4 c3 = {0.f, 0.f, 0.f, 0.f};
                    c2 = __builtin_amdgcn_mfma_f32_16x16x32_bf16(af0, bfrA[0][nt], c2, 0, 0, 0);
                    c2 = __builtin_amdgcn_mfma_f32_16x16x32_bf16(af1, bfrA[1][nt], c2, 0, 0, 0);
                    c3 = __builtin_amdgcn_mfma_f32_16x16x32_bf16(af0, bfrB[0][nt], c3, 0, 0, 0);
                    c3 = __builtin_amdgcn_mfma_f32_16x16x32_bf16(af1, bfrB[1][nt], c3, 0, 0, 0);
                    int col = nt * 16 + ln;
#pragma unroll
                    for (int r = 0; r < 4; r++) {
                        int row = row0 + rt * 16 + quad * 4 + r;
                        if (row < NNODES)
                            Tw[(size_t)row * DD + col] =
                                pack2(c2[r], __expf(-c3[r]));
                    }
                }
            }
        }
    };

    // Pipelined tile loop (double-buffered x in the reclaimed weight LDS).
    stage_store(lsd, tid, xa, xb);
    int tn = t + GMM;
    if (tn < NGB)
        stage_load<MODE>(tn, tid, bfflag, u, v, A, ab, xa, xb);
    __syncthreads();
    int buf = 0;
    while (true) {
        compute(lsd + buf * 4608, t * DD);
        if (tn >= NGB) break;
        t = tn;
        tn += GMM;
        stage_store(lsd + (buf ^ 1) * 4608, tid, xa, xb);
        if (tn < NGB)
            stage_load<MODE>(tn, tid, bfflag, u, v, A, ab, xa, xb);
        __syncthreads();
        buf ^= 1;
    }
}

// ---- MFMA final: out = relu(ab*A + ab' + x_in@R); wave w = rowtile w.
__global__ __launch_bounds__(256) void k_final_mfma(
    const unsigned short* __restrict__ A, const float* __restrict__ ab,
    const void* __restrict__ u, const void* __restrict__ v,
    const void* __restrict__ R, const int* __restrict__ flag,
    void* __restrict__ out)
{
    __shared__ __align__(16) unsigned short Wls[DD][72];
    __shared__ __align__(16) unsigned short xls[DD][72];
    const int bfflag = flag[0];
    const int tid = threadIdx.x;
    if (bfflag) {
        for (int i = tid; i < 512; i += 256) {
            int e0 = i * 8;
            *(uint4*)&Wls[e0 >> 6][e0 & 63] = ((const uint4*)R)[i];
        }
    } else {
        for (int i = tid; i < 1024; i += 256) {
            int e0 = i * 4;
            float4 f = ((const float4*)R)[i];
            *(uint2*)&Wls[e0 >> 6][e0 & 63] =
                make_uint2(pack2(f.x, f.y), pack2(f.z, f.w));
        }
    }
    uint4 w0, w1;
    stage_load<0>(blockIdx.x, tid, bfflag, u, v, nullptr, nullptr, w0, w1);
    stage_store(&xls[0][0], tid, w0, w1);
    __syncthreads();

    const int row0 = blockIdx.x * DD;
    const int wv = tid >> 6, lane = tid & 63;
    const int quad = lane >> 4, ln = lane & 15;
    bf16x8 bfr[2][4];
#pragma unroll
    for (int ks = 0; ks < 2; ks++)
#pragma unroll
        for (int nt = 0; nt < 4; nt++)
#pragma unroll
            for (int j = 0; j < 8; j++)
                bfr[ks][nt][j] = (short)Wls[ks * 32 + quad * 8 + j][nt * 16 + ln];
    float av[4], bv[4];
#pragma unroll
    for (int nt = 0; nt < 4; nt++) {
        av[nt] = ab[nt * 16 + ln];
        bv[nt] = ab[64 + nt * 16 + ln];
    }
    const int rt = wv;
    int m = rt * 16 + ln;
    bf16x8 af0 = *(const bf16x8*)&xls[m][quad * 8];
    bf16x8 af1 = *(const bf16x8*)&xls[m][32 + quad * 8];
#pragma unroll
    for (int nt = 0; nt < 4; nt++) {
        f32x4 c = {0.f, 0.f, 0.f, 0.f};
        c = __builtin_amdgcn_mfma_f32_16x16x32_bf16(af0, bfr[0][nt], c, 0, 0, 0);
        c = __builtin_amdgcn_mfma_f32_16x16x32_bf16(af1, bfr[1][nt], c, 0, 0, 0);
        int col = nt * 16 + ln;
#pragma unroll
        for (int r = 0; r < 4; r++) {
            int row = row0 + rt * 16 + quad * 4 + r;
            if (row < NNODES) {
                size_t o = (size_t)row * DD + col;
                float vv = av[nt] * us2f(A[o]) + bv[nt] + c[r];
                vv = vv > 0.f ? vv : 0.f;
                if (bfflag) ((unsigned short*)out)[o] = fbits(vv);
                else        ((float*)out)[o] = vv;
            }
        }
    }
}

// ---- Gather-accumulate: one wave per dst node. A stored bf16, summed fp32.
// sigma(gd+gs) = 1/(1 + e^-gd * e^-gs) = rcp(1 + Ed*Es) — no exp in the loop.
__global__ __launch_bounds__(256) void k_accum(
    const int* __restrict__ rowptr, const int* __restrict__ srcidx,
    const unsigned* __restrict__ T, const bf16* __restrict__ Ed,
    unsigned short* __restrict__ A)
{
    int d = blockIdx.x * 4 + (threadIdx.x >> 6);
    if (d >= NNODES) return;
    int c = threadIdx.x & 63;
    int r0 = rowptr[d], r1 = rowptr[d + 1];
    size_t o = (size_t)d * DD + c;
    float ed = b2f(Ed[o]);
    float sum = us2f(A[o]);
    int i = r0;
#define EDGE(tv) sum += lo_bf16(tv) * \
    __builtin_amdgcn_rcpf(1.f + ed * hi_bf16(tv));
    for (; i + 7 < r1; i += 8) {
        unsigned t0 = T[(size_t)srcidx[i] * DD + c];
        unsigned t1 = T[(size_t)srcidx[i + 1] * DD + c];
        unsigned t2 = T[(size_t)srcidx[i + 2] * DD + c];
        unsigned t3 = T[(size_t)srcidx[i + 3] * DD + c];
        unsigned t4 = T[(size_t)srcidx[i + 4] * DD + c];
        unsigned t5 = T[(size_t)srcidx[i + 5] * DD + c];
        unsigned t6 = T[(size_t)srcidx[i + 6] * DD + c];
        unsigned t7 = T[(size_t)srcidx[i + 7] * DD + c];
        EDGE(t0) EDGE(t1) EDGE(t2) EDGE(t3)
        EDGE(t4) EDGE(t5) EDGE(t6) EDGE(t7)
    }
    for (; i + 3 < r1; i += 4) {
        unsigned t0 = T[(size_t)srcidx[i] * DD + c];
        unsigned t1 = T[(size_t)srcidx[i + 1] * DD + c];
        unsigned t2 = T[(size_t)srcidx[i + 2] * DD + c];
        unsigned t3 = T[(size_t)srcidx[i + 3] * DD + c];
        EDGE(t0) EDGE(t1) EDGE(t2) EDGE(t3)
    }
    for (; i < r1; i++) {
        unsigned t = T[(size_t)srcidx[i] * DD + c];
        EDGE(t)
    }
#undef EDGE
    A[o] = fbits(sum);
}

// Column sums + sumsq over bf16 A [NNODES,64]
__global__ __launch_bounds__(256) void k_reduce(
    const unsigned short* __restrict__ x, float* __restrict__ red)
{
    __shared__ float s1[256], s2[256];
    const int c = threadIdx.x & 63, rg = threadIdx.x >> 6;
    float sum = 0.f, sq = 0.f;
    for (int row = blockIdx.x * 4 + rg; row < NNODES; row += gridDim.x * 4) {
        float vv = us2f(x[(size_t)row * DD + c]);
        sum += vv;
        sq += vv * vv;
    }
    s1[threadIdx.x] = sum;
    s2[threadIdx.x] = sq;
    __syncthreads();
    if (threadIdx.x < 64) {
        sum = s1[c] + s1[64 + c] + s1[128 + c] + s1[192 + c];
        sq = s2[c] + s2[64 + c] + s2[128 + c] + s2[192 + c];
        unsafeAtomicAdd(&red[c], sum);
        unsafeAtomicAdd(&red[64 + c], sq);
    }
}

__global__ void k_stats(const float* __restrict__ red,
                        const void* __restrict__ gamma,
                        const void* __restrict__ beta,
                        const int* __restrict__ flag,
                        float* __restrict__ ab)
{
    int c = threadIdx.x;  // 64 threads
    int bf = flag[0];
    float mean = red[c] * (1.f / NNODES);
    float var = red[64 + c] * (1.f / NNODES) - mean * mean;
    float rstd = rsqrtf(var + 1e-3f);
    float a = ldf(gamma, c, bf) * rstd;
    ab[c] = a;
    ab[64 + c] = ldf(beta, c, bf) - mean * a;
}

extern "C" void kernel_launch(void* const* d_in, const int* in_sizes, int n_in,
                              void* d_out, int out_size, void* d_ws, size_t ws_size,
                              hipStream_t stream)
{
    const void* u   = d_in[0];
    const void* v   = d_in[1];
    const int* es   = (const int*)d_in[2];
    const int* ee   = (const int*)d_in[3];
    const void* Ui1 = d_in[4];
    const void* Uj1 = d_in[5];
    const void* Vi1 = d_in[6];
    const void* Vj1 = d_in[7];
    const void* bu1 = d_in[8];
    const void* bv1 = d_in[9];
    const void* Ui2 = d_in[10];
    const void* Uj2 = d_in[11];
    const void* Vi2 = d_in[12];
    const void* Vj2 = d_in[13];
    const void* bu2 = d_in[14];
    const void* bv2 = d_in[15];
    const void* R   = d_in[16];
    const void* g1  = d_in[17];
    const void* be1 = d_in[18];
    const void* g2  = d_in[19];
    const void* be2 = d_in[20];
    const int E = in_sizes[2];

    // Workspace (~56.8 MB; proven layout — offsets unchanged, A now bf16).
    // ebuf aliases T (CSR build fully precedes k_mm4<0>'s T writes).
    // Ed table lives in d_out until k_final overwrites it.
    char* ws = (char*)d_ws;
    unsigned short* A = (unsigned short*)(ws);      // 12.8 MB bf16 accumulator
    unsigned* T    = (unsigned*)(ws + 25600000);    // 25.6 MB (Ui | exp(-Vj)<<16)
    unsigned* ebuf = (unsigned*)(ws + 25600000);    // 4 MB, aliases T
    int* srcidx    = (int*)(ws + 51200000);         // 4 MB
    int* rowptr    = (int*)(ws + 56000000);         // 400,004 B
    float* red     = (float*)(ws + 56802176);       // red1/red2/ab1/ab2 (2 KB)
    int* flag      = (int*)(ws + 56804224);
    int* btot      = (int*)(ws + 56804352);         // 256 ints
    int* bbase     = (int*)(ws + 56805376);         // 256 ints (ends 56806400)
    int* bcursor   = (int*)(ws + 56806400);         // 256 ints
    float* red1 = red, *red2 = red + 128, *ab1 = red + 256, *ab2 = red + 384;
    bf16* Ed = (bf16*)d_out;

    // ---- dtype sniff + bucketed CSR build ----
    k_sniff<<<1, 256, 0, stream>>>((const unsigned short*)u, flag, red, btot);
    k_bhist<<<400, 256, 0, stream>>>(ee, btot, E);
    k_bscan<<<1, 256, 0, stream>>>(btot, bbase, bcursor);
    k_bscatter<<<(E + ESB - 1) / ESB, 256, 0, stream>>>(es, ee, bcursor, ebuf, E);
    k_group<<<NBUK, 256, 0, stream>>>(bbase, ebuf, rowptr, srcidx);

    // ---- stage 1 ----
    k_mm4_mfma<0><<<GMM, 256, 0, stream>>>(u, v, nullptr,
                                           Uj1, Vi1, Ui1, Vj1, bu1, bv1, flag,
                                           A, (unsigned short*)Ed, T);
    k_accum<<<(NNODES + 3) / 4, 256, 0, stream>>>(rowptr, srcidx, T, Ed, A);
    k_reduce<<<1024, 256, 0, stream>>>(A, red1);
    k_stats<<<1, 64, 0, stream>>>(red1, g1, be1, flag, ab1);

    // ---- stage 2 (BN1+relu fused into staging; A updated in place) ----
    k_mm4_mfma<1><<<GMM, 256, 0, stream>>>(nullptr, nullptr, ab1,
                                           Uj2, Vi2, Ui2, Vj2, bu2, bv2, flag,
                                           A, (unsigned short*)Ed, T);
    k_accum<<<(NNODES + 3) / 4, 256, 0, stream>>>(rowptr, srcidx, T, Ed, A);
    k_reduce<<<1024, 256, 0, stream>>>(A, red2);
    k_stats<<<1, 64, 0, stream>>>(red2, g2, be2, flag, ab2);

    // ---- BN2 + residual (x_in@R via MFMA) + relu -> out ----
    k_final_mfma<<<NGB, 256, 0, stream>>>(A, ab2, u, v, R, flag, d_out);
}